// Round 15
// baseline (273.811 us; speedup 1.0000x reference)
//
#include <hip/hip_runtime.h>
#include <cstdint>
#include <cstddef>

#define NN 50000
#define NE 1600000
#define ET (NE + NN)          // edges + self loops
#define NG 64
#define SCAN_BLOCKS ((NN + 255) / 256)   // 196
#define NB ((NN + 127) >> 7)             // 391 dst-buckets, 128 nodes each
#define EPT 16
#define EPB (256 * EPT)                  // 4096 edges per bin-block
#define BIN_BLOCKS ((ET + EPB - 1) / EPB)

// ---------------- K0: transpose W1 [512][64] -> Wt2 k-packed float4
__global__ void k_wt(const float* __restrict__ W1, float* __restrict__ Wt2) {
    int id = blockIdx.x * 256 + threadIdx.x;
    if (id >= 128 * 64) return;
    int k4 = id >> 6, c = id & 63;
    float4 v;
    v.x = W1[(k4 * 4 + 0) * 64 + c];
    v.y = W1[(k4 * 4 + 1) * 64 + c];
    v.z = W1[(k4 * 4 + 2) * 64 + c];
    v.w = W1[(k4 * 4 + 3) * 64 + c];
    reinterpret_cast<float4*>(Wt2)[id] = v;
}

// ---------------- K1: h1 = x @ W1, full-K, 64 rows/block, double-buffered LDS,
// one barrier per phase (prefetch ph+1 overlaps compute ph). Fused as1/ad1.
__global__ __launch_bounds__(256, 8) void k_gemm1(
    const float* __restrict__ x, const float* __restrict__ Wt2,
    const float* __restrict__ aS, const float* __restrict__ aD,
    float* __restrict__ h1, float* __restrict__ as1, float* __restrict__ ad1) {
    __shared__ float4 xs[2][64 * 16];    // 2 x 16 KB
    __shared__ float4 wsr[2][16 * 64];   // 2 x 16 KB

    int t = threadIdx.x;
    int lane = t & 63, wv_id = t >> 6;
    int n0 = blockIdx.x * 64;

    const float4* __restrict__ xf = reinterpret_cast<const float4*>(x);
    const float4* __restrict__ wf = reinterpret_cast<const float4*>(Wt2);

    int tc = t & 15;
    int trg = t >> 4;                 // 0..15; rows trg + 16i
    int swz = (trg & 3) << 1;

    float acc[4][4];
#pragma unroll
    for (int i = 0; i < 4; ++i)
#pragma unroll
        for (int j = 0; j < 4; ++j) acc[i][j] = 0.f;

    // staging helper (4 x-issues + 4 W-issues per wave per phase)
#define STAGE(BUF, PH) {                                                        \
        int kb4 = (PH) * 16;                                                    \
        _Pragma("unroll")                                                       \
        for (int q = 0; q < 4; ++q) {                                           \
            int base = (wv_id * 4 + q) * 64;                                    \
            int s = base + lane;                                                \
            int row = s >> 4;                                                   \
            int m = s & 15;                                                     \
            int k4f = m ^ ((row & 3) << 1);                                     \
            int rr = n0 + row; if (rr >= NN) rr = NN - 1;                       \
            const float4* src = xf + (size_t)rr * 128 + kb4 + k4f;              \
            __builtin_amdgcn_global_load_lds(                                   \
                (const __attribute__((address_space(1))) void*)src,             \
                (__attribute__((address_space(3))) void*)&xs[BUF][base], 16, 0, 0); \
        }                                                                       \
        _Pragma("unroll")                                                       \
        for (int q = 0; q < 4; ++q) {                                           \
            int base = (wv_id * 4 + q) * 64;                                    \
            int s = base + lane;                                                \
            int k4 = s >> 6, c = s & 63;                                        \
            const float4* src = wf + (size_t)(kb4 + k4) * 64 + c;               \
            __builtin_amdgcn_global_load_lds(                                   \
                (const __attribute__((address_space(1))) void*)src,             \
                (__attribute__((address_space(3))) void*)&wsr[BUF][base], 16, 0, 0); \
        }                                                                       \
    }

    STAGE(0, 0);
    __syncthreads();

    int cur = 0;
    for (int ph = 0; ph < 8; ++ph) {
        if (ph + 1 < 8) STAGE(cur ^ 1, ph + 1);

        const float4* __restrict__ xb = xs[cur];
        const float4* __restrict__ wb = wsr[cur];
#pragma unroll 2
        for (int k4 = 0; k4 < 16; ++k4) {
            float4 wv0 = wb[k4 * 64 + tc];
            float4 wv1 = wb[k4 * 64 + tc + 16];
            float4 wv2 = wb[k4 * 64 + tc + 32];
            float4 wv3 = wb[k4 * 64 + tc + 48];
            int kx = k4 ^ swz;
            float4 xv0 = xb[(trg +  0) * 16 + kx];
            float4 xv1 = xb[(trg + 16) * 16 + kx];
            float4 xv2 = xb[(trg + 32) * 16 + kx];
            float4 xv3 = xb[(trg + 48) * 16 + kx];
#define FMA4(a, xv, wv) { a += xv.x * wv.x; a += xv.y * wv.y; a += xv.z * wv.z; a += xv.w * wv.w; }
            FMA4(acc[0][0], xv0, wv0) FMA4(acc[0][1], xv0, wv1) FMA4(acc[0][2], xv0, wv2) FMA4(acc[0][3], xv0, wv3)
            FMA4(acc[1][0], xv1, wv0) FMA4(acc[1][1], xv1, wv1) FMA4(acc[1][2], xv1, wv2) FMA4(acc[1][3], xv1, wv3)
            FMA4(acc[2][0], xv2, wv0) FMA4(acc[2][1], xv2, wv1) FMA4(acc[2][2], xv2, wv2) FMA4(acc[2][3], xv2, wv3)
            FMA4(acc[3][0], xv3, wv0) FMA4(acc[3][1], xv3, wv1) FMA4(acc[3][2], xv3, wv2) FMA4(acc[3][3], xv3, wv3)
#undef FMA4
        }
        __syncthreads();   // waves done with buf[cur]; prefetch into buf[cur^1] landed
        cur ^= 1;
    }
#undef STAGE

    // epilogue: store h1 (cols tc+16j) + fused as1/ad1
    int hb = tc >> 3;        // 0 or 1: heads 2j+hb
    int cc = tc & 7;         // channel within head
#pragma unroll
    for (int i = 0; i < 4; ++i) {
        int r = n0 + trg + 16 * i;
        if (r >= NN) continue;
        float* rowp = h1 + (size_t)r * 64 + tc;
        rowp[0]  = acc[i][0];
        rowp[16] = acc[i][1];
        rowp[32] = acc[i][2];
        rowp[48] = acc[i][3];

        float ps[4], pd[4];
#pragma unroll
        for (int j = 0; j < 4; ++j) {
            int h = 2 * j + hb;
            ps[j] = acc[i][j] * aS[h * 8 + cc];
            pd[j] = acc[i][j] * aD[h * 8 + cc];
        }
#pragma unroll
        for (int ofs = 1; ofs <= 4; ofs <<= 1) {
#pragma unroll
            for (int j = 0; j < 4; ++j) {
                ps[j] += __shfl_xor(ps[j], ofs);
                pd[j] += __shfl_xor(pd[j], ofs);
            }
        }
        if (cc == 0) {
#pragma unroll
            for (int j = 0; j < 4; ++j) {
                int h = 2 * j + hb;
                as1[r * 8 + h] = ps[j];
                ad1[r * 8 + h] = pd[j];
            }
        }
    }
}

// ---------------- CSR build: bhist -> bscan -> bin -> bdeg -> scan -> unbin
__global__ __launch_bounds__(256) void k_bhist(const int* __restrict__ edst, int* __restrict__ bdeg) {
    __shared__ int cnt[NB];
    int tid = threadIdx.x;
    for (int b = tid; b < NB; b += 256) cnt[b] = 0;
    __syncthreads();
    int e0 = blockIdx.x * EPB;
#pragma unroll
    for (int q = 0; q < EPT; ++q) {
        int e = e0 + q * 256 + tid;
        if (e < ET) {
            int d = (e < NE) ? edst[e] : (e - NE);
            atomicAdd(&cnt[d >> 7], 1);
        }
    }
    __syncthreads();
    for (int b = tid; b < NB; b += 256)
        if (cnt[b]) atomicAdd(&bdeg[b], cnt[b]);
}

__global__ __launch_bounds__(512) void k_bscan(const int* __restrict__ bdeg,
                                               int* __restrict__ bo, int* __restrict__ bcur) {
    __shared__ int lds_w[8];
    int tid = threadIdx.x;
    int lane = tid & 63, wid = tid >> 6;
    int v = (tid < NB) ? bdeg[tid] : 0;
    int incl = v;
#pragma unroll
    for (int ofs = 1; ofs < 64; ofs <<= 1) {
        int o = __shfl_up(incl, ofs);
        if (lane >= ofs) incl += o;
    }
    if (lane == 63) lds_w[wid] = incl;
    __syncthreads();
    int wadd = 0;
    for (int w = 0; w < wid; ++w) wadd += lds_w[w];
    incl += wadd;
    int ex = incl - v;
    if (tid < NB) { bo[tid] = ex; bcur[tid] = ex; }
    if (tid == NB - 1) bo[NB] = ex + v;   // == ET
}

__global__ __launch_bounds__(256) void k_bin(
    const int* __restrict__ esrc, const int* __restrict__ edst,
    int* __restrict__ bcur, uint2* __restrict__ rec) {
    __shared__ int bcnt[NB];
    int tid = threadIdx.x;
    for (int b = tid; b < NB; b += 256) bcnt[b] = 0;
    __syncthreads();
    int e0 = blockIdx.x * EPB;
    uint2 rv[EPT]; int rk[EPT];
#pragma unroll
    for (int q = 0; q < EPT; ++q) {
        int e = e0 + q * 256 + tid;
        rk[q] = -1;
        if (e < ET) {
            int s, d;
            if (e < NE) { s = esrc[e]; d = edst[e]; } else { s = d = e - NE; }
            rv[q] = make_uint2((unsigned)s, (unsigned)d);
            rk[q] = atomicAdd(&bcnt[d >> 7], 1);
        }
    }
    __syncthreads();
    for (int b = tid; b < NB; b += 256)
        bcnt[b] = atomicAdd(&bcur[b], bcnt[b]);
    __syncthreads();
#pragma unroll
    for (int q = 0; q < EPT; ++q) {
        if (rk[q] >= 0) rec[bcnt[rv[q].y >> 7] + rk[q]] = rv[q];
    }
}

__global__ __launch_bounds__(256) void k_bdeg(const int* __restrict__ bo, const uint2* __restrict__ rec,
                                              int* __restrict__ deg) {
    __shared__ int cnt[128];
    int b = blockIdx.x, tid = threadIdx.x;
    if (tid < 128) cnt[tid] = 0;
    __syncthreads();
    int lo = bo[b], hi = bo[b + 1];
    for (int i = lo + tid; i < hi; i += 256)
        atomicAdd(&cnt[rec[i].y & 127], 1);
    __syncthreads();
    if (tid < 128) {
        int n = (b << 7) + tid;
        if (n < NN) deg[n] = cnt[tid];
    }
}

__global__ __launch_bounds__(256) void k_scan1(const int* __restrict__ deg,
                                               int* __restrict__ offs, int* __restrict__ bsum) {
    __shared__ int lds_w[4];
    int i = blockIdx.x * 256 + threadIdx.x;
    int v = (i < NN) ? deg[i] : 0;
    int lane = threadIdx.x & 63, wid = threadIdx.x >> 6;
    int incl = v;
#pragma unroll
    for (int ofs = 1; ofs < 64; ofs <<= 1) {
        int o = __shfl_up(incl, ofs);
        if (lane >= ofs) incl += o;
    }
    if (lane == 63) lds_w[wid] = incl;
    __syncthreads();
    int wadd = 0;
    for (int w = 0; w < wid; ++w) wadd += lds_w[w];
    incl += wadd;
    if (i < NN) offs[i] = incl - v;
    if (threadIdx.x == 255) bsum[blockIdx.x] = incl;
}

__global__ void k_scan2(const int* __restrict__ bsum, int* __restrict__ bpre) {
    __shared__ int lds_w[4];
    int lane = threadIdx.x & 63, wid = threadIdx.x >> 6;
    int v = (threadIdx.x < SCAN_BLOCKS) ? bsum[threadIdx.x] : 0;
    int incl = v;
#pragma unroll
    for (int ofs = 1; ofs < 64; ofs <<= 1) {
        int o = __shfl_up(incl, ofs);
        if (lane >= ofs) incl += o;
    }
    if (lane == 63) lds_w[wid] = incl;
    __syncthreads();
    int wadd = 0;
    for (int w = 0; w < wid; ++w) wadd += lds_w[w];
    incl += wadd;
    bpre[threadIdx.x] = incl - v;
}

__global__ void k_scan3(int* __restrict__ offs, const int* __restrict__ bpre) {
    int i = blockIdx.x * 256 + threadIdx.x;
    if (i < NN) offs[i] = offs[i] + bpre[blockIdx.x];
    if (i == 0) offs[NN] = ET;
}

__global__ __launch_bounds__(256) void k_unbin(
    const int* __restrict__ offs, const int* __restrict__ bo,
    const uint2* __restrict__ rec, int* __restrict__ csr) {
    __shared__ int lcur[128];
    int b = blockIdx.x, tid = threadIdx.x;
    if (tid < 128) {
        int n = (b << 7) + tid;
        lcur[tid] = (n < NN) ? offs[n] : 0;
    }
    __syncthreads();
    int lo = bo[b], hi = bo[b + 1];
    for (int i = lo + tid; i < hi; i += 256) {
        uint2 r = rec[i];
        int pos = atomicAdd(&lcur[r.y & 127], 1);
        csr[pos] = (int)r.x;
    }
}

// ---------------- K4: layer-1 aggregation. Wave per dst; lane = (slot g = l>>4, f4 q = l&15).
__global__ __launch_bounds__(256) void k_agg1(
    const int* __restrict__ offs, const int* __restrict__ csr,
    const float* __restrict__ h1, const float* __restrict__ as1, const float* __restrict__ ad1,
    const float* __restrict__ bias1, float* __restrict__ h1o) {
    int l = threadIdx.x & 63;
    int dst = blockIdx.x * 4 + (threadIdx.x >> 6);
    if (dst >= NN) return;
    int g = l >> 4;            // edge slot 0..3
    int q = l & 15;            // float4 index in 64-ch row
    int h = q >> 1;            // head
    int beg = offs[dst], end = offs[dst + 1];
    int lastj = end - 1;       // deg >= 1 (self-loop)
    float adh = ad1[dst * 8 + h];
    const float4* __restrict__ h1f = reinterpret_cast<const float4*>(h1);

    float4 acc = make_float4(0.f, 0.f, 0.f, 0.f);
    float dsum = 0.f;

    int sA[4], sB[4];
#pragma unroll
    for (int p = 0; p < 4; ++p) sA[p] = csr[min(beg + p * 4 + g, lastj)];
    for (int j = beg; j < end; j += 16) {
#pragma unroll
        for (int p = 0; p < 4; ++p) sB[p] = csr[min(j + 16 + p * 4 + g, lastj)];
        float av[4]; float4 vv[4];
#pragma unroll
        for (int p = 0; p < 4; ++p) {
            av[p] = as1[sA[p] * 8 + h];
            vv[p] = h1f[sA[p] * 16 + q];
        }
#pragma unroll
        for (int p = 0; p < 4; ++p) {
            float e = av[p] + adh; e = (e > 0.f) ? e : 0.2f * e;
            float w = __expf(e);
            w = (j + p * 4 + g < end) ? w : 0.f;
            acc.x += w * vv[p].x; acc.y += w * vv[p].y;
            acc.z += w * vv[p].z; acc.w += w * vv[p].w;
            dsum += w;
        }
#pragma unroll
        for (int p = 0; p < 4; ++p) sA[p] = sB[p];
    }

#pragma unroll
    for (int ofs = 16; ofs <= 32; ofs <<= 1) {
        acc.x += __shfl_xor(acc.x, ofs);
        acc.y += __shfl_xor(acc.y, ofs);
        acc.z += __shfl_xor(acc.z, ofs);
        acc.w += __shfl_xor(acc.w, ofs);
        dsum  += __shfl_xor(dsum, ofs);
    }

    if (g == 0) {
        float inv = 1.f / (dsum + 1e-16f);
        const float4 bq = reinterpret_cast<const float4*>(bias1)[q];
        float4 r;
        r.x = acc.x * inv + bq.x;
        r.y = acc.y * inv + bq.y;
        r.z = acc.z * inv + bq.z;
        r.w = acc.w * inv + bq.w;
        r.x = (r.x > 0.f) ? r.x : (__expf(r.x) - 1.f);
        r.y = (r.y > 0.f) ? r.y : (__expf(r.y) - 1.f);
        r.z = (r.z > 0.f) ? r.z : (__expf(r.z) - 1.f);
        r.w = (r.w > 0.f) ? r.w : (__expf(r.w) - 1.f);
        reinterpret_cast<float4*>(h1o)[dst * 16 + q] = r;
    }
}

// ---------------- K6: h2 = h1o @ W2 (+ alpha2 reductions). 32 lanes per node.
__global__ __launch_bounds__(256) void k_gemm2(
    const float* __restrict__ h1o, const float* __restrict__ W2,
    const float* __restrict__ aS, const float* __restrict__ aD,
    float* __restrict__ h2, float* __restrict__ as2, float* __restrict__ ad2) {
    int c = threadIdx.x & 31;
    int n = blockIdx.x * 8 + (threadIdx.x >> 5);
    if (n >= NN) return;
    const float4* hf = reinterpret_cast<const float4*>(h1o + n * 64);
    float acc = 0.f;
#pragma unroll
    for (int k4 = 0; k4 < 16; ++k4) {
        float4 hv = hf[k4];
        acc += hv.x * W2[(k4 * 4 + 0) * 32 + c] + hv.y * W2[(k4 * 4 + 1) * 32 + c] +
               hv.z * W2[(k4 * 4 + 2) * 32 + c] + hv.w * W2[(k4 * 4 + 3) * 32 + c];
    }
    h2[n * 32 + c] = acc;
    float ps = acc * aS[c], pd = acc * aD[c];
#pragma unroll
    for (int o = 1; o < 32; o <<= 1) { ps += __shfl_xor(ps, o); pd += __shfl_xor(pd, o); }
    if (c == 0) { as2[n] = ps; ad2[n] = pd; }
}

// ---------------- K7: layer-2 aggregation. Wave per dst; lane = (slot g = l>>3, f4 q = l&7).
__global__ __launch_bounds__(256) void k_agg2(
    const int* __restrict__ offs, const int* __restrict__ csr,
    const float* __restrict__ h2, const float* __restrict__ as2, const float* __restrict__ ad2,
    const float* __restrict__ bias2, float* __restrict__ o2) {
    int l = threadIdx.x & 63;
    int dst = blockIdx.x * 4 + (threadIdx.x >> 6);
    if (dst >= NN) return;
    int g = l >> 3;            // edge slot 0..7
    int q = l & 7;             // float4 index in 32-ch row
    int beg = offs[dst], end = offs[dst + 1];
    int lastj = end - 1;
    float adh = ad2[dst];
    const float4* __restrict__ h2f = reinterpret_cast<const float4*>(h2);

    float4 acc = make_float4(0.f, 0.f, 0.f, 0.f);
    float dsum = 0.f;

    int sA[4], sB[4];
#pragma unroll
    for (int p = 0; p < 4; ++p) sA[p] = csr[min(beg + p * 8 + g, lastj)];
    for (int j = beg; j < end; j += 32) {
#pragma unroll
        for (int p = 0; p < 4; ++p) sB[p] = csr[min(j + 32 + p * 8 + g, lastj)];
        float av[4]; float4 vv[4];
#pragma unroll
        for (int p = 0; p < 4; ++p) {
            av[p] = as2[sA[p]];
            vv[p] = h2f[sA[p] * 8 + q];
        }
#pragma unroll
        for (int p = 0; p < 4; ++p) {
            float e = av[p] + adh; e = (e > 0.f) ? e : 0.2f * e;
            float w = __expf(e);
            w = (j + p * 8 + g < end) ? w : 0.f;
            acc.x += w * vv[p].x; acc.y += w * vv[p].y;
            acc.z += w * vv[p].z; acc.w += w * vv[p].w;
            dsum += w;
        }
#pragma unroll
        for (int p = 0; p < 4; ++p) sA[p] = sB[p];
    }

#pragma unroll
    for (int ofs = 8; ofs <= 32; ofs <<= 1) {
        acc.x += __shfl_xor(acc.x, ofs);
        acc.y += __shfl_xor(acc.y, ofs);
        acc.z += __shfl_xor(acc.z, ofs);
        acc.w += __shfl_xor(acc.w, ofs);
        dsum  += __shfl_xor(dsum, ofs);
    }

    if (g == 0) {
        float inv = 1.f / (dsum + 1e-16f);
        const float4 bq = reinterpret_cast<const float4*>(bias2)[q];
        float4 r;
        r.x = acc.x * inv + bq.x;
        r.y = acc.y * inv + bq.y;
        r.z = acc.z * inv + bq.z;
        r.w = acc.w * inv + bq.w;
        reinterpret_cast<float4*>(o2)[dst * 8 + q] = r;
    }
}

// ---------------- K8: graph boundaries from sorted batch.
__global__ void k_bound(const int* __restrict__ batch, int* __restrict__ lo) {
    int n = blockIdx.x * 256 + threadIdx.x;
    if (n >= NN) return;
    int b = batch[n];
    if (n == 0) {
        for (int g = 0; g <= b; ++g) lo[g] = 0;
    } else {
        int pb = batch[n - 1];
        for (int g = pb + 1; g <= b; ++g) lo[g] = n;
    }
    if (n == NN - 1) {
        for (int g = b + 1; g <= NG; ++g) lo[g] = NN;
    }
}

// ---------------- K9: pooled sums.
__global__ __launch_bounds__(256) void k_pool(const float* __restrict__ o2, const int* __restrict__ lo,
                                              float* __restrict__ pooled) {
    __shared__ float red[256];
    int g = blockIdx.x & 63, q = blockIdx.x >> 6;
    int beg = lo[g], end = lo[g + 1];
    int c = threadIdx.x & 31, row = threadIdx.x >> 5;
    float s = 0.f;
    for (int n = beg + q * 8 + row; n < end; n += 32) s += o2[n * 32 + c];
    red[threadIdx.x] = s;
    __syncthreads();
    for (int rr = 4; rr >= 1; rr >>= 1) {
        if (row < rr) red[threadIdx.x] += red[(row + rr) * 32 + c];
        __syncthreads();
    }
    if (row == 0) atomicAdd(&pooled[g * 32 + c], red[c]);
}

// ---------------- K10: mean + final linear -> out[64][2]
__global__ void k_fin(const float* __restrict__ pooled, const int* __restrict__ lo,
                      const float* __restrict__ lw, const float* __restrict__ lb,
                      float* __restrict__ out) {
    int t = threadIdx.x;
    if (t >= 128) return;
    int g = t >> 1, o = t & 1;
    int cnt = lo[g + 1] - lo[g];
    float inv = 1.f / fmaxf((float)cnt, 1.f);
    float s = 0.f;
#pragma unroll
    for (int c = 0; c < 32; ++c) s += pooled[g * 32 + c] * lw[c * 2 + o];
    out[g * 2 + o] = s * inv + lb[o];
}

// ----------------------------------------------------------------------------
extern "C" void kernel_launch(void* const* d_in, const int* in_sizes, int n_in,
                              void* d_out, int out_size, void* d_ws, size_t ws_size,
                              hipStream_t stream) {
    const float* x   = (const float*)d_in[0];
    const int*   ei  = (const int*)d_in[1];     // [2][NE]
    const int*   bat = (const int*)d_in[2];
    const float* W1  = (const float*)d_in[3];
    const float* aS1 = (const float*)d_in[4];
    const float* aD1 = (const float*)d_in[5];
    const float* b1  = (const float*)d_in[6];
    const float* W2  = (const float*)d_in[7];
    const float* aS2 = (const float*)d_in[8];
    const float* aD2 = (const float*)d_in[9];
    const float* b2  = (const float*)d_in[10];
    const float* lw  = (const float*)d_in[11];
    const float* lb  = (const float*)d_in[12];
    float* out = (float*)d_out;

    const int* esrc = ei;
    const int* edst = ei + NE;

    char* ws = (char*)d_ws;
    size_t off = 0;
    auto alloc = [&](size_t bytes) -> void* {
        off = (off + 255) & ~(size_t)255;
        void* p = ws + off;
        off += bytes;
        return p;
    };

    float* regA = (float*)alloc((size_t)NN * 64 * 4);   // h1; later reused: h2 @ 0, o2 @ NN*32
    float* h1   = regA;
    float* h2   = regA;                                  // alias (h1 dead after k_agg1)
    float* o2   = regA + (size_t)NN * 32;                // alias
    float* h1o  = (float*)alloc((size_t)NN * 64 * 4);
    float* as1  = (float*)alloc((size_t)NN * 8 * 4);
    float* ad1  = (float*)alloc((size_t)NN * 8 * 4);
    float* as2  = (float*)alloc((size_t)NN * 4);
    float* ad2  = (float*)alloc((size_t)NN * 4);
    int*   offs = (int*)alloc((size_t)(NN + 1) * 4);
    int*   deg  = (int*)alloc((size_t)NN * 4);
    int*   csr  = (int*)alloc((size_t)ET * 4);
    uint2* rec  = (uint2*)alloc((size_t)ET * 8);
    int*   bdeg = (int*)alloc((size_t)NB * 4);
    int*   bo   = (int*)alloc((size_t)(NB + 1) * 4);
    int*   bcur = (int*)alloc((size_t)NB * 4);
    float* Wt2  = (float*)alloc((size_t)512 * 64 * 4);
    int*   bsum = (int*)alloc(256 * 4);
    int*   bpre = (int*)alloc(256 * 4);
    float* pooled = (float*)alloc((size_t)NG * 32 * 4);
    int*   lo   = (int*)alloc((size_t)(NG + 1) * 4);
    if (off > ws_size) return;   // workspace too small: leave d_out poisoned (visible failure)

    hipMemsetAsync(bdeg, 0, (size_t)NB * 4, stream);
    hipMemsetAsync(pooled, 0, (size_t)NG * 32 * 4, stream);

    k_wt<<<32, 256, 0, stream>>>(W1, Wt2);
    k_gemm1<<<(NN + 63) / 64, 256, 0, stream>>>(x, Wt2, aS1, aD1, h1, as1, ad1);

    k_bhist<<<BIN_BLOCKS, 256, 0, stream>>>(edst, bdeg);
    k_bscan<<<1, 512, 0, stream>>>(bdeg, bo, bcur);
    k_bin<<<BIN_BLOCKS, 256, 0, stream>>>(esrc, edst, bcur, rec);
    k_bdeg<<<NB, 256, 0, stream>>>(bo, rec, deg);
    k_scan1<<<SCAN_BLOCKS, 256, 0, stream>>>(deg, offs, bsum);
    k_scan2<<<1, 256, 0, stream>>>(bsum, bpre);
    k_scan3<<<SCAN_BLOCKS, 256, 0, stream>>>(offs, bpre);
    k_unbin<<<NB, 256, 0, stream>>>(offs, bo, rec, csr);

    k_agg1<<<(NN + 3) / 4, 256, 0, stream>>>(offs, csr, h1, as1, ad1, b1, h1o);
    k_gemm2<<<(NN + 7) / 8, 256, 0, stream>>>(h1o, W2, aS2, aD2, h2, as2, ad2);
    k_agg2<<<(NN + 3) / 4, 256, 0, stream>>>(offs, csr, h2, as2, ad2, b2, o2);

    k_bound<<<SCAN_BLOCKS, 256, 0, stream>>>(bat, lo);
    k_pool<<<NG * 4, 256, 0, stream>>>(o2, lo, pooled);
    k_fin<<<1, 128, 0, stream>>>(pooled, lo, lw, lb, out);
}

// Round 16
// 257.926 us; speedup vs baseline: 1.0616x; 1.0616x over previous
//
#include <hip/hip_runtime.h>
#include <cstdint>
#include <cstddef>

#define NN 50000
#define NE 1600000
#define ET (NE + NN)          // edges + self loops
#define NG 64
#define SCAN_BLOCKS ((NN + 255) / 256)   // 196
#define NB ((NN + 127) >> 7)             // 391 dst-buckets, 128 nodes each
#define EPT 16
#define EPB (256 * EPT)                  // 4096 edges per bin-block
#define BIN_BLOCKS ((ET + EPB - 1) / EPB)

// ---------------- K0: transpose W1 [512][64] -> Wt2 k-packed float4
__global__ void k_wt(const float* __restrict__ W1, float* __restrict__ Wt2) {
    int id = blockIdx.x * 256 + threadIdx.x;
    if (id >= 128 * 64) return;
    int k4 = id >> 6, c = id & 63;
    float4 v;
    v.x = W1[(k4 * 4 + 0) * 64 + c];
    v.y = W1[(k4 * 4 + 1) * 64 + c];
    v.z = W1[(k4 * 4 + 2) * 64 + c];
    v.w = W1[(k4 * 4 + 3) * 64 + c];
    reinterpret_cast<float4*>(Wt2)[id] = v;
}

// ---------------- K1: h1 = x @ W1, full-K, 64 rows/block, 32KB LDS, 8 phases
// (r13 structure — best measured), with fused as1/ad1 epilogue (r14-verified).
__global__ __launch_bounds__(256, 8) void k_gemm1(
    const float* __restrict__ x, const float* __restrict__ Wt2,
    const float* __restrict__ aS, const float* __restrict__ aD,
    float* __restrict__ h1, float* __restrict__ as1, float* __restrict__ ad1) {
    __shared__ float4 xs[64 * 16];    // 16 KB
    __shared__ float4 wsr[16 * 64];   // 16 KB

    int t = threadIdx.x;
    int lane = t & 63, wv_id = t >> 6;
    int n0 = blockIdx.x * 64;

    const float4* __restrict__ xf = reinterpret_cast<const float4*>(x);
    const float4* __restrict__ wf = reinterpret_cast<const float4*>(Wt2);

    int tc = t & 15;
    int trg = t >> 4;
    int swz = (trg & 3) << 1;

    float acc[4][4];
#pragma unroll
    for (int i = 0; i < 4; ++i)
#pragma unroll
        for (int j = 0; j < 4; ++j) acc[i][j] = 0.f;

    for (int ph = 0; ph < 8; ++ph) {
        int kb4 = ph * 16;
#pragma unroll
        for (int q = 0; q < 4; ++q) {
            int base = (wv_id * 4 + q) * 64;
            int s = base + lane;
            int row = s >> 4;
            int m = s & 15;
            int k4f = m ^ ((row & 3) << 1);
            int rr = n0 + row; if (rr >= NN) rr = NN - 1;
            const float4* src = xf + (size_t)rr * 128 + kb4 + k4f;
            __builtin_amdgcn_global_load_lds(
                (const __attribute__((address_space(1))) void*)src,
                (__attribute__((address_space(3))) void*)&xs[base], 16, 0, 0);
        }
#pragma unroll
        for (int q = 0; q < 4; ++q) {
            int base = (wv_id * 4 + q) * 64;
            int s = base + lane;
            int k4 = s >> 6, c = s & 63;
            const float4* src = wf + (size_t)(kb4 + k4) * 64 + c;
            __builtin_amdgcn_global_load_lds(
                (const __attribute__((address_space(1))) void*)src,
                (__attribute__((address_space(3))) void*)&wsr[base], 16, 0, 0);
        }
        __syncthreads();

#pragma unroll 2
        for (int k4 = 0; k4 < 16; ++k4) {
            float4 wv0 = wsr[k4 * 64 + tc];
            float4 wv1 = wsr[k4 * 64 + tc + 16];
            float4 wv2 = wsr[k4 * 64 + tc + 32];
            float4 wv3 = wsr[k4 * 64 + tc + 48];
            int kx = k4 ^ swz;
            float4 xv0 = xs[(trg +  0) * 16 + kx];
            float4 xv1 = xs[(trg + 16) * 16 + kx];
            float4 xv2 = xs[(trg + 32) * 16 + kx];
            float4 xv3 = xs[(trg + 48) * 16 + kx];
#define FMA4(a, xv, wv) { a += xv.x * wv.x; a += xv.y * wv.y; a += xv.z * wv.z; a += xv.w * wv.w; }
            FMA4(acc[0][0], xv0, wv0) FMA4(acc[0][1], xv0, wv1) FMA4(acc[0][2], xv0, wv2) FMA4(acc[0][3], xv0, wv3)
            FMA4(acc[1][0], xv1, wv0) FMA4(acc[1][1], xv1, wv1) FMA4(acc[1][2], xv1, wv2) FMA4(acc[1][3], xv1, wv3)
            FMA4(acc[2][0], xv2, wv0) FMA4(acc[2][1], xv2, wv1) FMA4(acc[2][2], xv2, wv2) FMA4(acc[2][3], xv2, wv3)
            FMA4(acc[3][0], xv3, wv0) FMA4(acc[3][1], xv3, wv1) FMA4(acc[3][2], xv3, wv2) FMA4(acc[3][3], xv3, wv3)
#undef FMA4
        }
        __syncthreads();
    }

    // epilogue: store h1 (cols tc+16j) + fused as1/ad1 (8-lane shfl reduce)
    int hb = tc >> 3;        // 0/1: heads 2j+hb
    int cc = tc & 7;         // channel within head
#pragma unroll
    for (int i = 0; i < 4; ++i) {
        int r = n0 + trg + 16 * i;
        if (r >= NN) continue;
        float* rowp = h1 + (size_t)r * 64 + tc;
        rowp[0]  = acc[i][0];
        rowp[16] = acc[i][1];
        rowp[32] = acc[i][2];
        rowp[48] = acc[i][3];

        float ps[4], pd[4];
#pragma unroll
        for (int j = 0; j < 4; ++j) {
            int h = 2 * j + hb;
            ps[j] = acc[i][j] * aS[h * 8 + cc];
            pd[j] = acc[i][j] * aD[h * 8 + cc];
        }
#pragma unroll
        for (int ofs = 1; ofs <= 4; ofs <<= 1) {
#pragma unroll
            for (int j = 0; j < 4; ++j) {
                ps[j] += __shfl_xor(ps[j], ofs);
                pd[j] += __shfl_xor(pd[j], ofs);
            }
        }
        if (cc == 0) {
#pragma unroll
            for (int j = 0; j < 4; ++j) {
                int h = 2 * j + hb;
                as1[r * 8 + h] = ps[j];
                ad1[r * 8 + h] = pd[j];
            }
        }
    }
}

// ---------------- CSR build: bhist -> bscan -> bin -> unbin2 (fused deg/scan/scatter)
__global__ __launch_bounds__(256) void k_bhist(const int* __restrict__ edst, int* __restrict__ bdeg) {
    __shared__ int cnt[NB];
    int tid = threadIdx.x;
    for (int b = tid; b < NB; b += 256) cnt[b] = 0;
    __syncthreads();
    int e0 = blockIdx.x * EPB;
#pragma unroll
    for (int q = 0; q < EPT; ++q) {
        int e = e0 + q * 256 + tid;
        if (e < ET) {
            int d = (e < NE) ? edst[e] : (e - NE);
            atomicAdd(&cnt[d >> 7], 1);
        }
    }
    __syncthreads();
    for (int b = tid; b < NB; b += 256)
        if (cnt[b]) atomicAdd(&bdeg[b], cnt[b]);
}

__global__ __launch_bounds__(512) void k_bscan(const int* __restrict__ bdeg,
                                               int* __restrict__ bo, int* __restrict__ bcur) {
    __shared__ int lds_w[8];
    int tid = threadIdx.x;
    int lane = tid & 63, wid = tid >> 6;
    int v = (tid < NB) ? bdeg[tid] : 0;
    int incl = v;
#pragma unroll
    for (int ofs = 1; ofs < 64; ofs <<= 1) {
        int o = __shfl_up(incl, ofs);
        if (lane >= ofs) incl += o;
    }
    if (lane == 63) lds_w[wid] = incl;
    __syncthreads();
    int wadd = 0;
    for (int w = 0; w < wid; ++w) wadd += lds_w[w];
    incl += wadd;
    int ex = incl - v;
    if (tid < NB) { bo[tid] = ex; bcur[tid] = ex; }
    if (tid == NB - 1) bo[NB] = ex + v;   // == ET
}

// bin: block-aggregated bucket scatter; rec packed u32 = (src<<7)|(dst&127)
__global__ __launch_bounds__(256) void k_bin(
    const int* __restrict__ esrc, const int* __restrict__ edst,
    int* __restrict__ bcur, unsigned* __restrict__ rec) {
    __shared__ int bcnt[NB];
    int tid = threadIdx.x;
    for (int b = tid; b < NB; b += 256) bcnt[b] = 0;
    __syncthreads();
    int e0 = blockIdx.x * EPB;
    unsigned rv[EPT]; int bk[EPT]; int rk[EPT];
#pragma unroll
    for (int q = 0; q < EPT; ++q) {
        int e = e0 + q * 256 + tid;
        rk[q] = -1;
        if (e < ET) {
            int s, d;
            if (e < NE) { s = esrc[e]; d = edst[e]; } else { s = d = e - NE; }
            rv[q] = ((unsigned)s << 7) | (unsigned)(d & 127);
            bk[q] = d >> 7;
            rk[q] = atomicAdd(&bcnt[bk[q]], 1);
        }
    }
    __syncthreads();
    for (int b = tid; b < NB; b += 256)
        bcnt[b] = atomicAdd(&bcur[b], bcnt[b]);
    __syncthreads();
#pragma unroll
    for (int q = 0; q < EPT; ++q) {
        if (rk[q] >= 0) rec[bcnt[bk[q]] + rk[q]] = rv[q];
    }
}

// unbin2: one block per bucket. Pass A: LDS degree count + 128-wide scan -> offs + lcur.
// Pass B: scatter csr via LDS cursors. Replaces bdeg + scan1/2/3 + unbin.
__global__ __launch_bounds__(256) void k_unbin2(
    const int* __restrict__ bo, const unsigned* __restrict__ rec,
    int* __restrict__ offs, int* __restrict__ csr) {
    __shared__ int cnt[128];
    __shared__ int lcur[128];
    int b = blockIdx.x, tid = threadIdx.x;
    if (tid < 128) cnt[tid] = 0;
    __syncthreads();
    int lo = bo[b], hi = bo[b + 1];
    for (int i = lo + tid; i < hi; i += 256)
        atomicAdd(&cnt[rec[i] & 127], 1);
    __syncthreads();
    int v = 0, incl = 0;
    if (tid < 128) {
        int lane = tid & 63;
        v = cnt[tid];
        incl = v;
#pragma unroll
        for (int ofs = 1; ofs < 64; ofs <<= 1) {
            int o = __shfl_up(incl, ofs);
            if (lane >= ofs) incl += o;
        }
        cnt[tid] = incl;   // inclusive scan within own 64-wide half
    }
    __syncthreads();
    if (tid < 128) {
        int ex = incl - v + ((tid >= 64) ? cnt[63] : 0);
        int n = (b << 7) + tid;
        int base = lo + ex;
        if (n < NN) offs[n] = base;
        lcur[tid] = base;
        if (n == NN - 1 || (b == NB - 1 && tid == 127)) offs[NN] = ET;
    }
    __syncthreads();
    for (int i = lo + tid; i < hi; i += 256) {
        unsigned r = rec[i];
        int pos = atomicAdd(&lcur[r & 127], 1);
        csr[pos] = (int)(r >> 7);
    }
}

// ---------------- K4: layer-1 aggregation. Wave per dst; lane = (slot g = l>>4, f4 q = l&15).
__global__ __launch_bounds__(256) void k_agg1(
    const int* __restrict__ offs, const int* __restrict__ csr,
    const float* __restrict__ h1, const float* __restrict__ as1, const float* __restrict__ ad1,
    const float* __restrict__ bias1, float* __restrict__ h1o) {
    int l = threadIdx.x & 63;
    int dst = blockIdx.x * 4 + (threadIdx.x >> 6);
    if (dst >= NN) return;
    int g = l >> 4;            // edge slot 0..3
    int q = l & 15;            // float4 index in 64-ch row
    int h = q >> 1;            // head
    int beg = offs[dst], end = offs[dst + 1];
    int lastj = end - 1;       // deg >= 1 (self-loop)
    float adh = ad1[dst * 8 + h];
    const float4* __restrict__ h1f = reinterpret_cast<const float4*>(h1);

    float4 acc = make_float4(0.f, 0.f, 0.f, 0.f);
    float dsum = 0.f;

    int sA[4], sB[4];
#pragma unroll
    for (int p = 0; p < 4; ++p) sA[p] = csr[min(beg + p * 4 + g, lastj)];
    for (int j = beg; j < end; j += 16) {
#pragma unroll
        for (int p = 0; p < 4; ++p) sB[p] = csr[min(j + 16 + p * 4 + g, lastj)];
        float av[4]; float4 vv[4];
#pragma unroll
        for (int p = 0; p < 4; ++p) {
            av[p] = as1[sA[p] * 8 + h];
            vv[p] = h1f[sA[p] * 16 + q];
        }
#pragma unroll
        for (int p = 0; p < 4; ++p) {
            float e = av[p] + adh; e = (e > 0.f) ? e : 0.2f * e;
            float w = __expf(e);
            w = (j + p * 4 + g < end) ? w : 0.f;
            acc.x += w * vv[p].x; acc.y += w * vv[p].y;
            acc.z += w * vv[p].z; acc.w += w * vv[p].w;
            dsum += w;
        }
#pragma unroll
        for (int p = 0; p < 4; ++p) sA[p] = sB[p];
    }

#pragma unroll
    for (int ofs = 16; ofs <= 32; ofs <<= 1) {
        acc.x += __shfl_xor(acc.x, ofs);
        acc.y += __shfl_xor(acc.y, ofs);
        acc.z += __shfl_xor(acc.z, ofs);
        acc.w += __shfl_xor(acc.w, ofs);
        dsum  += __shfl_xor(dsum, ofs);
    }

    if (g == 0) {
        float inv = 1.f / (dsum + 1e-16f);
        const float4 bq = reinterpret_cast<const float4*>(bias1)[q];
        float4 r;
        r.x = acc.x * inv + bq.x;
        r.y = acc.y * inv + bq.y;
        r.z = acc.z * inv + bq.z;
        r.w = acc.w * inv + bq.w;
        r.x = (r.x > 0.f) ? r.x : (__expf(r.x) - 1.f);
        r.y = (r.y > 0.f) ? r.y : (__expf(r.y) - 1.f);
        r.z = (r.z > 0.f) ? r.z : (__expf(r.z) - 1.f);
        r.w = (r.w > 0.f) ? r.w : (__expf(r.w) - 1.f);
        reinterpret_cast<float4*>(h1o)[dst * 16 + q] = r;
    }
}

// ---------------- K6: h2 = h1o @ W2 (+ alpha2 reductions). 32 lanes per node.
__global__ __launch_bounds__(256) void k_gemm2(
    const float* __restrict__ h1o, const float* __restrict__ W2,
    const float* __restrict__ aS, const float* __restrict__ aD,
    float* __restrict__ h2, float* __restrict__ as2, float* __restrict__ ad2) {
    int c = threadIdx.x & 31;
    int n = blockIdx.x * 8 + (threadIdx.x >> 5);
    if (n >= NN) return;
    const float4* hf = reinterpret_cast<const float4*>(h1o + n * 64);
    float acc = 0.f;
#pragma unroll
    for (int k4 = 0; k4 < 16; ++k4) {
        float4 hv = hf[k4];
        acc += hv.x * W2[(k4 * 4 + 0) * 32 + c] + hv.y * W2[(k4 * 4 + 1) * 32 + c] +
               hv.z * W2[(k4 * 4 + 2) * 32 + c] + hv.w * W2[(k4 * 4 + 3) * 32 + c];
    }
    h2[n * 32 + c] = acc;
    float ps = acc * aS[c], pd = acc * aD[c];
#pragma unroll
    for (int o = 1; o < 32; o <<= 1) { ps += __shfl_xor(ps, o); pd += __shfl_xor(pd, o); }
    if (c == 0) { as2[n] = ps; ad2[n] = pd; }
}

// ---------------- K7: layer-2 aggregation. Wave per dst; lane = (slot g = l>>3, f4 q = l&7).
__global__ __launch_bounds__(256) void k_agg2(
    const int* __restrict__ offs, const int* __restrict__ csr,
    const float* __restrict__ h2, const float* __restrict__ as2, const float* __restrict__ ad2,
    const float* __restrict__ bias2, float* __restrict__ o2) {
    int l = threadIdx.x & 63;
    int dst = blockIdx.x * 4 + (threadIdx.x >> 6);
    if (dst >= NN) return;
    int g = l >> 3;            // edge slot 0..7
    int q = l & 7;             // float4 index in 32-ch row
    int beg = offs[dst], end = offs[dst + 1];
    int lastj = end - 1;
    float adh = ad2[dst];
    const float4* __restrict__ h2f = reinterpret_cast<const float4*>(h2);

    float4 acc = make_float4(0.f, 0.f, 0.f, 0.f);
    float dsum = 0.f;

    int sA[4], sB[4];
#pragma unroll
    for (int p = 0; p < 4; ++p) sA[p] = csr[min(beg + p * 8 + g, lastj)];
    for (int j = beg; j < end; j += 32) {
#pragma unroll
        for (int p = 0; p < 4; ++p) sB[p] = csr[min(j + 32 + p * 8 + g, lastj)];
        float av[4]; float4 vv[4];
#pragma unroll
        for (int p = 0; p < 4; ++p) {
            av[p] = as2[sA[p]];
            vv[p] = h2f[sA[p] * 8 + q];
        }
#pragma unroll
        for (int p = 0; p < 4; ++p) {
            float e = av[p] + adh; e = (e > 0.f) ? e : 0.2f * e;
            float w = __expf(e);
            w = (j + p * 8 + g < end) ? w : 0.f;
            acc.x += w * vv[p].x; acc.y += w * vv[p].y;
            acc.z += w * vv[p].z; acc.w += w * vv[p].w;
            dsum += w;
        }
#pragma unroll
        for (int p = 0; p < 4; ++p) sA[p] = sB[p];
    }

#pragma unroll
    for (int ofs = 8; ofs <= 32; ofs <<= 1) {
        acc.x += __shfl_xor(acc.x, ofs);
        acc.y += __shfl_xor(acc.y, ofs);
        acc.z += __shfl_xor(acc.z, ofs);
        acc.w += __shfl_xor(acc.w, ofs);
        dsum  += __shfl_xor(dsum, ofs);
    }

    if (g == 0) {
        float inv = 1.f / (dsum + 1e-16f);
        const float4 bq = reinterpret_cast<const float4*>(bias2)[q];
        float4 r;
        r.x = acc.x * inv + bq.x;
        r.y = acc.y * inv + bq.y;
        r.z = acc.z * inv + bq.z;
        r.w = acc.w * inv + bq.w;
        reinterpret_cast<float4*>(o2)[dst * 8 + q] = r;
    }
}

// ---------------- K8: graph boundaries from sorted batch.
__global__ void k_bound(const int* __restrict__ batch, int* __restrict__ lo) {
    int n = blockIdx.x * 256 + threadIdx.x;
    if (n >= NN) return;
    int b = batch[n];
    if (n == 0) {
        for (int g = 0; g <= b; ++g) lo[g] = 0;
    } else {
        int pb = batch[n - 1];
        for (int g = pb + 1; g <= b; ++g) lo[g] = n;
    }
    if (n == NN - 1) {
        for (int g = b + 1; g <= NG; ++g) lo[g] = NN;
    }
}

// ---------------- K9: pooled sums.
__global__ __launch_bounds__(256) void k_pool(const float* __restrict__ o2, const int* __restrict__ lo,
                                              float* __restrict__ pooled) {
    __shared__ float red[256];
    int g = blockIdx.x & 63, q = blockIdx.x >> 6;
    int beg = lo[g], end = lo[g + 1];
    int c = threadIdx.x & 31, row = threadIdx.x >> 5;
    float s = 0.f;
    for (int n = beg + q * 8 + row; n < end; n += 32) s += o2[n * 32 + c];
    red[threadIdx.x] = s;
    __syncthreads();
    for (int rr = 4; rr >= 1; rr >>= 1) {
        if (row < rr) red[threadIdx.x] += red[(row + rr) * 32 + c];
        __syncthreads();
    }
    if (row == 0) atomicAdd(&pooled[g * 32 + c], red[c]);
}

// ---------------- K10: mean + final linear -> out[64][2]
__global__ void k_fin(const float* __restrict__ pooled, const int* __restrict__ lo,
                      const float* __restrict__ lw, const float* __restrict__ lb,
                      float* __restrict__ out) {
    int t = threadIdx.x;
    if (t >= 128) return;
    int g = t >> 1, o = t & 1;
    int cnt = lo[g + 1] - lo[g];
    float inv = 1.f / fmaxf((float)cnt, 1.f);
    float s = 0.f;
#pragma unroll
    for (int c = 0; c < 32; ++c) s += pooled[g * 32 + c] * lw[c * 2 + o];
    out[g * 2 + o] = s * inv + lb[o];
}

// ----------------------------------------------------------------------------
extern "C" void kernel_launch(void* const* d_in, const int* in_sizes, int n_in,
                              void* d_out, int out_size, void* d_ws, size_t ws_size,
                              hipStream_t stream) {
    const float* x   = (const float*)d_in[0];
    const int*   ei  = (const int*)d_in[1];     // [2][NE]
    const int*   bat = (const int*)d_in[2];
    const float* W1  = (const float*)d_in[3];
    const float* aS1 = (const float*)d_in[4];
    const float* aD1 = (const float*)d_in[5];
    const float* b1  = (const float*)d_in[6];
    const float* W2  = (const float*)d_in[7];
    const float* aS2 = (const float*)d_in[8];
    const float* aD2 = (const float*)d_in[9];
    const float* b2  = (const float*)d_in[10];
    const float* lw  = (const float*)d_in[11];
    const float* lb  = (const float*)d_in[12];
    float* out = (float*)d_out;

    const int* esrc = ei;
    const int* edst = ei + NE;

    char* ws = (char*)d_ws;
    size_t off = 0;
    auto alloc = [&](size_t bytes) -> void* {
        off = (off + 255) & ~(size_t)255;
        void* p = ws + off;
        off += bytes;
        return p;
    };

    float* regA = (float*)alloc((size_t)NN * 64 * 4);   // h1; later reused: h2 @ 0, o2 @ NN*32
    float* h1   = regA;
    float* h2   = regA;                                  // alias (h1 dead after k_agg1)
    float* o2   = regA + (size_t)NN * 32;                // alias
    float* h1o  = (float*)alloc((size_t)NN * 64 * 4);
    float* as1  = (float*)alloc((size_t)NN * 8 * 4);
    float* ad1  = (float*)alloc((size_t)NN * 8 * 4);
    float* as2  = (float*)alloc((size_t)NN * 4);
    float* ad2  = (float*)alloc((size_t)NN * 4);
    int*   offs = (int*)alloc((size_t)(NN + 1) * 4);
    int*   csr  = (int*)alloc((size_t)ET * 4);
    unsigned* rec = (unsigned*)alloc((size_t)ET * 4);
    int*   bdeg = (int*)alloc((size_t)NB * 4);
    int*   bo   = (int*)alloc((size_t)(NB + 1) * 4);
    int*   bcur = (int*)alloc((size_t)NB * 4);
    float* Wt2  = (float*)alloc((size_t)512 * 64 * 4);
    float* pooled = (float*)alloc((size_t)NG * 32 * 4);
    int*   lo   = (int*)alloc((size_t)(NG + 1) * 4);
    if (off > ws_size) return;   // workspace too small: leave d_out poisoned (visible failure)

    hipMemsetAsync(bdeg, 0, (size_t)NB * 4, stream);
    hipMemsetAsync(pooled, 0, (size_t)NG * 32 * 4, stream);

    k_wt<<<32, 256, 0, stream>>>(W1, Wt2);
    k_gemm1<<<(NN + 63) / 64, 256, 0, stream>>>(x, Wt2, aS1, aD1, h1, as1, ad1);

    k_bhist<<<BIN_BLOCKS, 256, 0, stream>>>(edst, bdeg);
    k_bscan<<<1, 512, 0, stream>>>(bdeg, bo, bcur);
    k_bin<<<BIN_BLOCKS, 256, 0, stream>>>(esrc, edst, bcur, rec);
    k_unbin2<<<NB, 256, 0, stream>>>(bo, rec, offs, csr);

    k_agg1<<<(NN + 3) / 4, 256, 0, stream>>>(offs, csr, h1, as1, ad1, b1, h1o);
    k_gemm2<<<(NN + 7) / 8, 256, 0, stream>>>(h1o, W2, aS2, aD2, h2, as2, ad2);
    k_agg2<<<(NN + 3) / 4, 256, 0, stream>>>(offs, csr, h2, as2, ad2, b2, o2);

    k_bound<<<SCAN_BLOCKS, 256, 0, stream>>>(bat, lo);
    k_pool<<<NG * 4, 256, 0, stream>>>(o2, lo, pooled);
    k_fin<<<1, 128, 0, stream>>>(pooled, lo, lw, lb, out);
}

// Round 17
// 231.609 us; speedup vs baseline: 1.1822x; 1.1136x over previous
//
#include <hip/hip_runtime.h>
#include <cstdint>
#include <cstddef>

#define NN 50000
#define NE 1600000
#define ET (NE + NN)          // edges + self loops
#define NG 64
#define SCAN_BLOCKS ((NN + 255) / 256)   // 196
#define NB ((NN + 127) >> 7)             // 391 dst-buckets, 128 nodes each
#define EPT 16
#define EPB (256 * EPT)                  // 4096 edges per bin-block
#define BIN_BLOCKS ((ET + EPB - 1) / EPB)
#define GEMM1_BLOCKS ((NN + 63) / 64)    // 782

// ---------------- F0: wt (32 blocks) || bhist (403) || bound (196)
__global__ __launch_bounds__(256) void k_f0(
    const float* __restrict__ W1, float* __restrict__ Wt2,
    const int* __restrict__ edst, int* __restrict__ bdeg,
    const int* __restrict__ batch, int* __restrict__ lo) {
    __shared__ int cnt[NB];
    int bid = blockIdx.x, tid = threadIdx.x;
    if (bid < 32) {
        // ---- wt: transpose W1 [512][64] -> k-packed float4
        int id = bid * 256 + tid;
        int k4 = id >> 6, c = id & 63;
        float4 v;
        v.x = W1[(k4 * 4 + 0) * 64 + c];
        v.y = W1[(k4 * 4 + 1) * 64 + c];
        v.z = W1[(k4 * 4 + 2) * 64 + c];
        v.w = W1[(k4 * 4 + 3) * 64 + c];
        reinterpret_cast<float4*>(Wt2)[id] = v;
    } else if (bid < 32 + BIN_BLOCKS) {
        // ---- bhist: bucket histogram, LDS-aggregated
        for (int b = tid; b < NB; b += 256) cnt[b] = 0;
        __syncthreads();
        int e0 = (bid - 32) * EPB;
#pragma unroll
        for (int q = 0; q < EPT; ++q) {
            int e = e0 + q * 256 + tid;
            if (e < ET) {
                int d = (e < NE) ? edst[e] : (e - NE);
                atomicAdd(&cnt[d >> 7], 1);
            }
        }
        __syncthreads();
        for (int b = tid; b < NB; b += 256)
            if (cnt[b]) atomicAdd(&bdeg[b], cnt[b]);
    } else {
        // ---- bound: graph boundaries from sorted batch
        int n = (bid - 32 - BIN_BLOCKS) * 256 + tid;
        if (n >= NN) return;
        int b = batch[n];
        if (n == 0) {
            for (int g = 0; g <= b; ++g) lo[g] = 0;
        } else {
            int pb = batch[n - 1];
            for (int g = pb + 1; g <= b; ++g) lo[g] = n;
        }
        if (n == NN - 1) {
            for (int g = b + 1; g <= NG; ++g) lo[g] = NN;
        }
    }
}

__global__ __launch_bounds__(512) void k_bscan(const int* __restrict__ bdeg,
                                               int* __restrict__ bo, int* __restrict__ bcur) {
    __shared__ int lds_w[8];
    int tid = threadIdx.x;
    int lane = tid & 63, wid = tid >> 6;
    int v = (tid < NB) ? bdeg[tid] : 0;
    int incl = v;
#pragma unroll
    for (int ofs = 1; ofs < 64; ofs <<= 1) {
        int o = __shfl_up(incl, ofs);
        if (lane >= ofs) incl += o;
    }
    if (lane == 63) lds_w[wid] = incl;
    __syncthreads();
    int wadd = 0;
    for (int w = 0; w < wid; ++w) wadd += lds_w[w];
    incl += wadd;
    int ex = incl - v;
    if (tid < NB) { bo[tid] = ex; bcur[tid] = ex; }
    if (tid == NB - 1) bo[NB] = ex + v;   // == ET
}

// ---------------- F1: gemm1 (782 blocks) || bin (403 blocks). LDS unioned (32 KB).
__global__ __launch_bounds__(256, 4) void k_f1(
    const float* __restrict__ x, const float* __restrict__ Wt2,
    const float* __restrict__ aS, const float* __restrict__ aD,
    float* __restrict__ h1, float* __restrict__ as1, float* __restrict__ ad1,
    const int* __restrict__ esrc, const int* __restrict__ edst,
    int* __restrict__ bcur, unsigned* __restrict__ rec) {
    __shared__ float4 smem4[2048];    // 32 KB: gemm1 {xs[1024], wsr[1024]} | bin {bcnt[NB]}
    int bid = blockIdx.x, t = threadIdx.x;

    if (bid < GEMM1_BLOCKS) {
        // ======== gemm1: h1 = x @ W1, full-K, 64 rows/block, 8 LDS phases ========
        float4* xs  = smem4;
        float4* wsr = smem4 + 1024;
        int lane = t & 63, wv_id = t >> 6;
        int n0 = bid * 64;

        const float4* __restrict__ xf = reinterpret_cast<const float4*>(x);
        const float4* __restrict__ wf = reinterpret_cast<const float4*>(Wt2);

        int tc = t & 15;
        int trg = t >> 4;
        int swz = (trg & 3) << 1;

        float acc[4][4];
#pragma unroll
        for (int i = 0; i < 4; ++i)
#pragma unroll
            for (int j = 0; j < 4; ++j) acc[i][j] = 0.f;

        for (int ph = 0; ph < 8; ++ph) {
            int kb4 = ph * 16;
#pragma unroll
            for (int q = 0; q < 4; ++q) {
                int base = (wv_id * 4 + q) * 64;
                int s = base + lane;
                int row = s >> 4;
                int m = s & 15;
                int k4f = m ^ ((row & 3) << 1);
                int rr = n0 + row; if (rr >= NN) rr = NN - 1;
                const float4* src = xf + (size_t)rr * 128 + kb4 + k4f;
                __builtin_amdgcn_global_load_lds(
                    (const __attribute__((address_space(1))) void*)src,
                    (__attribute__((address_space(3))) void*)&xs[base], 16, 0, 0);
            }
#pragma unroll
            for (int q = 0; q < 4; ++q) {
                int base = (wv_id * 4 + q) * 64;
                int s = base + lane;
                int k4 = s >> 6, c = s & 63;
                const float4* src = wf + (size_t)(kb4 + k4) * 64 + c;
                __builtin_amdgcn_global_load_lds(
                    (const __attribute__((address_space(1))) void*)src,
                    (__attribute__((address_space(3))) void*)&wsr[base], 16, 0, 0);
            }
            __syncthreads();

#pragma unroll 2
            for (int k4 = 0; k4 < 16; ++k4) {
                float4 wv0 = wsr[k4 * 64 + tc];
                float4 wv1 = wsr[k4 * 64 + tc + 16];
                float4 wv2 = wsr[k4 * 64 + tc + 32];
                float4 wv3 = wsr[k4 * 64 + tc + 48];
                int kx = k4 ^ swz;
                float4 xv0 = xs[(trg +  0) * 16 + kx];
                float4 xv1 = xs[(trg + 16) * 16 + kx];
                float4 xv2 = xs[(trg + 32) * 16 + kx];
                float4 xv3 = xs[(trg + 48) * 16 + kx];
#define FMA4(a, xv, wv) { a += xv.x * wv.x; a += xv.y * wv.y; a += xv.z * wv.z; a += xv.w * wv.w; }
                FMA4(acc[0][0], xv0, wv0) FMA4(acc[0][1], xv0, wv1) FMA4(acc[0][2], xv0, wv2) FMA4(acc[0][3], xv0, wv3)
                FMA4(acc[1][0], xv1, wv0) FMA4(acc[1][1], xv1, wv1) FMA4(acc[1][2], xv1, wv2) FMA4(acc[1][3], xv1, wv3)
                FMA4(acc[2][0], xv2, wv0) FMA4(acc[2][1], xv2, wv1) FMA4(acc[2][2], xv2, wv2) FMA4(acc[2][3], xv2, wv3)
                FMA4(acc[3][0], xv3, wv0) FMA4(acc[3][1], xv3, wv1) FMA4(acc[3][2], xv3, wv2) FMA4(acc[3][3], xv3, wv3)
#undef FMA4
            }
            __syncthreads();
        }

        // epilogue: store h1 + fused as1/ad1
        int hb = tc >> 3;
        int cc = tc & 7;
#pragma unroll
        for (int i = 0; i < 4; ++i) {
            int r = n0 + trg + 16 * i;
            if (r >= NN) continue;
            float* rowp = h1 + (size_t)r * 64 + tc;
            rowp[0]  = acc[i][0];
            rowp[16] = acc[i][1];
            rowp[32] = acc[i][2];
            rowp[48] = acc[i][3];

            float ps[4], pd[4];
#pragma unroll
            for (int j = 0; j < 4; ++j) {
                int h = 2 * j + hb;
                ps[j] = acc[i][j] * aS[h * 8 + cc];
                pd[j] = acc[i][j] * aD[h * 8 + cc];
            }
#pragma unroll
            for (int ofs = 1; ofs <= 4; ofs <<= 1) {
#pragma unroll
                for (int j = 0; j < 4; ++j) {
                    ps[j] += __shfl_xor(ps[j], ofs);
                    pd[j] += __shfl_xor(pd[j], ofs);
                }
            }
            if (cc == 0) {
#pragma unroll
                for (int j = 0; j < 4; ++j) {
                    int h = 2 * j + hb;
                    as1[r * 8 + h] = ps[j];
                    ad1[r * 8 + h] = pd[j];
                }
            }
        }
    } else {
        // ======== bin: block-aggregated bucket scatter; rec = (src<<7)|(dst&127) ========
        int* bcnt = reinterpret_cast<int*>(smem4);
        int tid = t;
        for (int b = tid; b < NB; b += 256) bcnt[b] = 0;
        __syncthreads();
        int e0 = (bid - GEMM1_BLOCKS) * EPB;
        unsigned rv[EPT]; int bk[EPT]; int rk[EPT];
#pragma unroll
        for (int q = 0; q < EPT; ++q) {
            int e = e0 + q * 256 + tid;
            rk[q] = -1;
            if (e < ET) {
                int s, d;
                if (e < NE) { s = esrc[e]; d = edst[e]; } else { s = d = e - NE; }
                rv[q] = ((unsigned)s << 7) | (unsigned)(d & 127);
                bk[q] = d >> 7;
                rk[q] = atomicAdd(&bcnt[bk[q]], 1);
            }
        }
        __syncthreads();
        for (int b = tid; b < NB; b += 256)
            bcnt[b] = atomicAdd(&bcur[b], bcnt[b]);
        __syncthreads();
#pragma unroll
        for (int q = 0; q < EPT; ++q) {
            if (rk[q] >= 0) rec[bcnt[bk[q]] + rk[q]] = rv[q];
        }
    }
}

// unbin2: one block per bucket. LDS degree count + scan -> offs; then scatter csr.
__global__ __launch_bounds__(256) void k_unbin2(
    const int* __restrict__ bo, const unsigned* __restrict__ rec,
    int* __restrict__ offs, int* __restrict__ csr) {
    __shared__ int cnt[128];
    __shared__ int lcur[128];
    int b = blockIdx.x, tid = threadIdx.x;
    if (tid < 128) cnt[tid] = 0;
    __syncthreads();
    int lo = bo[b], hi = bo[b + 1];
    for (int i = lo + tid; i < hi; i += 256)
        atomicAdd(&cnt[rec[i] & 127], 1);
    __syncthreads();
    int v = 0, incl = 0;
    if (tid < 128) {
        int lane = tid & 63;
        v = cnt[tid];
        incl = v;
#pragma unroll
        for (int ofs = 1; ofs < 64; ofs <<= 1) {
            int o = __shfl_up(incl, ofs);
            if (lane >= ofs) incl += o;
        }
        cnt[tid] = incl;
    }
    __syncthreads();
    if (tid < 128) {
        int ex = incl - v + ((tid >= 64) ? cnt[63] : 0);
        int n = (b << 7) + tid;
        int base = lo + ex;
        if (n < NN) offs[n] = base;
        lcur[tid] = base;
        if (n == NN - 1 || (b == NB - 1 && tid == 127)) offs[NN] = ET;
    }
    __syncthreads();
    for (int i = lo + tid; i < hi; i += 256) {
        unsigned r = rec[i];
        int pos = atomicAdd(&lcur[r & 127], 1);
        csr[pos] = (int)(r >> 7);
    }
}

// ---------------- K4: layer-1 aggregation. Wave per dst; lane = (slot g = l>>4, f4 q = l&15).
__global__ __launch_bounds__(256) void k_agg1(
    const int* __restrict__ offs, const int* __restrict__ csr,
    const float* __restrict__ h1, const float* __restrict__ as1, const float* __restrict__ ad1,
    const float* __restrict__ bias1, float* __restrict__ h1o) {
    int l = threadIdx.x & 63;
    int dst = blockIdx.x * 4 + (threadIdx.x >> 6);
    if (dst >= NN) return;
    int g = l >> 4;            // edge slot 0..3
    int q = l & 15;            // float4 index in 64-ch row
    int h = q >> 1;            // head
    int beg = offs[dst], end = offs[dst + 1];
    int lastj = end - 1;       // deg >= 1 (self-loop)
    float adh = ad1[dst * 8 + h];
    const float4* __restrict__ h1f = reinterpret_cast<const float4*>(h1);

    float4 acc = make_float4(0.f, 0.f, 0.f, 0.f);
    float dsum = 0.f;

    int sA[4], sB[4];
#pragma unroll
    for (int p = 0; p < 4; ++p) sA[p] = csr[min(beg + p * 4 + g, lastj)];
    for (int j = beg; j < end; j += 16) {
#pragma unroll
        for (int p = 0; p < 4; ++p) sB[p] = csr[min(j + 16 + p * 4 + g, lastj)];
        float av[4]; float4 vv[4];
#pragma unroll
        for (int p = 0; p < 4; ++p) {
            av[p] = as1[sA[p] * 8 + h];
            vv[p] = h1f[sA[p] * 16 + q];
        }
#pragma unroll
        for (int p = 0; p < 4; ++p) {
            float e = av[p] + adh; e = (e > 0.f) ? e : 0.2f * e;
            float w = __expf(e);
            w = (j + p * 4 + g < end) ? w : 0.f;
            acc.x += w * vv[p].x; acc.y += w * vv[p].y;
            acc.z += w * vv[p].z; acc.w += w * vv[p].w;
            dsum += w;
        }
#pragma unroll
        for (int p = 0; p < 4; ++p) sA[p] = sB[p];
    }

#pragma unroll
    for (int ofs = 16; ofs <= 32; ofs <<= 1) {
        acc.x += __shfl_xor(acc.x, ofs);
        acc.y += __shfl_xor(acc.y, ofs);
        acc.z += __shfl_xor(acc.z, ofs);
        acc.w += __shfl_xor(acc.w, ofs);
        dsum  += __shfl_xor(dsum, ofs);
    }

    if (g == 0) {
        float inv = 1.f / (dsum + 1e-16f);
        const float4 bq = reinterpret_cast<const float4*>(bias1)[q];
        float4 r;
        r.x = acc.x * inv + bq.x;
        r.y = acc.y * inv + bq.y;
        r.z = acc.z * inv + bq.z;
        r.w = acc.w * inv + bq.w;
        r.x = (r.x > 0.f) ? r.x : (__expf(r.x) - 1.f);
        r.y = (r.y > 0.f) ? r.y : (__expf(r.y) - 1.f);
        r.z = (r.z > 0.f) ? r.z : (__expf(r.z) - 1.f);
        r.w = (r.w > 0.f) ? r.w : (__expf(r.w) - 1.f);
        reinterpret_cast<float4*>(h1o)[dst * 16 + q] = r;
    }
}

// ---------------- K6: h2 = h1o @ W2 (+ alpha2 reductions). 32 lanes per node.
__global__ __launch_bounds__(256) void k_gemm2(
    const float* __restrict__ h1o, const float* __restrict__ W2,
    const float* __restrict__ aS, const float* __restrict__ aD,
    float* __restrict__ h2, float* __restrict__ as2, float* __restrict__ ad2) {
    int c = threadIdx.x & 31;
    int n = blockIdx.x * 8 + (threadIdx.x >> 5);
    if (n >= NN) return;
    const float4* hf = reinterpret_cast<const float4*>(h1o + n * 64);
    float acc = 0.f;
#pragma unroll
    for (int k4 = 0; k4 < 16; ++k4) {
        float4 hv = hf[k4];
        acc += hv.x * W2[(k4 * 4 + 0) * 32 + c] + hv.y * W2[(k4 * 4 + 1) * 32 + c] +
               hv.z * W2[(k4 * 4 + 2) * 32 + c] + hv.w * W2[(k4 * 4 + 3) * 32 + c];
    }
    h2[n * 32 + c] = acc;
    float ps = acc * aS[c], pd = acc * aD[c];
#pragma unroll
    for (int o = 1; o < 32; o <<= 1) { ps += __shfl_xor(ps, o); pd += __shfl_xor(pd, o); }
    if (c == 0) { as2[n] = ps; ad2[n] = pd; }
}

// ---------------- K7: layer-2 aggregation. Wave per dst; lane = (slot g = l>>3, f4 q = l&7).
__global__ __launch_bounds__(256) void k_agg2(
    const int* __restrict__ offs, const int* __restrict__ csr,
    const float* __restrict__ h2, const float* __restrict__ as2, const float* __restrict__ ad2,
    const float* __restrict__ bias2, float* __restrict__ o2) {
    int l = threadIdx.x & 63;
    int dst = blockIdx.x * 4 + (threadIdx.x >> 6);
    if (dst >= NN) return;
    int g = l >> 3;            // edge slot 0..7
    int q = l & 7;             // float4 index in 32-ch row
    int beg = offs[dst], end = offs[dst + 1];
    int lastj = end - 1;
    float adh = ad2[dst];
    const float4* __restrict__ h2f = reinterpret_cast<const float4*>(h2);

    float4 acc = make_float4(0.f, 0.f, 0.f, 0.f);
    float dsum = 0.f;

    int sA[4], sB[4];
#pragma unroll
    for (int p = 0; p < 4; ++p) sA[p] = csr[min(beg + p * 8 + g, lastj)];
    for (int j = beg; j < end; j += 32) {
#pragma unroll
        for (int p = 0; p < 4; ++p) sB[p] = csr[min(j + 32 + p * 8 + g, lastj)];
        float av[4]; float4 vv[4];
#pragma unroll
        for (int p = 0; p < 4; ++p) {
            av[p] = as2[sA[p]];
            vv[p] = h2f[sA[p] * 8 + q];
        }
#pragma unroll
        for (int p = 0; p < 4; ++p) {
            float e = av[p] + adh; e = (e > 0.f) ? e : 0.2f * e;
            float w = __expf(e);
            w = (j + p * 8 + g < end) ? w : 0.f;
            acc.x += w * vv[p].x; acc.y += w * vv[p].y;
            acc.z += w * vv[p].z; acc.w += w * vv[p].w;
            dsum += w;
        }
#pragma unroll
        for (int p = 0; p < 4; ++p) sA[p] = sB[p];
    }

#pragma unroll
    for (int ofs = 8; ofs <= 32; ofs <<= 1) {
        acc.x += __shfl_xor(acc.x, ofs);
        acc.y += __shfl_xor(acc.y, ofs);
        acc.z += __shfl_xor(acc.z, ofs);
        acc.w += __shfl_xor(acc.w, ofs);
        dsum  += __shfl_xor(dsum, ofs);
    }

    if (g == 0) {
        float inv = 1.f / (dsum + 1e-16f);
        const float4 bq = reinterpret_cast<const float4*>(bias2)[q];
        float4 r;
        r.x = acc.x * inv + bq.x;
        r.y = acc.y * inv + bq.y;
        r.z = acc.z * inv + bq.z;
        r.w = acc.w * inv + bq.w;
        reinterpret_cast<float4*>(o2)[dst * 8 + q] = r;
    }
}

// ---------------- K9: pooled sums.
__global__ __launch_bounds__(256) void k_pool(const float* __restrict__ o2, const int* __restrict__ lo,
                                              float* __restrict__ pooled) {
    __shared__ float red[256];
    int g = blockIdx.x & 63, q = blockIdx.x >> 6;
    int beg = lo[g], end = lo[g + 1];
    int c = threadIdx.x & 31, row = threadIdx.x >> 5;
    float s = 0.f;
    for (int n = beg + q * 8 + row; n < end; n += 32) s += o2[n * 32 + c];
    red[threadIdx.x] = s;
    __syncthreads();
    for (int rr = 4; rr >= 1; rr >>= 1) {
        if (row < rr) red[threadIdx.x] += red[(row + rr) * 32 + c];
        __syncthreads();
    }
    if (row == 0) atomicAdd(&pooled[g * 32 + c], red[c]);
}

// ---------------- K10: mean + final linear -> out[64][2]
__global__ void k_fin(const float* __restrict__ pooled, const int* __restrict__ lo,
                      const float* __restrict__ lw, const float* __restrict__ lb,
                      float* __restrict__ out) {
    int t = threadIdx.x;
    if (t >= 128) return;
    int g = t >> 1, o = t & 1;
    int cnt = lo[g + 1] - lo[g];
    float inv = 1.f / fmaxf((float)cnt, 1.f);
    float s = 0.f;
#pragma unroll
    for (int c = 0; c < 32; ++c) s += pooled[g * 32 + c] * lw[c * 2 + o];
    out[g * 2 + o] = s * inv + lb[o];
}

// ----------------------------------------------------------------------------
extern "C" void kernel_launch(void* const* d_in, const int* in_sizes, int n_in,
                              void* d_out, int out_size, void* d_ws, size_t ws_size,
                              hipStream_t stream) {
    const float* x   = (const float*)d_in[0];
    const int*   ei  = (const int*)d_in[1];     // [2][NE]
    const int*   bat = (const int*)d_in[2];
    const float* W1  = (const float*)d_in[3];
    const float* aS1 = (const float*)d_in[4];
    const float* aD1 = (const float*)d_in[5];
    const float* b1  = (const float*)d_in[6];
    const float* W2  = (const float*)d_in[7];
    const float* aS2 = (const float*)d_in[8];
    const float* aD2 = (const float*)d_in[9];
    const float* b2  = (const float*)d_in[10];
    const float* lw  = (const float*)d_in[11];
    const float* lb  = (const float*)d_in[12];
    float* out = (float*)d_out;

    const int* esrc = ei;
    const int* edst = ei + NE;

    char* ws = (char*)d_ws;
    size_t off = 0;
    auto alloc = [&](size_t bytes) -> void* {
        off = (off + 255) & ~(size_t)255;
        void* p = ws + off;
        off += bytes;
        return p;
    };

    float* regA = (float*)alloc((size_t)NN * 64 * 4);   // h1; later reused: h2 @ 0, o2 @ NN*32
    float* h1   = regA;
    float* h2   = regA;                                  // alias (h1 dead after k_agg1)
    float* o2   = regA + (size_t)NN * 32;                // alias
    float* h1o  = (float*)alloc((size_t)NN * 64 * 4);
    float* as1  = (float*)alloc((size_t)NN * 8 * 4);
    float* ad1  = (float*)alloc((size_t)NN * 8 * 4);
    float* as2  = (float*)alloc((size_t)NN * 4);
    float* ad2  = (float*)alloc((size_t)NN * 4);
    int*   offs = (int*)alloc((size_t)(NN + 1) * 4);
    int*   csr  = (int*)alloc((size_t)ET * 4);
    unsigned* rec = (unsigned*)alloc((size_t)ET * 4);
    int*   bdeg = (int*)alloc((size_t)NB * 4);
    int*   bo   = (int*)alloc((size_t)(NB + 1) * 4);
    int*   bcur = (int*)alloc((size_t)NB * 4);
    float* Wt2  = (float*)alloc((size_t)512 * 64 * 4);
    float* pooled = (float*)alloc((size_t)NG * 32 * 4);
    int*   lo   = (int*)alloc((size_t)(NG + 1) * 4);
    if (off > ws_size) return;   // workspace too small: leave d_out poisoned (visible failure)

    hipMemsetAsync(bdeg, 0, (size_t)NB * 4, stream);
    hipMemsetAsync(pooled, 0, (size_t)NG * 32 * 4, stream);

    k_f0<<<32 + BIN_BLOCKS + SCAN_BLOCKS, 256, 0, stream>>>(W1, Wt2, edst, bdeg, bat, lo);
    k_bscan<<<1, 512, 0, stream>>>(bdeg, bo, bcur);
    k_f1<<<GEMM1_BLOCKS + BIN_BLOCKS, 256, 0, stream>>>(
        x, Wt2, aS1, aD1, h1, as1, ad1, esrc, edst, bcur, rec);
    k_unbin2<<<NB, 256, 0, stream>>>(bo, rec, offs, csr);

    k_agg1<<<(NN + 3) / 4, 256, 0, stream>>>(offs, csr, h1, as1, ad1, b1, h1o);
    k_gemm2<<<(NN + 7) / 8, 256, 0, stream>>>(h1o, W2, aS2, aD2, h2, as2, ad2);
    k_agg2<<<(NN + 3) / 4, 256, 0, stream>>>(offs, csr, h2, as2, ad2, b2, o2);

    k_pool<<<NG * 4, 256, 0, stream>>>(o2, lo, pooled);
    k_fin<<<1, 128, 0, stream>>>(pooled, lo, lw, lb, out);
}

// Round 18
// 208.546 us; speedup vs baseline: 1.3129x; 1.1106x over previous
//
#include <hip/hip_runtime.h>
#include <cstdint>
#include <cstddef>

#define NN 50000
#define NE 1600000
#define ET (NE + NN)          // edges + self loops
#define NG 64
#define SCAN_BLOCKS ((NN + 255) / 256)   // 196
#define NB ((NN + 127) >> 7)             // 391 dst-buckets, 128 nodes each
#define EPT 16
#define EPB (256 * EPT)                  // 4096 edges per bin-block
#define BIN_BLOCKS ((ET + EPB - 1) / EPB)
#define GEMM1_BLOCKS ((NN + 63) / 64)    // 782

// ---------------- F0: wt (32 blocks) || bhist (403) || bound (196)
__global__ __launch_bounds__(256) void k_f0(
    const float* __restrict__ W1, float* __restrict__ Wt2,
    const int* __restrict__ edst, int* __restrict__ bdeg,
    const int* __restrict__ batch, int* __restrict__ lo) {
    __shared__ int cnt[NB];
    int bid = blockIdx.x, tid = threadIdx.x;
    if (bid < 32) {
        int id = bid * 256 + tid;
        int k4 = id >> 6, c = id & 63;
        float4 v;
        v.x = W1[(k4 * 4 + 0) * 64 + c];
        v.y = W1[(k4 * 4 + 1) * 64 + c];
        v.z = W1[(k4 * 4 + 2) * 64 + c];
        v.w = W1[(k4 * 4 + 3) * 64 + c];
        reinterpret_cast<float4*>(Wt2)[id] = v;
    } else if (bid < 32 + BIN_BLOCKS) {
        for (int b = tid; b < NB; b += 256) cnt[b] = 0;
        __syncthreads();
        int e0 = (bid - 32) * EPB;
#pragma unroll
        for (int q = 0; q < EPT; ++q) {
            int e = e0 + q * 256 + tid;
            if (e < ET) {
                int d = (e < NE) ? edst[e] : (e - NE);
                atomicAdd(&cnt[d >> 7], 1);
            }
        }
        __syncthreads();
        for (int b = tid; b < NB; b += 256)
            if (cnt[b]) atomicAdd(&bdeg[b], cnt[b]);
    } else {
        int n = (bid - 32 - BIN_BLOCKS) * 256 + tid;
        if (n >= NN) return;
        int b = batch[n];
        if (n == 0) {
            for (int g = 0; g <= b; ++g) lo[g] = 0;
        } else {
            int pb = batch[n - 1];
            for (int g = pb + 1; g <= b; ++g) lo[g] = n;
        }
        if (n == NN - 1) {
            for (int g = b + 1; g <= NG; ++g) lo[g] = NN;
        }
    }
}

__global__ __launch_bounds__(512) void k_bscan(const int* __restrict__ bdeg,
                                               int* __restrict__ bo, int* __restrict__ bcur) {
    __shared__ int lds_w[8];
    int tid = threadIdx.x;
    int lane = tid & 63, wid = tid >> 6;
    int v = (tid < NB) ? bdeg[tid] : 0;
    int incl = v;
#pragma unroll
    for (int ofs = 1; ofs < 64; ofs <<= 1) {
        int o = __shfl_up(incl, ofs);
        if (lane >= ofs) incl += o;
    }
    if (lane == 63) lds_w[wid] = incl;
    __syncthreads();
    int wadd = 0;
    for (int w = 0; w < wid; ++w) wadd += lds_w[w];
    incl += wadd;
    int ex = incl - v;
    if (tid < NB) { bo[tid] = ex; bcur[tid] = ex; }
    if (tid == NB - 1) bo[NB] = ex + v;   // == ET
}

// ---------------- F1: gemm1 (782 blocks) || bin (403 blocks). LDS unioned (32 KB).
__global__ __launch_bounds__(256, 4) void k_f1(
    const float* __restrict__ x, const float* __restrict__ Wt2,
    const float* __restrict__ aS, const float* __restrict__ aD,
    float* __restrict__ h1, float* __restrict__ as1, float* __restrict__ ad1,
    const int* __restrict__ esrc, const int* __restrict__ edst,
    int* __restrict__ bcur, unsigned* __restrict__ rec) {
    __shared__ float4 smem4[2048];    // 32 KB
    int bid = blockIdx.x, t = threadIdx.x;

    if (bid < GEMM1_BLOCKS) {
        float4* xs  = smem4;
        float4* wsr = smem4 + 1024;
        int lane = t & 63, wv_id = t >> 6;
        int n0 = bid * 64;

        const float4* __restrict__ xf = reinterpret_cast<const float4*>(x);
        const float4* __restrict__ wf = reinterpret_cast<const float4*>(Wt2);

        int tc = t & 15;
        int trg = t >> 4;
        int swz = (trg & 3) << 1;

        float acc[4][4];
#pragma unroll
        for (int i = 0; i < 4; ++i)
#pragma unroll
            for (int j = 0; j < 4; ++j) acc[i][j] = 0.f;

        for (int ph = 0; ph < 8; ++ph) {
            int kb4 = ph * 16;
#pragma unroll
            for (int q = 0; q < 4; ++q) {
                int base = (wv_id * 4 + q) * 64;
                int s = base + lane;
                int row = s >> 4;
                int m = s & 15;
                int k4f = m ^ ((row & 3) << 1);
                int rr = n0 + row; if (rr >= NN) rr = NN - 1;
                const float4* src = xf + (size_t)rr * 128 + kb4 + k4f;
                __builtin_amdgcn_global_load_lds(
                    (const __attribute__((address_space(1))) void*)src,
                    (__attribute__((address_space(3))) void*)&xs[base], 16, 0, 0);
            }
#pragma unroll
            for (int q = 0; q < 4; ++q) {
                int base = (wv_id * 4 + q) * 64;
                int s = base + lane;
                int k4 = s >> 6, c = s & 63;
                const float4* src = wf + (size_t)(kb4 + k4) * 64 + c;
                __builtin_amdgcn_global_load_lds(
                    (const __attribute__((address_space(1))) void*)src,
                    (__attribute__((address_space(3))) void*)&wsr[base], 16, 0, 0);
            }
            __syncthreads();

#pragma unroll 2
            for (int k4 = 0; k4 < 16; ++k4) {
                float4 wv0 = wsr[k4 * 64 + tc];
                float4 wv1 = wsr[k4 * 64 + tc + 16];
                float4 wv2 = wsr[k4 * 64 + tc + 32];
                float4 wv3 = wsr[k4 * 64 + tc + 48];
                int kx = k4 ^ swz;
                float4 xv0 = xs[(trg +  0) * 16 + kx];
                float4 xv1 = xs[(trg + 16) * 16 + kx];
                float4 xv2 = xs[(trg + 32) * 16 + kx];
                float4 xv3 = xs[(trg + 48) * 16 + kx];
#define FMA4(a, xv, wv) { a += xv.x * wv.x; a += xv.y * wv.y; a += xv.z * wv.z; a += xv.w * wv.w; }
                FMA4(acc[0][0], xv0, wv0) FMA4(acc[0][1], xv0, wv1) FMA4(acc[0][2], xv0, wv2) FMA4(acc[0][3], xv0, wv3)
                FMA4(acc[1][0], xv1, wv0) FMA4(acc[1][1], xv1, wv1) FMA4(acc[1][2], xv1, wv2) FMA4(acc[1][3], xv1, wv3)
                FMA4(acc[2][0], xv2, wv0) FMA4(acc[2][1], xv2, wv1) FMA4(acc[2][2], xv2, wv2) FMA4(acc[2][3], xv2, wv3)
                FMA4(acc[3][0], xv3, wv0) FMA4(acc[3][1], xv3, wv1) FMA4(acc[3][2], xv3, wv2) FMA4(acc[3][3], xv3, wv3)
#undef FMA4
            }
            __syncthreads();
        }

        int hb = tc >> 3;
        int cc = tc & 7;
#pragma unroll
        for (int i = 0; i < 4; ++i) {
            int r = n0 + trg + 16 * i;
            if (r >= NN) continue;
            float* rowp = h1 + (size_t)r * 64 + tc;
            rowp[0]  = acc[i][0];
            rowp[16] = acc[i][1];
            rowp[32] = acc[i][2];
            rowp[48] = acc[i][3];

            float ps[4], pd[4];
#pragma unroll
            for (int j = 0; j < 4; ++j) {
                int h = 2 * j + hb;
                ps[j] = acc[i][j] * aS[h * 8 + cc];
                pd[j] = acc[i][j] * aD[h * 8 + cc];
            }
#pragma unroll
            for (int ofs = 1; ofs <= 4; ofs <<= 1) {
#pragma unroll
                for (int j = 0; j < 4; ++j) {
                    ps[j] += __shfl_xor(ps[j], ofs);
                    pd[j] += __shfl_xor(pd[j], ofs);
                }
            }
            if (cc == 0) {
#pragma unroll
                for (int j = 0; j < 4; ++j) {
                    int h = 2 * j + hb;
                    as1[r * 8 + h] = ps[j];
                    ad1[r * 8 + h] = pd[j];
                }
            }
        }
    } else {
        int* bcnt = reinterpret_cast<int*>(smem4);
        int tid = t;
        for (int b = tid; b < NB; b += 256) bcnt[b] = 0;
        __syncthreads();
        int e0 = (bid - GEMM1_BLOCKS) * EPB;
        unsigned rv[EPT]; int bk[EPT]; int rk[EPT];
#pragma unroll
        for (int q = 0; q < EPT; ++q) {
            int e = e0 + q * 256 + tid;
            rk[q] = -1;
            if (e < ET) {
                int s, d;
                if (e < NE) { s = esrc[e]; d = edst[e]; } else { s = d = e - NE; }
                rv[q] = ((unsigned)s << 7) | (unsigned)(d & 127);
                bk[q] = d >> 7;
                rk[q] = atomicAdd(&bcnt[bk[q]], 1);
            }
        }
        __syncthreads();
        for (int b = tid; b < NB; b += 256)
            bcnt[b] = atomicAdd(&bcur[b], bcnt[b]);
        __syncthreads();
#pragma unroll
        for (int q = 0; q < EPT; ++q) {
            if (rk[q] >= 0) rec[bcnt[bk[q]] + rk[q]] = rv[q];
        }
    }
}

// unbin2: one block per bucket. LDS degree count + scan -> offs; then scatter csr.
__global__ __launch_bounds__(256) void k_unbin2(
    const int* __restrict__ bo, const unsigned* __restrict__ rec,
    int* __restrict__ offs, int* __restrict__ csr) {
    __shared__ int cnt[128];
    __shared__ int lcur[128];
    int b = blockIdx.x, tid = threadIdx.x;
    if (tid < 128) cnt[tid] = 0;
    __syncthreads();
    int lo = bo[b], hi = bo[b + 1];
    for (int i = lo + tid; i < hi; i += 256)
        atomicAdd(&cnt[rec[i] & 127], 1);
    __syncthreads();
    int v = 0, incl = 0;
    if (tid < 128) {
        int lane = tid & 63;
        v = cnt[tid];
        incl = v;
#pragma unroll
        for (int ofs = 1; ofs < 64; ofs <<= 1) {
            int o = __shfl_up(incl, ofs);
            if (lane >= ofs) incl += o;
        }
        cnt[tid] = incl;
    }
    __syncthreads();
    if (tid < 128) {
        int ex = incl - v + ((tid >= 64) ? cnt[63] : 0);
        int n = (b << 7) + tid;
        int base = lo + ex;
        if (n < NN) offs[n] = base;
        lcur[tid] = base;
        if (n == NN - 1 || (b == NB - 1 && tid == 127)) offs[NN] = ET;
    }
    __syncthreads();
    for (int i = lo + tid; i < hi; i += 256) {
        unsigned r = rec[i];
        int pos = atomicAdd(&lcur[r & 127], 1);
        csr[pos] = (int)(r >> 7);
    }
}

// ---------------- K4: fused layer-1 aggregation + layer-2 GEMM.
// Wave per dst; lane = (slot g = l>>4, f4 q = l&15). After h1o row is formed,
// stage it in wave-local LDS and compute h2 = h1o @ W2 + as2/ad2 in-register.
__global__ __launch_bounds__(256) void k_agg1g(
    const int* __restrict__ offs, const int* __restrict__ csr,
    const float* __restrict__ h1, const float* __restrict__ as1, const float* __restrict__ ad1,
    const float* __restrict__ bias1, const float* __restrict__ W2,
    const float* __restrict__ aS2, const float* __restrict__ aD2,
    float* __restrict__ h2, float* __restrict__ as2, float* __restrict__ ad2) {
    __shared__ float w2l[64 * 32];     // 8 KB
    __shared__ float h1ol[4][64];      // per-wave h1o row
    int tid = threadIdx.x;
    for (int i = tid; i < 2048; i += 256) w2l[i] = W2[i];
    __syncthreads();

    int l = tid & 63;
    int wv = tid >> 6;
    int dst = blockIdx.x * 4 + wv;
    if (dst >= NN) return;              // never taken (NN % 4 == 0), kept for safety
    int g = l >> 4;            // edge slot 0..3
    int q = l & 15;            // float4 index in 64-ch row
    int h = q >> 1;            // head
    int beg = offs[dst], end = offs[dst + 1];
    int lastj = end - 1;       // deg >= 1 (self-loop)
    float adh = ad1[dst * 8 + h];
    const float4* __restrict__ h1f = reinterpret_cast<const float4*>(h1);

    float4 acc = make_float4(0.f, 0.f, 0.f, 0.f);
    float dsum = 0.f;

    int sA[4], sB[4];
#pragma unroll
    for (int p = 0; p < 4; ++p) sA[p] = csr[min(beg + p * 4 + g, lastj)];
    for (int j = beg; j < end; j += 16) {
#pragma unroll
        for (int p = 0; p < 4; ++p) sB[p] = csr[min(j + 16 + p * 4 + g, lastj)];
        float av[4]; float4 vv[4];
#pragma unroll
        for (int p = 0; p < 4; ++p) {
            av[p] = as1[sA[p] * 8 + h];
            vv[p] = h1f[sA[p] * 16 + q];
        }
#pragma unroll
        for (int p = 0; p < 4; ++p) {
            float e = av[p] + adh; e = (e > 0.f) ? e : 0.2f * e;
            float w = __expf(e);
            w = (j + p * 4 + g < end) ? w : 0.f;
            acc.x += w * vv[p].x; acc.y += w * vv[p].y;
            acc.z += w * vv[p].z; acc.w += w * vv[p].w;
            dsum += w;
        }
#pragma unroll
        for (int p = 0; p < 4; ++p) sA[p] = sB[p];
    }

#pragma unroll
    for (int ofs = 16; ofs <= 32; ofs <<= 1) {
        acc.x += __shfl_xor(acc.x, ofs);
        acc.y += __shfl_xor(acc.y, ofs);
        acc.z += __shfl_xor(acc.z, ofs);
        acc.w += __shfl_xor(acc.w, ofs);
        dsum  += __shfl_xor(dsum, ofs);
    }

    if (g == 0) {
        float inv = 1.f / (dsum + 1e-16f);
        const float4 bq = reinterpret_cast<const float4*>(bias1)[q];
        float4 r;
        r.x = acc.x * inv + bq.x;
        r.y = acc.y * inv + bq.y;
        r.z = acc.z * inv + bq.z;
        r.w = acc.w * inv + bq.w;
        r.x = (r.x > 0.f) ? r.x : (__expf(r.x) - 1.f);
        r.y = (r.y > 0.f) ? r.y : (__expf(r.y) - 1.f);
        r.z = (r.z > 0.f) ? r.z : (__expf(r.z) - 1.f);
        r.w = (r.w > 0.f) ? r.w : (__expf(r.w) - 1.f);
        h1ol[wv][q * 4 + 0] = r.x;
        h1ol[wv][q * 4 + 1] = r.y;
        h1ol[wv][q * 4 + 2] = r.z;
        h1ol[wv][q * 4 + 3] = r.w;
    }
    // wave-local LDS visibility: same wave wrote, same wave reads (lockstep; compiler
    // inserts lgkmcnt wait on the dependent reads).

    // ---- fused gemm2: h2[dst][c] = sum_k h1o[k] * W2[k][c]
    int c = l & 31, half = l >> 5;
    const float* hrow = h1ol[wv];
    float acc2 = 0.f;
#pragma unroll 8
    for (int kk = 0; kk < 32; ++kk) {
        int k = half * 32 + kk;
        acc2 += hrow[k] * w2l[k * 32 + c];
    }
    acc2 += __shfl_xor(acc2, 32);
    if (l < 32) h2[dst * 32 + c] = acc2;
    float ps = acc2 * aS2[c], pd = acc2 * aD2[c];
#pragma unroll
    for (int ofs = 1; ofs <= 16; ofs <<= 1) {
        ps += __shfl_xor(ps, ofs);
        pd += __shfl_xor(pd, ofs);
    }
    if (l == 0) { as2[dst] = ps; ad2[dst] = pd; }
}

// ---------------- K7: layer-2 aggregation. Wave per dst; lane = (slot g = l>>3, f4 q = l&7).
__global__ __launch_bounds__(256) void k_agg2(
    const int* __restrict__ offs, const int* __restrict__ csr,
    const float* __restrict__ h2, const float* __restrict__ as2, const float* __restrict__ ad2,
    const float* __restrict__ bias2, float* __restrict__ o2) {
    int l = threadIdx.x & 63;
    int dst = blockIdx.x * 4 + (threadIdx.x >> 6);
    if (dst >= NN) return;
    int g = l >> 3;            // edge slot 0..7
    int q = l & 7;             // float4 index in 32-ch row
    int beg = offs[dst], end = offs[dst + 1];
    int lastj = end - 1;
    float adh = ad2[dst];
    const float4* __restrict__ h2f = reinterpret_cast<const float4*>(h2);

    float4 acc = make_float4(0.f, 0.f, 0.f, 0.f);
    float dsum = 0.f;

    int sA[4], sB[4];
#pragma unroll
    for (int p = 0; p < 4; ++p) sA[p] = csr[min(beg + p * 8 + g, lastj)];
    for (int j = beg; j < end; j += 32) {
#pragma unroll
        for (int p = 0; p < 4; ++p) sB[p] = csr[min(j + 32 + p * 8 + g, lastj)];
        float av[4]; float4 vv[4];
#pragma unroll
        for (int p = 0; p < 4; ++p) {
            av[p] = as2[sA[p]];
            vv[p] = h2f[sA[p] * 8 + q];
        }
#pragma unroll
        for (int p = 0; p < 4; ++p) {
            float e = av[p] + adh; e = (e > 0.f) ? e : 0.2f * e;
            float w = __expf(e);
            w = (j + p * 8 + g < end) ? w : 0.f;
            acc.x += w * vv[p].x; acc.y += w * vv[p].y;
            acc.z += w * vv[p].z; acc.w += w * vv[p].w;
            dsum += w;
        }
#pragma unroll
        for (int p = 0; p < 4; ++p) sA[p] = sB[p];
    }

#pragma unroll
    for (int ofs = 8; ofs <= 32; ofs <<= 1) {
        acc.x += __shfl_xor(acc.x, ofs);
        acc.y += __shfl_xor(acc.y, ofs);
        acc.z += __shfl_xor(acc.z, ofs);
        acc.w += __shfl_xor(acc.w, ofs);
        dsum  += __shfl_xor(dsum, ofs);
    }

    if (g == 0) {
        float inv = 1.f / (dsum + 1e-16f);
        const float4 bq = reinterpret_cast<const float4*>(bias2)[q];
        float4 r;
        r.x = acc.x * inv + bq.x;
        r.y = acc.y * inv + bq.y;
        r.z = acc.z * inv + bq.z;
        r.w = acc.w * inv + bq.w;
        reinterpret_cast<float4*>(o2)[dst * 8 + q] = r;
    }
}

// ---------------- K9: pooled sums.
__global__ __launch_bounds__(256) void k_pool(const float* __restrict__ o2, const int* __restrict__ lo,
                                              float* __restrict__ pooled) {
    __shared__ float red[256];
    int g = blockIdx.x & 63, q = blockIdx.x >> 6;
    int beg = lo[g], end = lo[g + 1];
    int c = threadIdx.x & 31, row = threadIdx.x >> 5;
    float s = 0.f;
    for (int n = beg + q * 8 + row; n < end; n += 32) s += o2[n * 32 + c];
    red[threadIdx.x] = s;
    __syncthreads();
    for (int rr = 4; rr >= 1; rr >>= 1) {
        if (row < rr) red[threadIdx.x] += red[(row + rr) * 32 + c];
        __syncthreads();
    }
    if (row == 0) atomicAdd(&pooled[g * 32 + c], red[c]);
}

// ---------------- K10: mean + final linear -> out[64][2]
__global__ void k_fin(const float* __restrict__ pooled, const int* __restrict__ lo,
                      const float* __restrict__ lw, const float* __restrict__ lb,
                      float* __restrict__ out) {
    int t = threadIdx.x;
    if (t >= 128) return;
    int g = t >> 1, o = t & 1;
    int cnt = lo[g + 1] - lo[g];
    float inv = 1.f / fmaxf((float)cnt, 1.f);
    float s = 0.f;
#pragma unroll
    for (int c = 0; c < 32; ++c) s += pooled[g * 32 + c] * lw[c * 2 + o];
    out[g * 2 + o] = s * inv + lb[o];
}

// ----------------------------------------------------------------------------
extern "C" void kernel_launch(void* const* d_in, const int* in_sizes, int n_in,
                              void* d_out, int out_size, void* d_ws, size_t ws_size,
                              hipStream_t stream) {
    const float* x   = (const float*)d_in[0];
    const int*   ei  = (const int*)d_in[1];     // [2][NE]
    const int*   bat = (const int*)d_in[2];
    const float* W1  = (const float*)d_in[3];
    const float* aS1 = (const float*)d_in[4];
    const float* aD1 = (const float*)d_in[5];
    const float* b1  = (const float*)d_in[6];
    const float* W2  = (const float*)d_in[7];
    const float* aS2 = (const float*)d_in[8];
    const float* aD2 = (const float*)d_in[9];
    const float* b2  = (const float*)d_in[10];
    const float* lw  = (const float*)d_in[11];
    const float* lb  = (const float*)d_in[12];
    float* out = (float*)d_out;

    const int* esrc = ei;
    const int* edst = ei + NE;

    char* ws = (char*)d_ws;
    size_t off = 0;
    auto alloc = [&](size_t bytes) -> void* {
        off = (off + 255) & ~(size_t)255;
        void* p = ws + off;
        off += bytes;
        return p;
    };

    float* regA = (float*)alloc((size_t)NN * 64 * 4);   // h1; o2 reuses its upper half later
    float* h1   = regA;
    float* o2   = regA + (size_t)NN * 32;                // alias (h1 dead after k_agg1g)
    float* h2   = (float*)alloc((size_t)NN * 32 * 4);    // own buffer: written while h1 still live
    float* as1  = (float*)alloc((size_t)NN * 8 * 4);
    float* ad1  = (float*)alloc((size_t)NN * 8 * 4);
    float* as2  = (float*)alloc((size_t)NN * 4);
    float* ad2  = (float*)alloc((size_t)NN * 4);
    int*   offs = (int*)alloc((size_t)(NN + 1) * 4);
    int*   csr  = (int*)alloc((size_t)ET * 4);
    unsigned* rec = (unsigned*)alloc((size_t)ET * 4);
    int*   bdeg = (int*)alloc((size_t)NB * 4);
    int*   bo   = (int*)alloc((size_t)(NB + 1) * 4);
    int*   bcur = (int*)alloc((size_t)NB * 4);
    float* Wt2  = (float*)alloc((size_t)512 * 64 * 4);
    float* pooled = (float*)alloc((size_t)NG * 32 * 4);
    int*   lo   = (int*)alloc((size_t)(NG + 1) * 4);
    if (off > ws_size) return;   // workspace too small: leave d_out poisoned (visible failure)

    hipMemsetAsync(bdeg, 0, (size_t)NB * 4, stream);
    hipMemsetAsync(pooled, 0, (size_t)NG * 32 * 4, stream);

    k_f0<<<32 + BIN_BLOCKS + SCAN_BLOCKS, 256, 0, stream>>>(W1, Wt2, edst, bdeg, bat, lo);
    k_bscan<<<1, 512, 0, stream>>>(bdeg, bo, bcur);
    k_f1<<<GEMM1_BLOCKS + BIN_BLOCKS, 256, 0, stream>>>(
        x, Wt2, aS1, aD1, h1, as1, ad1, esrc, edst, bcur, rec);
    k_unbin2<<<NB, 256, 0, stream>>>(bo, rec, offs, csr);

    k_agg1g<<<(NN + 3) / 4, 256, 0, stream>>>(offs, csr, h1, as1, ad1, b1,
                                              W2, aS2, aD2, h2, as2, ad2);
    k_agg2<<<(NN + 3) / 4, 256, 0, stream>>>(offs, csr, h2, as2, ad2, b2, o2);

    k_pool<<<NG * 4, 256, 0, stream>>>(o2, lo, pooled);
    k_fin<<<1, 128, 0, stream>>>(pooled, lo, lw, lb, out);
}

// Round 19
// 204.380 us; speedup vs baseline: 1.3397x; 1.0204x over previous
//
#include <hip/hip_runtime.h>
#include <cstdint>
#include <cstddef>

#define NN 50000
#define NE 1600000
#define ET (NE + NN)          // edges + self loops
#define NG 64
#define SCAN_BLOCKS ((NN + 255) / 256)   // 196
#define NB ((NN + 127) >> 7)             // 391 dst-buckets, 128 nodes each
#define CAP 6144                         // slots per bucket segment (mean 4224, sigma 64)
#define EPT 16
#define EPB (256 * EPT)                  // 4096 edges per bin-block
#define BIN_BLOCKS ((ET + EPB - 1) / EPB)
#define GEMM1_BLOCKS ((NN + 63) / 64)    // 782

// ---------------- F0: bin (403 blocks) || wt (32) || bound (196)
__global__ __launch_bounds__(256) void k_f0(
    const int* __restrict__ esrc, const int* __restrict__ edst,
    int* __restrict__ gcnt, unsigned* __restrict__ rec,
    const float* __restrict__ W1, float* __restrict__ Wt2,
    const int* __restrict__ batch, int* __restrict__ lo) {
    __shared__ int bcnt[NB];
    int bid = blockIdx.x, tid = threadIdx.x;
    if (bid < BIN_BLOCKS) {
        // ---- bin: block-aggregated bucket scatter into fixed segments; rec=(src<<7)|(dst&127)
        for (int b = tid; b < NB; b += 256) bcnt[b] = 0;
        __syncthreads();
        int e0 = bid * EPB;
        unsigned rv[EPT]; int bk[EPT]; int rk[EPT];
#pragma unroll
        for (int q = 0; q < EPT; ++q) {
            int e = e0 + q * 256 + tid;
            rk[q] = -1;
            if (e < ET) {
                int s, d;
                if (e < NE) { s = esrc[e]; d = edst[e]; } else { s = d = e - NE; }
                rv[q] = ((unsigned)s << 7) | (unsigned)(d & 127);
                bk[q] = d >> 7;
                rk[q] = atomicAdd(&bcnt[bk[q]], 1);
            }
        }
        __syncthreads();
        for (int b = tid; b < NB; b += 256)
            bcnt[b] = atomicAdd(&gcnt[b], bcnt[b]);
        __syncthreads();
#pragma unroll
        for (int q = 0; q < EPT; ++q) {
            if (rk[q] >= 0) rec[(size_t)bk[q] * CAP + bcnt[bk[q]] + rk[q]] = rv[q];
        }
    } else if (bid < BIN_BLOCKS + 32) {
        // ---- wt: transpose W1 [512][64] -> k-packed float4
        int id = (bid - BIN_BLOCKS) * 256 + tid;
        int k4 = id >> 6, c = id & 63;
        float4 v;
        v.x = W1[(k4 * 4 + 0) * 64 + c];
        v.y = W1[(k4 * 4 + 1) * 64 + c];
        v.z = W1[(k4 * 4 + 2) * 64 + c];
        v.w = W1[(k4 * 4 + 3) * 64 + c];
        reinterpret_cast<float4*>(Wt2)[id] = v;
    } else {
        // ---- bound: graph boundaries from sorted batch
        int n = (bid - BIN_BLOCKS - 32) * 256 + tid;
        if (n >= NN) return;
        int b = batch[n];
        if (n == 0) {
            for (int g = 0; g <= b; ++g) lo[g] = 0;
        } else {
            int pb = batch[n - 1];
            for (int g = pb + 1; g <= b; ++g) lo[g] = n;
        }
        if (n == NN - 1) {
            for (int g = b + 1; g <= NG; ++g) lo[g] = NN;
        }
    }
}

// ---------------- F1: unbin2 (391 blocks, first) || gemm1 (782). LDS unioned (32 KB).
__global__ __launch_bounds__(256, 4) void k_f1(
    const int* __restrict__ gcnt, const unsigned* __restrict__ rec,
    int* __restrict__ obeg, int* __restrict__ oend, int* __restrict__ csr,
    const float* __restrict__ x, const float* __restrict__ Wt2,
    const float* __restrict__ aS, const float* __restrict__ aD,
    float* __restrict__ h1, float* __restrict__ as1, float* __restrict__ ad1) {
    __shared__ float4 smem4[2048];    // 32 KB
    int bid = blockIdx.x, t = threadIdx.x;

    if (bid < NB) {
        // ======== unbin2: bucket-local degree count + scan -> obeg/oend; scatter csr ========
        int* cnt  = reinterpret_cast<int*>(smem4);
        int* lcur = cnt + 128;
        int b = bid, tid = t;
        if (tid < 128) cnt[tid] = 0;
        __syncthreads();
        size_t base = (size_t)b * CAP;
        int nrec = gcnt[b];
        for (int i = tid; i < nrec; i += 256)
            atomicAdd(&cnt[rec[base + i] & 127], 1);
        __syncthreads();
        int v = 0, incl = 0;
        if (tid < 128) {
            int lane = tid & 63;
            v = cnt[tid];
            incl = v;
#pragma unroll
            for (int ofs = 1; ofs < 64; ofs <<= 1) {
                int o = __shfl_up(incl, ofs);
                if (lane >= ofs) incl += o;
            }
            cnt[tid] = incl;
        }
        __syncthreads();
        if (tid < 128) {
            int ex = incl - v + ((tid >= 64) ? cnt[63] : 0);
            int n = (b << 7) + tid;
            int pos = (int)base + ex;
            if (n < NN) { obeg[n] = pos; oend[n] = pos + v; }
            lcur[tid] = pos;
        }
        __syncthreads();
        for (int i = tid; i < nrec; i += 256) {
            unsigned r = rec[base + i];
            int pos = atomicAdd(&lcur[r & 127], 1);
            csr[pos] = (int)(r >> 7);
        }
    } else {
        // ======== gemm1: h1 = x @ W1, full-K, 64 rows/block, 8 LDS phases ========
        float4* xs  = smem4;
        float4* wsr = smem4 + 1024;
        int lane = t & 63, wv_id = t >> 6;
        int n0 = (bid - NB) * 64;

        const float4* __restrict__ xf = reinterpret_cast<const float4*>(x);
        const float4* __restrict__ wf = reinterpret_cast<const float4*>(Wt2);

        int tc = t & 15;
        int trg = t >> 4;
        int swz = (trg & 3) << 1;

        float acc[4][4];
#pragma unroll
        for (int i = 0; i < 4; ++i)
#pragma unroll
            for (int j = 0; j < 4; ++j) acc[i][j] = 0.f;

        for (int ph = 0; ph < 8; ++ph) {
            int kb4 = ph * 16;
#pragma unroll
            for (int q = 0; q < 4; ++q) {
                int base = (wv_id * 4 + q) * 64;
                int s = base + lane;
                int row = s >> 4;
                int m = s & 15;
                int k4f = m ^ ((row & 3) << 1);
                int rr = n0 + row; if (rr >= NN) rr = NN - 1;
                const float4* src = xf + (size_t)rr * 128 + kb4 + k4f;
                __builtin_amdgcn_global_load_lds(
                    (const __attribute__((address_space(1))) void*)src,
                    (__attribute__((address_space(3))) void*)&xs[base], 16, 0, 0);
            }
#pragma unroll
            for (int q = 0; q < 4; ++q) {
                int base = (wv_id * 4 + q) * 64;
                int s = base + lane;
                int k4 = s >> 6, c = s & 63;
                const float4* src = wf + (size_t)(kb4 + k4) * 64 + c;
                __builtin_amdgcn_global_load_lds(
                    (const __attribute__((address_space(1))) void*)src,
                    (__attribute__((address_space(3))) void*)&wsr[base], 16, 0, 0);
            }
            __syncthreads();

#pragma unroll 2
            for (int k4 = 0; k4 < 16; ++k4) {
                float4 wv0 = wsr[k4 * 64 + tc];
                float4 wv1 = wsr[k4 * 64 + tc + 16];
                float4 wv2 = wsr[k4 * 64 + tc + 32];
                float4 wv3 = wsr[k4 * 64 + tc + 48];
                int kx = k4 ^ swz;
                float4 xv0 = xs[(trg +  0) * 16 + kx];
                float4 xv1 = xs[(trg + 16) * 16 + kx];
                float4 xv2 = xs[(trg + 32) * 16 + kx];
                float4 xv3 = xs[(trg + 48) * 16 + kx];
#define FMA4(a, xv, wv) { a += xv.x * wv.x; a += xv.y * wv.y; a += xv.z * wv.z; a += xv.w * wv.w; }
                FMA4(acc[0][0], xv0, wv0) FMA4(acc[0][1], xv0, wv1) FMA4(acc[0][2], xv0, wv2) FMA4(acc[0][3], xv0, wv3)
                FMA4(acc[1][0], xv1, wv0) FMA4(acc[1][1], xv1, wv1) FMA4(acc[1][2], xv1, wv2) FMA4(acc[1][3], xv1, wv3)
                FMA4(acc[2][0], xv2, wv0) FMA4(acc[2][1], xv2, wv1) FMA4(acc[2][2], xv2, wv2) FMA4(acc[2][3], xv2, wv3)
                FMA4(acc[3][0], xv3, wv0) FMA4(acc[3][1], xv3, wv1) FMA4(acc[3][2], xv3, wv2) FMA4(acc[3][3], xv3, wv3)
#undef FMA4
            }
            __syncthreads();
        }

        int hb = tc >> 3;
        int cc = tc & 7;
#pragma unroll
        for (int i = 0; i < 4; ++i) {
            int r = n0 + trg + 16 * i;
            if (r >= NN) continue;
            float* rowp = h1 + (size_t)r * 64 + tc;
            rowp[0]  = acc[i][0];
            rowp[16] = acc[i][1];
            rowp[32] = acc[i][2];
            rowp[48] = acc[i][3];

            float ps[4], pd[4];
#pragma unroll
            for (int j = 0; j < 4; ++j) {
                int h = 2 * j + hb;
                ps[j] = acc[i][j] * aS[h * 8 + cc];
                pd[j] = acc[i][j] * aD[h * 8 + cc];
            }
#pragma unroll
            for (int ofs = 1; ofs <= 4; ofs <<= 1) {
#pragma unroll
                for (int j = 0; j < 4; ++j) {
                    ps[j] += __shfl_xor(ps[j], ofs);
                    pd[j] += __shfl_xor(pd[j], ofs);
                }
            }
            if (cc == 0) {
#pragma unroll
                for (int j = 0; j < 4; ++j) {
                    int h = 2 * j + hb;
                    as1[r * 8 + h] = ps[j];
                    ad1[r * 8 + h] = pd[j];
                }
            }
        }
    }
}

// ---------------- K4: fused layer-1 aggregation + layer-2 GEMM.
__global__ __launch_bounds__(256) void k_agg1g(
    const int* __restrict__ obeg, const int* __restrict__ oend, const int* __restrict__ csr,
    const float* __restrict__ h1, const float* __restrict__ as1, const float* __restrict__ ad1,
    const float* __restrict__ bias1, const float* __restrict__ W2,
    const float* __restrict__ aS2, const float* __restrict__ aD2,
    float* __restrict__ h2, float* __restrict__ as2, float* __restrict__ ad2) {
    __shared__ float w2l[64 * 32];     // 8 KB
    __shared__ float h1ol[4][64];      // per-wave h1o row
    int tid = threadIdx.x;
    for (int i = tid; i < 2048; i += 256) w2l[i] = W2[i];
    __syncthreads();

    int l = tid & 63;
    int wv = tid >> 6;
    int dst = blockIdx.x * 4 + wv;
    if (dst >= NN) return;
    int g = l >> 4;            // edge slot 0..3
    int q = l & 15;            // float4 index in 64-ch row
    int h = q >> 1;            // head
    int beg = obeg[dst], end = oend[dst];
    int lastj = end - 1;       // deg >= 1 (self-loop)
    float adh = ad1[dst * 8 + h];
    const float4* __restrict__ h1f = reinterpret_cast<const float4*>(h1);

    float4 acc = make_float4(0.f, 0.f, 0.f, 0.f);
    float dsum = 0.f;

    int sA[4], sB[4];
#pragma unroll
    for (int p = 0; p < 4; ++p) sA[p] = csr[min(beg + p * 4 + g, lastj)];
    for (int j = beg; j < end; j += 16) {
#pragma unroll
        for (int p = 0; p < 4; ++p) sB[p] = csr[min(j + 16 + p * 4 + g, lastj)];
        float av[4]; float4 vv[4];
#pragma unroll
        for (int p = 0; p < 4; ++p) {
            av[p] = as1[sA[p] * 8 + h];
            vv[p] = h1f[sA[p] * 16 + q];
        }
#pragma unroll
        for (int p = 0; p < 4; ++p) {
            float e = av[p] + adh; e = (e > 0.f) ? e : 0.2f * e;
            float w = __expf(e);
            w = (j + p * 4 + g < end) ? w : 0.f;
            acc.x += w * vv[p].x; acc.y += w * vv[p].y;
            acc.z += w * vv[p].z; acc.w += w * vv[p].w;
            dsum += w;
        }
#pragma unroll
        for (int p = 0; p < 4; ++p) sA[p] = sB[p];
    }

#pragma unroll
    for (int ofs = 16; ofs <= 32; ofs <<= 1) {
        acc.x += __shfl_xor(acc.x, ofs);
        acc.y += __shfl_xor(acc.y, ofs);
        acc.z += __shfl_xor(acc.z, ofs);
        acc.w += __shfl_xor(acc.w, ofs);
        dsum  += __shfl_xor(dsum, ofs);
    }

    if (g == 0) {
        float inv = 1.f / (dsum + 1e-16f);
        const float4 bq = reinterpret_cast<const float4*>(bias1)[q];
        float4 r;
        r.x = acc.x * inv + bq.x;
        r.y = acc.y * inv + bq.y;
        r.z = acc.z * inv + bq.z;
        r.w = acc.w * inv + bq.w;
        r.x = (r.x > 0.f) ? r.x : (__expf(r.x) - 1.f);
        r.y = (r.y > 0.f) ? r.y : (__expf(r.y) - 1.f);
        r.z = (r.z > 0.f) ? r.z : (__expf(r.z) - 1.f);
        r.w = (r.w > 0.f) ? r.w : (__expf(r.w) - 1.f);
        h1ol[wv][q * 4 + 0] = r.x;
        h1ol[wv][q * 4 + 1] = r.y;
        h1ol[wv][q * 4 + 2] = r.z;
        h1ol[wv][q * 4 + 3] = r.w;
    }

    // fused gemm2
    int c = l & 31, half = l >> 5;
    const float* hrow = h1ol[wv];
    float acc2 = 0.f;
#pragma unroll 8
    for (int kk = 0; kk < 32; ++kk) {
        int k = half * 32 + kk;
        acc2 += hrow[k] * w2l[k * 32 + c];
    }
    acc2 += __shfl_xor(acc2, 32);
    if (l < 32) h2[dst * 32 + c] = acc2;
    float ps = acc2 * aS2[c], pd = acc2 * aD2[c];
#pragma unroll
    for (int ofs = 1; ofs <= 16; ofs <<= 1) {
        ps += __shfl_xor(ps, ofs);
        pd += __shfl_xor(pd, ofs);
    }
    if (l == 0) { as2[dst] = ps; ad2[dst] = pd; }
}

// ---------------- K7: layer-2 aggregation. Wave per dst; lane = (slot g = l>>3, f4 q = l&7).
__global__ __launch_bounds__(256) void k_agg2(
    const int* __restrict__ obeg, const int* __restrict__ oend, const int* __restrict__ csr,
    const float* __restrict__ h2, const float* __restrict__ as2, const float* __restrict__ ad2,
    const float* __restrict__ bias2, float* __restrict__ o2) {
    int l = threadIdx.x & 63;
    int dst = blockIdx.x * 4 + (threadIdx.x >> 6);
    if (dst >= NN) return;
    int g = l >> 3;            // edge slot 0..7
    int q = l & 7;             // float4 index in 32-ch row
    int beg = obeg[dst], end = oend[dst];
    int lastj = end - 1;
    float adh = ad2[dst];
    const float4* __restrict__ h2f = reinterpret_cast<const float4*>(h2);

    float4 acc = make_float4(0.f, 0.f, 0.f, 0.f);
    float dsum = 0.f;

    int sA[4], sB[4];
#pragma unroll
    for (int p = 0; p < 4; ++p) sA[p] = csr[min(beg + p * 8 + g, lastj)];
    for (int j = beg; j < end; j += 32) {
#pragma unroll
        for (int p = 0; p < 4; ++p) sB[p] = csr[min(j + 32 + p * 8 + g, lastj)];
        float av[4]; float4 vv[4];
#pragma unroll
        for (int p = 0; p < 4; ++p) {
            av[p] = as2[sA[p]];
            vv[p] = h2f[sA[p] * 8 + q];
        }
#pragma unroll
        for (int p = 0; p < 4; ++p) {
            float e = av[p] + adh; e = (e > 0.f) ? e : 0.2f * e;
            float w = __expf(e);
            w = (j + p * 8 + g < end) ? w : 0.f;
            acc.x += w * vv[p].x; acc.y += w * vv[p].y;
            acc.z += w * vv[p].z; acc.w += w * vv[p].w;
            dsum += w;
        }
#pragma unroll
        for (int p = 0; p < 4; ++p) sA[p] = sB[p];
    }

#pragma unroll
    for (int ofs = 8; ofs <= 32; ofs <<= 1) {
        acc.x += __shfl_xor(acc.x, ofs);
        acc.y += __shfl_xor(acc.y, ofs);
        acc.z += __shfl_xor(acc.z, ofs);
        acc.w += __shfl_xor(acc.w, ofs);
        dsum  += __shfl_xor(dsum, ofs);
    }

    if (g == 0) {
        float inv = 1.f / (dsum + 1e-16f);
        const float4 bq = reinterpret_cast<const float4*>(bias2)[q];
        float4 r;
        r.x = acc.x * inv + bq.x;
        r.y = acc.y * inv + bq.y;
        r.z = acc.z * inv + bq.z;
        r.w = acc.w * inv + bq.w;
        reinterpret_cast<float4*>(o2)[dst * 8 + q] = r;
    }
}

// ---------------- K9: pooled sums.
__global__ __launch_bounds__(256) void k_pool(const float* __restrict__ o2, const int* __restrict__ lo,
                                              float* __restrict__ pooled) {
    __shared__ float red[256];
    int g = blockIdx.x & 63, q = blockIdx.x >> 6;
    int beg = lo[g], end = lo[g + 1];
    int c = threadIdx.x & 31, row = threadIdx.x >> 5;
    float s = 0.f;
    for (int n = beg + q * 8 + row; n < end; n += 32) s += o2[n * 32 + c];
    red[threadIdx.x] = s;
    __syncthreads();
    for (int rr = 4; rr >= 1; rr >>= 1) {
        if (row < rr) red[threadIdx.x] += red[(row + rr) * 32 + c];
        __syncthreads();
    }
    if (row == 0) atomicAdd(&pooled[g * 32 + c], red[c]);
}

// ---------------- K10: mean + final linear -> out[64][2]
__global__ void k_fin(const float* __restrict__ pooled, const int* __restrict__ lo,
                      const float* __restrict__ lw, const float* __restrict__ lb,
                      float* __restrict__ out) {
    int t = threadIdx.x;
    if (t >= 128) return;
    int g = t >> 1, o = t & 1;
    int cnt = lo[g + 1] - lo[g];
    float inv = 1.f / fmaxf((float)cnt, 1.f);
    float s = 0.f;
#pragma unroll
    for (int c = 0; c < 32; ++c) s += pooled[g * 32 + c] * lw[c * 2 + o];
    out[g * 2 + o] = s * inv + lb[o];
}

// ----------------------------------------------------------------------------
extern "C" void kernel_launch(void* const* d_in, const int* in_sizes, int n_in,
                              void* d_out, int out_size, void* d_ws, size_t ws_size,
                              hipStream_t stream) {
    const float* x   = (const float*)d_in[0];
    const int*   ei  = (const int*)d_in[1];     // [2][NE]
    const int*   bat = (const int*)d_in[2];
    const float* W1  = (const float*)d_in[3];
    const float* aS1 = (const float*)d_in[4];
    const float* aD1 = (const float*)d_in[5];
    const float* b1  = (const float*)d_in[6];
    const float* W2  = (const float*)d_in[7];
    const float* aS2 = (const float*)d_in[8];
    const float* aD2 = (const float*)d_in[9];
    const float* b2  = (const float*)d_in[10];
    const float* lw  = (const float*)d_in[11];
    const float* lb  = (const float*)d_in[12];
    float* out = (float*)d_out;

    const int* esrc = ei;
    const int* edst = ei + NE;

    char* ws = (char*)d_ws;
    size_t off = 0;
    auto alloc = [&](size_t bytes) -> void* {
        off = (off + 255) & ~(size_t)255;
        void* p = ws + off;
        off += bytes;
        return p;
    };

    float* regA = (float*)alloc((size_t)NN * 64 * 4);   // h1; o2 reuses its upper half later
    float* h1   = regA;
    float* o2   = regA + (size_t)NN * 32;                // alias (h1 dead after k_agg1g)
    float* h2   = (float*)alloc((size_t)NN * 32 * 4);
    float* as1  = (float*)alloc((size_t)NN * 8 * 4);
    float* ad1  = (float*)alloc((size_t)NN * 8 * 4);
    float* as2  = (float*)alloc((size_t)NN * 4);
    float* ad2  = (float*)alloc((size_t)NN * 4);
    int*   obeg = (int*)alloc((size_t)NN * 4);
    int*   oend = (int*)alloc((size_t)NN * 4);
    int*   csr  = (int*)alloc((size_t)NB * CAP * 4);
    unsigned* rec = (unsigned*)alloc((size_t)NB * CAP * 4);
    int*   gcnt = (int*)alloc((size_t)NB * 4);
    float* Wt2  = (float*)alloc((size_t)512 * 64 * 4);
    float* pooled = (float*)alloc((size_t)NG * 32 * 4);
    int*   lo   = (int*)alloc((size_t)(NG + 1) * 4);
    if (off > ws_size) return;   // workspace too small: leave d_out poisoned (visible failure)

    hipMemsetAsync(gcnt, 0, (size_t)NB * 4, stream);
    hipMemsetAsync(pooled, 0, (size_t)NG * 32 * 4, stream);

    k_f0<<<BIN_BLOCKS + 32 + SCAN_BLOCKS, 256, 0, stream>>>(
        esrc, edst, gcnt, rec, W1, Wt2, bat, lo);
    k_f1<<<NB + GEMM1_BLOCKS, 256, 0, stream>>>(
        gcnt, rec, obeg, oend, csr, x, Wt2, aS1, aD1, h1, as1, ad1);

    k_agg1g<<<(NN + 3) / 4, 256, 0, stream>>>(obeg, oend, csr, h1, as1, ad1, b1,
                                              W2, aS2, aD2, h2, as2, ad2);
    k_agg2<<<(NN + 3) / 4, 256, 0, stream>>>(obeg, oend, csr, h2, as2, ad2, b2, o2);

    k_pool<<<NG * 4, 256, 0, stream>>>(o2, lo, pooled);
    k_fin<<<1, 128, 0, stream>>>(pooled, lo, lw, lb, out);
}

// Round 22
// 186.159 us; speedup vs baseline: 1.4708x; 1.0979x over previous
//
#include <hip/hip_runtime.h>
#include <cstdint>
#include <cstddef>

#define NN 50000
#define NE 1600000
#define ET (NE + NN)          // edges + self loops
#define NG 64
#define SCAN_BLOCKS ((NN + 255) / 256)   // 196
#define NB ((NN + 127) >> 7)             // 391 dst-buckets, 128 nodes each
#define CAP 6144                         // slots per bucket segment (mean 4224, sigma 64)
#define EPT 16
#define EPB (256 * EPT)                  // 4096 edges per bin-block
#define BIN_BLOCKS ((ET + EPB - 1) / EPB)
#define GEMM1_BLOCKS ((NN + 63) / 64)    // 782

__device__ inline unsigned short f2bf(float f) {
    unsigned u = __float_as_uint(f);
    u += 0x7fffu + ((u >> 16) & 1u);     // round-to-nearest-even
    return (unsigned short)(u >> 16);
}

// ---------------- F0: bin (403 blocks) || wt (32) || bound (196)
__global__ __launch_bounds__(256) void k_f0(
    const int* __restrict__ esrc, const int* __restrict__ edst,
    int* __restrict__ gcnt, unsigned* __restrict__ rec,
    const float* __restrict__ W1, float* __restrict__ Wt2,
    const int* __restrict__ batch, int* __restrict__ lo) {
    __shared__ int bcnt[NB];
    int bid = blockIdx.x, tid = threadIdx.x;
    if (bid < BIN_BLOCKS) {
        for (int b = tid; b < NB; b += 256) bcnt[b] = 0;
        __syncthreads();
        int e0 = bid * EPB;
        unsigned rv[EPT]; int bk[EPT]; int rk[EPT];
#pragma unroll
        for (int q = 0; q < EPT; ++q) {
            int e = e0 + q * 256 + tid;
            rk[q] = -1;
            if (e < ET) {
                int s, d;
                if (e < NE) { s = esrc[e]; d = edst[e]; } else { s = d = e - NE; }
                rv[q] = ((unsigned)s << 7) | (unsigned)(d & 127);
                bk[q] = d >> 7;
                rk[q] = atomicAdd(&bcnt[bk[q]], 1);
            }
        }
        __syncthreads();
        for (int b = tid; b < NB; b += 256)
            bcnt[b] = atomicAdd(&gcnt[b], bcnt[b]);
        __syncthreads();
#pragma unroll
        for (int q = 0; q < EPT; ++q) {
            if (rk[q] >= 0) rec[(size_t)bk[q] * CAP + bcnt[bk[q]] + rk[q]] = rv[q];
        }
    } else if (bid < BIN_BLOCKS + 32) {
        int id = (bid - BIN_BLOCKS) * 256 + tid;
        int k4 = id >> 6, c = id & 63;
        float4 v;
        v.x = W1[(k4 * 4 + 0) * 64 + c];
        v.y = W1[(k4 * 4 + 1) * 64 + c];
        v.z = W1[(k4 * 4 + 2) * 64 + c];
        v.w = W1[(k4 * 4 + 3) * 64 + c];
        reinterpret_cast<float4*>(Wt2)[id] = v;
    } else {
        int n = (bid - BIN_BLOCKS - 32) * 256 + tid;
        if (n >= NN) return;
        int b = batch[n];
        if (n == 0) {
            for (int g = 0; g <= b; ++g) lo[g] = 0;
        } else {
            int pb = batch[n - 1];
            for (int g = pb + 1; g <= b; ++g) lo[g] = n;
        }
        if (n == NN - 1) {
            for (int g = b + 1; g <= NG; ++g) lo[g] = NN;
        }
    }
}

// ---------------- F1: unbin2 (391 blocks, first) || gemm1 (782). LDS unioned (32 KB).
__global__ __launch_bounds__(256, 4) void k_f1(
    const int* __restrict__ gcnt, const unsigned* __restrict__ rec,
    int* __restrict__ obeg, int* __restrict__ oend, int* __restrict__ csr,
    const float* __restrict__ x, const float* __restrict__ Wt2,
    const float* __restrict__ aS, const float* __restrict__ aD,
    unsigned short* __restrict__ h1b, float* __restrict__ as1, float* __restrict__ ad1) {
    __shared__ float4 smem4[2048];    // 32 KB
    int bid = blockIdx.x, t = threadIdx.x;

    if (bid < NB) {
        // ======== unbin2 ========
        int* cnt  = reinterpret_cast<int*>(smem4);
        int* lcur = cnt + 128;
        int b = bid, tid = t;
        if (tid < 128) cnt[tid] = 0;
        __syncthreads();
        size_t base = (size_t)b * CAP;
        int nrec = gcnt[b];
        for (int i = tid; i < nrec; i += 256)
            atomicAdd(&cnt[rec[base + i] & 127], 1);
        __syncthreads();
        int v = 0, incl = 0;
        if (tid < 128) {
            int lane = tid & 63;
            v = cnt[tid];
            incl = v;
#pragma unroll
            for (int ofs = 1; ofs < 64; ofs <<= 1) {
                int o = __shfl_up(incl, ofs);
                if (lane >= ofs) incl += o;
            }
            cnt[tid] = incl;
        }
        __syncthreads();
        if (tid < 128) {
            int ex = incl - v + ((tid >= 64) ? cnt[63] : 0);
            int n = (b << 7) + tid;
            int pos = (int)base + ex;
            if (n < NN) { obeg[n] = pos; oend[n] = pos + v; }
            lcur[tid] = pos;
        }
        __syncthreads();
        for (int i = tid; i < nrec; i += 256) {
            unsigned r = rec[base + i];
            int pos = atomicAdd(&lcur[r & 127], 1);
            csr[pos] = (int)(r >> 7);
        }
    } else {
        // ======== gemm1: h1 = x @ W1 -> bf16, full-K, 64 rows/block, 8 LDS phases ========
        float4* xs  = smem4;
        float4* wsr = smem4 + 1024;
        int lane = t & 63, wv_id = t >> 6;
        int n0 = (bid - NB) * 64;

        const float4* __restrict__ xf = reinterpret_cast<const float4*>(x);
        const float4* __restrict__ wf = reinterpret_cast<const float4*>(Wt2);

        int tc = t & 15;
        int trg = t >> 4;
        int swz = (trg & 3) << 1;

        float acc[4][4];
#pragma unroll
        for (int i = 0; i < 4; ++i)
#pragma unroll
            for (int j = 0; j < 4; ++j) acc[i][j] = 0.f;

        for (int ph = 0; ph < 8; ++ph) {
            int kb4 = ph * 16;
#pragma unroll
            for (int q = 0; q < 4; ++q) {
                int base = (wv_id * 4 + q) * 64;
                int s = base + lane;
                int row = s >> 4;
                int m = s & 15;
                int k4f = m ^ ((row & 3) << 1);
                int rr = n0 + row; if (rr >= NN) rr = NN - 1;
                const float4* src = xf + (size_t)rr * 128 + kb4 + k4f;
                __builtin_amdgcn_global_load_lds(
                    (const __attribute__((address_space(1))) void*)src,
                    (__attribute__((address_space(3))) void*)&xs[base], 16, 0, 0);
            }
#pragma unroll
            for (int q = 0; q < 4; ++q) {
                int base = (wv_id * 4 + q) * 64;
                int s = base + lane;
                int k4 = s >> 6, c = s & 63;
                const float4* src = wf + (size_t)(kb4 + k4) * 64 + c;
                __builtin_amdgcn_global_load_lds(
                    (const __attribute__((address_space(1))) void*)src,
                    (__attribute__((address_space(3))) void*)&wsr[base], 16, 0, 0);
            }
            __syncthreads();

#pragma unroll 2
            for (int k4 = 0; k4 < 16; ++k4) {
                float4 wv0 = wsr[k4 * 64 + tc];
                float4 wv1 = wsr[k4 * 64 + tc + 16];
                float4 wv2 = wsr[k4 * 64 + tc + 32];
                float4 wv3 = wsr[k4 * 64 + tc + 48];
                int kx = k4 ^ swz;
                float4 xv0 = xs[(trg +  0) * 16 + kx];
                float4 xv1 = xs[(trg + 16) * 16 + kx];
                float4 xv2 = xs[(trg + 32) * 16 + kx];
                float4 xv3 = xs[(trg + 48) * 16 + kx];
#define FMA4(a, xv, wv) { a += xv.x * wv.x; a += xv.y * wv.y; a += xv.z * wv.z; a += xv.w * wv.w; }
                FMA4(acc[0][0], xv0, wv0) FMA4(acc[0][1], xv0, wv1) FMA4(acc[0][2], xv0, wv2) FMA4(acc[0][3], xv0, wv3)
                FMA4(acc[1][0], xv1, wv0) FMA4(acc[1][1], xv1, wv1) FMA4(acc[1][2], xv1, wv2) FMA4(acc[1][3], xv1, wv3)
                FMA4(acc[2][0], xv2, wv0) FMA4(acc[2][1], xv2, wv1) FMA4(acc[2][2], xv2, wv2) FMA4(acc[2][3], xv2, wv3)
                FMA4(acc[3][0], xv3, wv0) FMA4(acc[3][1], xv3, wv1) FMA4(acc[3][2], xv3, wv2) FMA4(acc[3][3], xv3, wv3)
#undef FMA4
            }
            __syncthreads();
        }

        // fused as1/ad1 (compute layout)
        int hb = tc >> 3;
        int cc = tc & 7;
#pragma unroll
        for (int i = 0; i < 4; ++i) {
            int r = n0 + trg + 16 * i;
            if (r >= NN) continue;
            float ps[4], pd[4];
#pragma unroll
            for (int j = 0; j < 4; ++j) {
                int h = 2 * j + hb;
                ps[j] = acc[i][j] * aS[h * 8 + cc];
                pd[j] = acc[i][j] * aD[h * 8 + cc];
            }
#pragma unroll
            for (int ofs = 1; ofs <= 4; ofs <<= 1) {
#pragma unroll
                for (int j = 0; j < 4; ++j) {
                    ps[j] += __shfl_xor(ps[j], ofs);
                    pd[j] += __shfl_xor(pd[j], ofs);
                }
            }
            if (cc == 0) {
#pragma unroll
                for (int j = 0; j < 4; ++j) {
                    int h = 2 * j + hb;
                    as1[r * 8 + h] = ps[j];
                    ad1[r * 8 + h] = pd[j];
                }
            }
        }

        // repack acc (cols tc+16j) -> contiguous via LDS, store bf16 ushort4
        float* hs = reinterpret_cast<float*>(smem4);   // 64x64 floats = 16 KB
#pragma unroll
        for (int i = 0; i < 4; ++i) {
            int lr = trg + 16 * i;
            hs[lr * 64 + tc]      = acc[i][0];
            hs[lr * 64 + tc + 16] = acc[i][1];
            hs[lr * 64 + tc + 32] = acc[i][2];
            hs[lr * 64 + tc + 48] = acc[i][3];
        }
        __syncthreads();
        ushort4* h1v = reinterpret_cast<ushort4*>(h1b);
#pragma unroll
        for (int i = 0; i < 4; ++i) {
            int lr = trg + 16 * i;
            int r = n0 + lr;
            if (r >= NN) continue;
            const float4* rowf = reinterpret_cast<const float4*>(&hs[lr * 64]);
            float4 fv = rowf[tc];
            ushort4 b;
            b.x = f2bf(fv.x); b.y = f2bf(fv.y); b.z = f2bf(fv.z); b.w = f2bf(fv.w);
            h1v[(size_t)r * 16 + tc] = b;
        }
    }
}

// ---------------- K4: fused layer-1 aggregation + layer-2 GEMM. h1 gathered as bf16.
__global__ __launch_bounds__(256) void k_agg1g(
    const int* __restrict__ obeg, const int* __restrict__ oend, const int* __restrict__ csr,
    const unsigned short* __restrict__ h1b, const float* __restrict__ as1, const float* __restrict__ ad1,
    const float* __restrict__ bias1, const float* __restrict__ W2,
    const float* __restrict__ aS2, const float* __restrict__ aD2,
    unsigned short* __restrict__ h2b, float* __restrict__ as2, float* __restrict__ ad2) {
    __shared__ float w2l[64 * 32];     // 8 KB
    __shared__ float h1ol[4][64];      // per-wave h1o row
    int tid = threadIdx.x;
    for (int i = tid; i < 2048; i += 256) w2l[i] = W2[i];
    __syncthreads();

    int l = tid & 63;
    int wv = tid >> 6;
    int dst = blockIdx.x * 4 + wv;
    if (dst >= NN) return;
    int g = l >> 4;            // edge slot 0..3
    int q = l & 15;            // 4-channel group: channels 4q..4q+3
    int h = q >> 1;            // head
    int beg = obeg[dst], end = oend[dst];
    int lastj = end - 1;       // deg >= 1 (self-loop)
    float adh = ad1[dst * 8 + h];
    const uint2* __restrict__ h1u = reinterpret_cast<const uint2*>(h1b);

    float4 acc = make_float4(0.f, 0.f, 0.f, 0.f);
    float dsum = 0.f;

    int sA[4], sB[4];
#pragma unroll
    for (int p = 0; p < 4; ++p) sA[p] = csr[min(beg + p * 4 + g, lastj)];
    for (int j = beg; j < end; j += 16) {
#pragma unroll
        for (int p = 0; p < 4; ++p) sB[p] = csr[min(j + 16 + p * 4 + g, lastj)];
        float av[4]; uint2 vv[4];
#pragma unroll
        for (int p = 0; p < 4; ++p) {
            av[p] = as1[sA[p] * 8 + h];
            vv[p] = h1u[(size_t)sA[p] * 16 + q];
        }
#pragma unroll
        for (int p = 0; p < 4; ++p) {
            float e = av[p] + adh; e = (e > 0.f) ? e : 0.2f * e;
            float w = __expf(e);
            w = (j + p * 4 + g < end) ? w : 0.f;
            float x0 = __uint_as_float(vv[p].x << 16);
            float x1 = __uint_as_float(vv[p].x & 0xffff0000u);
            float x2 = __uint_as_float(vv[p].y << 16);
            float x3 = __uint_as_float(vv[p].y & 0xffff0000u);
            acc.x += w * x0; acc.y += w * x1;
            acc.z += w * x2; acc.w += w * x3;
            dsum += w;
        }
#pragma unroll
        for (int p = 0; p < 4; ++p) sA[p] = sB[p];
    }

#pragma unroll
    for (int ofs = 16; ofs <= 32; ofs <<= 1) {
        acc.x += __shfl_xor(acc.x, ofs);
        acc.y += __shfl_xor(acc.y, ofs);
        acc.z += __shfl_xor(acc.z, ofs);
        acc.w += __shfl_xor(acc.w, ofs);
        dsum  += __shfl_xor(dsum, ofs);
    }

    if (g == 0) {
        float inv = 1.f / (dsum + 1e-16f);
        const float4 bq = reinterpret_cast<const float4*>(bias1)[q];
        float4 r;
        r.x = acc.x * inv + bq.x;
        r.y = acc.y * inv + bq.y;
        r.z = acc.z * inv + bq.z;
        r.w = acc.w * inv + bq.w;
        r.x = (r.x > 0.f) ? r.x : (__expf(r.x) - 1.f);
        r.y = (r.y > 0.f) ? r.y : (__expf(r.y) - 1.f);
        r.z = (r.z > 0.f) ? r.z : (__expf(r.z) - 1.f);
        r.w = (r.w > 0.f) ? r.w : (__expf(r.w) - 1.f);
        h1ol[wv][q * 4 + 0] = r.x;
        h1ol[wv][q * 4 + 1] = r.y;
        h1ol[wv][q * 4 + 2] = r.z;
        h1ol[wv][q * 4 + 3] = r.w;
    }

    // fused gemm2 (fp32 inputs from LDS); h2 stored bf16
    int c = l & 31, half = l >> 5;
    const float* hrow = h1ol[wv];
    float acc2 = 0.f;
#pragma unroll 8
    for (int kk = 0; kk < 32; ++kk) {
        int k = half * 32 + kk;
        acc2 += hrow[k] * w2l[k * 32 + c];
    }
    acc2 += __shfl_xor(acc2, 32);
    if (l < 32) h2b[(size_t)dst * 32 + c] = f2bf(acc2);
    float ps = acc2 * aS2[c], pd = acc2 * aD2[c];
#pragma unroll
    for (int ofs = 1; ofs <= 16; ofs <<= 1) {
        ps += __shfl_xor(ps, ofs);
        pd += __shfl_xor(pd, ofs);
    }
    if (l == 0) { as2[dst] = ps; ad2[dst] = pd; }
}

// ---------------- K7: layer-2 aggregation; h2 gathered as bf16. o2 fp32.
__global__ __launch_bounds__(256) void k_agg2(
    const int* __restrict__ obeg, const int* __restrict__ oend, const int* __restrict__ csr,
    const unsigned short* __restrict__ h2b, const float* __restrict__ as2, const float* __restrict__ ad2,
    const float* __restrict__ bias2, float* __restrict__ o2) {
    int l = threadIdx.x & 63;
    int dst = blockIdx.x * 4 + (threadIdx.x >> 6);
    if (dst >= NN) return;
    int g = l >> 3;            // edge slot 0..7
    int q = l & 7;             // 4-channel group: channels 4q..4q+3
    int beg = obeg[dst], end = oend[dst];
    int lastj = end - 1;
    float adh = ad2[dst];
    const uint2* __restrict__ h2u = reinterpret_cast<const uint2*>(h2b);

    float4 acc = make_float4(0.f, 0.f, 0.f, 0.f);
    float dsum = 0.f;

    int sA[4], sB[4];
#pragma unroll
    for (int p = 0; p < 4; ++p) sA[p] = csr[min(beg + p * 8 + g, lastj)];
    for (int j = beg; j < end; j += 32) {
#pragma unroll
        for (int p = 0; p < 4; ++p) sB[p] = csr[min(j + 32 + p * 8 + g, lastj)];
        float av[4]; uint2 vv[4];
#pragma unroll
        for (int p = 0; p < 4; ++p) {
            av[p] = as2[sA[p]];
            vv[p] = h2u[(size_t)sA[p] * 8 + q];
        }
#pragma unroll
        for (int p = 0; p < 4; ++p) {
            float e = av[p] + adh; e = (e > 0.f) ? e : 0.2f * e;
            float w = __expf(e);
            w = (j + p * 8 + g < end) ? w : 0.f;
            float x0 = __uint_as_float(vv[p].x << 16);
            float x1 = __uint_as_float(vv[p].x & 0xffff0000u);
            float x2 = __uint_as_float(vv[p].y << 16);
            float x3 = __uint_as_float(vv[p].y & 0xffff0000u);
            acc.x += w * x0; acc.y += w * x1;
            acc.z += w * x2; acc.w += w * x3;
            dsum += w;
        }
#pragma unroll
        for (int p = 0; p < 4; ++p) sA[p] = sB[p];
    }

#pragma unroll
    for (int ofs = 8; ofs <= 32; ofs <<= 1) {
        acc.x += __shfl_xor(acc.x, ofs);
        acc.y += __shfl_xor(acc.y, ofs);
        acc.z += __shfl_xor(acc.z, ofs);
        acc.w += __shfl_xor(acc.w, ofs);
        dsum  += __shfl_xor(dsum, ofs);
    }

    if (g == 0) {
        float inv = 1.f / (dsum + 1e-16f);
        const float4 bq = reinterpret_cast<const float4*>(bias2)[q];
        float4 r;
        r.x = acc.x * inv + bq.x;
        r.y = acc.y * inv + bq.y;
        r.z = acc.z * inv + bq.z;
        r.w = acc.w * inv + bq.w;
        reinterpret_cast<float4*>(o2)[dst * 8 + q] = r;
    }
}

// ---------------- K9: pooled sums.
__global__ __launch_bounds__(256) void k_pool(const float* __restrict__ o2, const int* __restrict__ lo,
                                              float* __restrict__ pooled) {
    __shared__ float red[256];
    int g = blockIdx.x & 63, q = blockIdx.x >> 6;
    int beg = lo[g], end = lo[g + 1];
    int c = threadIdx.x & 31, row = threadIdx.x >> 5;
    float s = 0.f;
    for (int n = beg + q * 8 + row; n < end; n += 32) s += o2[n * 32 + c];
    red[threadIdx.x] = s;
    __syncthreads();
    for (int rr = 4; rr >= 1; rr >>= 1) {
        if (row < rr) red[threadIdx.x] += red[(row + rr) * 32 + c];
        __syncthreads();
    }
    if (row == 0) atomicAdd(&pooled[g * 32 + c], red[c]);
}

// ---------------- K10: mean + final linear -> out[64][2]
__global__ void k_fin(const float* __restrict__ pooled, const int* __restrict__ lo,
                      const float* __restrict__ lw, const float* __restrict__ lb,
                      float* __restrict__ out) {
    int t = threadIdx.x;
    if (t >= 128) return;
    int g = t >> 1, o = t & 1;
    int cnt = lo[g + 1] - lo[g];
    float inv = 1.f / fmaxf((float)cnt, 1.f);
    float s = 0.f;
#pragma unroll
    for (int c = 0; c < 32; ++c) s += pooled[g * 32 + c] * lw[c * 2 + o];
    out[g * 2 + o] = s * inv + lb[o];
}

// ----------------------------------------------------------------------------
extern "C" void kernel_launch(void* const* d_in, const int* in_sizes, int n_in,
                              void* d_out, int out_size, void* d_ws, size_t ws_size,
                              hipStream_t stream) {
    const float* x   = (const float*)d_in[0];
    const int*   ei  = (const int*)d_in[1];     // [2][NE]
    const int*   bat = (const int*)d_in[2];
    const float* W1  = (const float*)d_in[3];
    const float* aS1 = (const float*)d_in[4];
    const float* aD1 = (const float*)d_in[5];
    const float* b1  = (const float*)d_in[6];
    const float* W2  = (const float*)d_in[7];
    const float* aS2 = (const float*)d_in[8];
    const float* aD2 = (const float*)d_in[9];
    const float* b2  = (const float*)d_in[10];
    const float* lw  = (const float*)d_in[11];
    const float* lb  = (const float*)d_in[12];
    float* out = (float*)d_out;

    const int* esrc = ei;
    const int* edst = ei + NE;

    char* ws = (char*)d_ws;
    size_t off = 0;
    auto alloc = [&](size_t bytes) -> void* {
        off = (off + 255) & ~(size_t)255;
        void* p = ws + off;
        off += bytes;
        return p;
    };

    unsigned short* h1b = (unsigned short*)alloc((size_t)NN * 64 * 2);
    unsigned short* h2b = (unsigned short*)alloc((size_t)NN * 32 * 2);
    float* o2   = (float*)alloc((size_t)NN * 32 * 4);
    float* as1  = (float*)alloc((size_t)NN * 8 * 4);
    float* ad1  = (float*)alloc((size_t)NN * 8 * 4);
    float* as2  = (float*)alloc((size_t)NN * 4);
    float* ad2  = (float*)alloc((size_t)NN * 4);
    int*   obeg = (int*)alloc((size_t)NN * 4);
    int*   oend = (int*)alloc((size_t)NN * 4);
    int*   csr  = (int*)alloc((size_t)NB * CAP * 4);
    unsigned* rec = (unsigned*)alloc((size_t)NB * CAP * 4);
    int*   gcnt = (int*)alloc((size_t)NB * 4);
    float* Wt2  = (float*)alloc((size_t)512 * 64 * 4);
    float* pooled = (float*)alloc((size_t)NG * 32 * 4);
    int*   lo   = (int*)alloc((size_t)(NG + 1) * 4);
    if (off > ws_size) return;   // workspace too small: leave d_out poisoned (visible failure)

    hipMemsetAsync(gcnt, 0, (size_t)NB * 4, stream);
    hipMemsetAsync(pooled, 0, (size_t)NG * 32 * 4, stream);

    k_f0<<<BIN_BLOCKS + 32 + SCAN_BLOCKS, 256, 0, stream>>>(
        esrc, edst, gcnt, rec, W1, Wt2, bat, lo);
    k_f1<<<NB + GEMM1_BLOCKS, 256, 0, stream>>>(
        gcnt, rec, obeg, oend, csr, x, Wt2, aS1, aD1, h1b, as1, ad1);

    k_agg1g<<<(NN + 3) / 4, 256, 0, stream>>>(obeg, oend, csr, h1b, as1, ad1, b1,
                                              W2, aS2, aD2, h2b, as2, ad2);
    k_agg2<<<(NN + 3) / 4, 256, 0, stream>>>(obeg, oend, csr, h2b, as2, ad2, b2, o2);

    k_pool<<<NG * 4, 256, 0, stream>>>(o2, lo, pooled);
    k_fin<<<1, 128, 0, stream>>>(pooled, lo, lw, lb, out);
}

// Round 23
// 152.498 us; speedup vs baseline: 1.7955x; 1.2207x over previous
//
#include <hip/hip_runtime.h>
#include <cstdint>
#include <cstddef>

#define NN 50000
#define NE 1600000
#define ET (NE + NN)          // edges + self loops
#define NG 64
#define SCAN_BLOCKS ((NN + 255) / 256)   // 196
#define NB ((NN + 127) >> 7)             // 391 dst-buckets, 128 nodes each
#define CAP 6144                         // slots per bucket segment
#define EPT 16
#define EPB (256 * EPT)                  // 4096 edges per bin-block
#define BIN_BLOCKS ((ET + EPB - 1) / EPB)
#define GEMM1_BLOCKS ((NN + 63) / 64)    // 782
#define WFRAG_BLOCKS 16                  // 4096 frag-slots / 256

typedef __attribute__((ext_vector_type(8))) short short8v;
typedef __attribute__((ext_vector_type(4))) float f32x4;

__device__ inline unsigned short f2bf(float f) {
    unsigned u = __float_as_uint(f);
    u += 0x7fffu + ((u >> 16) & 1u);     // round-to-nearest-even
    return (unsigned short)(u >> 16);
}

// ---------------- F0: bin (403) || wfrag (16) || bound (196)
__global__ __launch_bounds__(256) void k_f0(
    const int* __restrict__ esrc, const int* __restrict__ edst,
    int* __restrict__ gcnt, unsigned* __restrict__ rec,
    const float* __restrict__ W1, unsigned short* __restrict__ w1f,
    const int* __restrict__ batch, int* __restrict__ lo) {
    __shared__ int bcnt[NB];
    int bid = blockIdx.x, tid = threadIdx.x;
    if (bid < BIN_BLOCKS) {
        for (int b = tid; b < NB; b += 256) bcnt[b] = 0;
        __syncthreads();
        int e0 = bid * EPB;
        unsigned rv[EPT]; int bk[EPT]; int rk[EPT];
#pragma unroll
        for (int q = 0; q < EPT; ++q) {
            int e = e0 + q * 256 + tid;
            rk[q] = -1;
            if (e < ET) {
                int s, d;
                if (e < NE) { s = esrc[e]; d = edst[e]; } else { s = d = e - NE; }
                rv[q] = ((unsigned)s << 7) | (unsigned)(d & 127);
                bk[q] = d >> 7;
                rk[q] = atomicAdd(&bcnt[bk[q]], 1);
            }
        }
        __syncthreads();
        for (int b = tid; b < NB; b += 256)
            bcnt[b] = atomicAdd(&gcnt[b], bcnt[b]);
        __syncthreads();
#pragma unroll
        for (int q = 0; q < EPT; ++q) {
            if (rk[q] >= 0) rec[(size_t)bk[q] * CAP + bcnt[bk[q]] + rk[q]] = rv[q];
        }
    } else if (bid < BIN_BLOCKS + WFRAG_BLOCKS) {
        // ---- wfrag: pack W1 (512x64 fp32) into MFMA B-fragment order, bf16.
        // slot = (S,ct,l): value j -> W1[S*32 + (l>>4)*8 + j][ct*16 + (l&15)]
        int slot = (bid - BIN_BLOCKS) * 256 + tid;   // 0..4095
        int S = slot >> 8;
        int ct = (slot >> 6) & 3;
        int l = slot & 63;
        int kb = S * 32 + ((l >> 4) << 3);
        int c = ct * 16 + (l & 15);
        unsigned short* dst = w1f + (size_t)slot * 8;
#pragma unroll
        for (int j = 0; j < 8; ++j)
            dst[j] = f2bf(W1[(kb + j) * 64 + c]);
    } else {
        int n = (bid - BIN_BLOCKS - WFRAG_BLOCKS) * 256 + tid;
        if (n >= NN) return;
        int b = batch[n];
        if (n == 0) {
            for (int g = 0; g <= b; ++g) lo[g] = 0;
        } else {
            int pb = batch[n - 1];
            for (int g = pb + 1; g <= b; ++g) lo[g] = n;
        }
        if (n == NN - 1) {
            for (int g = b + 1; g <= NG; ++g) lo[g] = NN;
        }
    }
}

// ---------------- F1: unbin2 (391 blocks) || gemm1-MFMA (782). LDS unioned (32 KB).
__global__ __launch_bounds__(256, 4) void k_f1(
    const int* __restrict__ gcnt, const unsigned* __restrict__ rec,
    int* __restrict__ obeg, int* __restrict__ oend, int* __restrict__ csr,
    const float* __restrict__ x, const unsigned short* __restrict__ w1f,
    const float* __restrict__ aS, const float* __restrict__ aD,
    unsigned short* __restrict__ h1b, float* __restrict__ as1, float* __restrict__ ad1) {
    __shared__ float4 smem4[2048];    // 32 KB
    int bid = blockIdx.x, t = threadIdx.x;

    if (bid < NB) {
        // ======== unbin2 ========
        int* cnt  = reinterpret_cast<int*>(smem4);
        int* lcur = cnt + 128;
        int b = bid, tid = t;
        if (tid < 128) cnt[tid] = 0;
        __syncthreads();
        size_t base = (size_t)b * CAP;
        int nrec = gcnt[b];
        for (int i = tid; i < nrec; i += 256)
            atomicAdd(&cnt[rec[base + i] & 127], 1);
        __syncthreads();
        int v = 0, incl = 0;
        if (tid < 128) {
            int lane = tid & 63;
            v = cnt[tid];
            incl = v;
#pragma unroll
            for (int ofs = 1; ofs < 64; ofs <<= 1) {
                int o = __shfl_up(incl, ofs);
                if (lane >= ofs) incl += o;
            }
            cnt[tid] = incl;
        }
        __syncthreads();
        if (tid < 128) {
            int ex = incl - v + ((tid >= 64) ? cnt[63] : 0);
            int n = (b << 7) + tid;
            int pos = (int)base + ex;
            if (n < NN) { obeg[n] = pos; oend[n] = pos + v; }
            lcur[tid] = pos;
        }
        __syncthreads();
        for (int i = tid; i < nrec; i += 256) {
            unsigned r = rec[base + i];
            int pos = atomicAdd(&lcur[r & 127], 1);
            csr[pos] = (int)(r >> 7);
        }
    } else {
        // ======== gemm1-MFMA: h1 = x @ W1 -> bf16; 64 rows/block, 2 K-phases x 8 steps ========
        unsigned short* bl = reinterpret_cast<unsigned short*>(smem4);  // 16384 ushorts
        int w = t >> 6, l = t & 63;
        int n0 = (bid - NB) * 64;
        int rrow = n0 + w * 16 + (l & 15);                // A-load row for this lane
        int rc = (rrow < NN) ? rrow : (NN - 1);
        const float* __restrict__ xr = x + (size_t)rc * 512;

        f32x4 acc0 = {0.f, 0.f, 0.f, 0.f};
        f32x4 acc1 = {0.f, 0.f, 0.f, 0.f};
        f32x4 acc2 = {0.f, 0.f, 0.f, 0.f};
        f32x4 acc3 = {0.f, 0.f, 0.f, 0.f};

        for (int p = 0; p < 2; ++p) {
            // stage B-frags for this phase: linear 32 KB copy, 8 x 16B per lane per wave
#pragma unroll
            for (int q = 0; q < 8; ++q) {
                int off = (w * 8 + q) * 512;              // ushort offset, wave-uniform base
                const unsigned short* src = w1f + (size_t)p * 16384 + off + (size_t)l * 8;
                __builtin_amdgcn_global_load_lds(
                    (const __attribute__((address_space(1))) void*)src,
                    (__attribute__((address_space(3))) void*)&bl[off], 16, 0, 0);
            }
            __syncthreads();

#pragma unroll
            for (int s8 = 0; s8 < 8; ++s8) {
                int k0 = (p * 8 + s8) * 32 + ((l >> 4) << 3);
                const float4* xp = reinterpret_cast<const float4*>(xr + k0);
                float4 a0 = xp[0];
                float4 a1 = xp[1];
                short8v af;
                af[0] = (short)f2bf(a0.x); af[1] = (short)f2bf(a0.y);
                af[2] = (short)f2bf(a0.z); af[3] = (short)f2bf(a0.w);
                af[4] = (short)f2bf(a1.x); af[5] = (short)f2bf(a1.y);
                af[6] = (short)f2bf(a1.z); af[7] = (short)f2bf(a1.w);
                const short8v* bfp = reinterpret_cast<const short8v*>(&bl[(size_t)(s8 * 4) * 512 + (size_t)l * 8]);
                // bfp[ct*64... ] stride between ct groups = 64 lanes * 8 = 512 ushorts = 64 short8v
                short8v bf0 = bfp[0];
                short8v bf1 = bfp[64];
                short8v bf2 = bfp[128];
                short8v bf3 = bfp[192];
                acc0 = __builtin_amdgcn_mfma_f32_16x16x32_bf16(af, bf0, acc0, 0, 0, 0);
                acc1 = __builtin_amdgcn_mfma_f32_16x16x32_bf16(af, bf1, acc1, 0, 0, 0);
                acc2 = __builtin_amdgcn_mfma_f32_16x16x32_bf16(af, bf2, acc2, 0, 0, 0);
                acc3 = __builtin_amdgcn_mfma_f32_16x16x32_bf16(af, bf3, acc3, 0, 0, 0);
            }
            __syncthreads();   // all waves done reading bl before restage
        }

        // epilogue: C/D layout col=lane&15, row=(lane>>4)*4+reg (m89-verified)
        int hi = (l & 15) >> 3;   // which half of a 16-col tile -> head parity
        int cc = l & 7;           // channel within head
#pragma unroll
        for (int reg = 0; reg < 4; ++reg) {
            int row16 = ((l >> 4) << 2) + reg;
            int r = n0 + w * 16 + row16;
            float v0 = acc0[reg], v1 = acc1[reg], v2 = acc2[reg], v3 = acc3[reg];
            if (r < NN) {
                unsigned short* hp = h1b + (size_t)r * 64 + (l & 15);
                hp[0]  = f2bf(v0);
                hp[16] = f2bf(v1);
                hp[32] = f2bf(v2);
                hp[48] = f2bf(v3);
            }
            float ps[4], pd[4];
            float vv[4] = {v0, v1, v2, v3};
#pragma unroll
            for (int ct = 0; ct < 4; ++ct) {
                int h = ct * 2 + hi;
                ps[ct] = vv[ct] * aS[h * 8 + cc];
                pd[ct] = vv[ct] * aD[h * 8 + cc];
            }
#pragma unroll
            for (int ofs = 1; ofs <= 4; ofs <<= 1) {
#pragma unroll
                for (int ct = 0; ct < 4; ++ct) {
                    ps[ct] += __shfl_xor(ps[ct], ofs);
                    pd[ct] += __shfl_xor(pd[ct], ofs);
                }
            }
            if (cc == 0 && r < NN) {
#pragma unroll
                for (int ct = 0; ct < 4; ++ct) {
                    int h = ct * 2 + hi;
                    as1[r * 8 + h] = ps[ct];
                    ad1[r * 8 + h] = pd[ct];
                }
            }
        }
    }
}

// ---------------- K4: fused layer-1 aggregation + layer-2 GEMM. h1 gathered as bf16.
__global__ __launch_bounds__(256) void k_agg1g(
    const int* __restrict__ obeg, const int* __restrict__ oend, const int* __restrict__ csr,
    const unsigned short* __restrict__ h1b, const float* __restrict__ as1, const float* __restrict__ ad1,
    const float* __restrict__ bias1, const float* __restrict__ W2,
    const float* __restrict__ aS2, const float* __restrict__ aD2,
    unsigned short* __restrict__ h2b, float* __restrict__ as2, float* __restrict__ ad2) {
    __shared__ float w2l[64 * 32];     // 8 KB
    __shared__ float h1ol[4][64];      // per-wave h1o row
    int tid = threadIdx.x;
    for (int i = tid; i < 2048; i += 256) w2l[i] = W2[i];
    __syncthreads();

    int l = tid & 63;
    int wv = tid >> 6;
    int dst = blockIdx.x * 4 + wv;
    if (dst >= NN) return;
    int g = l >> 4;            // edge slot 0..3
    int q = l & 15;            // 4-channel group
    int h = q >> 1;            // head
    int beg = obeg[dst], end = oend[dst];
    int lastj = end - 1;
    float adh = ad1[dst * 8 + h];
    const uint2* __restrict__ h1u = reinterpret_cast<const uint2*>(h1b);

    float4 acc = make_float4(0.f, 0.f, 0.f, 0.f);
    float dsum = 0.f;

    int sA[4], sB[4];
#pragma unroll
    for (int p = 0; p < 4; ++p) sA[p] = csr[min(beg + p * 4 + g, lastj)];
    for (int j = beg; j < end; j += 16) {
#pragma unroll
        for (int p = 0; p < 4; ++p) sB[p] = csr[min(j + 16 + p * 4 + g, lastj)];
        float av[4]; uint2 vv[4];
#pragma unroll
        for (int p = 0; p < 4; ++p) {
            av[p] = as1[sA[p] * 8 + h];
            vv[p] = h1u[(size_t)sA[p] * 16 + q];
        }
#pragma unroll
        for (int p = 0; p < 4; ++p) {
            float e = av[p] + adh; e = (e > 0.f) ? e : 0.2f * e;
            float w = __expf(e);
            w = (j + p * 4 + g < end) ? w : 0.f;
            float x0 = __uint_as_float(vv[p].x << 16);
            float x1 = __uint_as_float(vv[p].x & 0xffff0000u);
            float x2 = __uint_as_float(vv[p].y << 16);
            float x3 = __uint_as_float(vv[p].y & 0xffff0000u);
            acc.x += w * x0; acc.y += w * x1;
            acc.z += w * x2; acc.w += w * x3;
            dsum += w;
        }
#pragma unroll
        for (int p = 0; p < 4; ++p) sA[p] = sB[p];
    }

#pragma unroll
    for (int ofs = 16; ofs <= 32; ofs <<= 1) {
        acc.x += __shfl_xor(acc.x, ofs);
        acc.y += __shfl_xor(acc.y, ofs);
        acc.z += __shfl_xor(acc.z, ofs);
        acc.w += __shfl_xor(acc.w, ofs);
        dsum  += __shfl_xor(dsum, ofs);
    }

    if (g == 0) {
        float inv = 1.f / (dsum + 1e-16f);
        const float4 bq = reinterpret_cast<const float4*>(bias1)[q];
        float4 r;
        r.x = acc.x * inv + bq.x;
        r.y = acc.y * inv + bq.y;
        r.z = acc.z * inv + bq.z;
        r.w = acc.w * inv + bq.w;
        r.x = (r.x > 0.f) ? r.x : (__expf(r.x) - 1.f);
        r.y = (r.y > 0.f) ? r.y : (__expf(r.y) - 1.f);
        r.z = (r.z > 0.f) ? r.z : (__expf(r.z) - 1.f);
        r.w = (r.w > 0.f) ? r.w : (__expf(r.w) - 1.f);
        h1ol[wv][q * 4 + 0] = r.x;
        h1ol[wv][q * 4 + 1] = r.y;
        h1ol[wv][q * 4 + 2] = r.z;
        h1ol[wv][q * 4 + 3] = r.w;
    }

    // fused gemm2; h2 stored bf16
    int c = l & 31, half = l >> 5;
    const float* hrow = h1ol[wv];
    float acc2 = 0.f;
#pragma unroll 8
    for (int kk = 0; kk < 32; ++kk) {
        int k = half * 32 + kk;
        acc2 += hrow[k] * w2l[k * 32 + c];
    }
    acc2 += __shfl_xor(acc2, 32);
    if (l < 32) h2b[(size_t)dst * 32 + c] = f2bf(acc2);
    float ps = acc2 * aS2[c], pd = acc2 * aD2[c];
#pragma unroll
    for (int ofs = 1; ofs <= 16; ofs <<= 1) {
        ps += __shfl_xor(ps, ofs);
        pd += __shfl_xor(pd, ofs);
    }
    if (l == 0) { as2[dst] = ps; ad2[dst] = pd; }
}

// ---------------- K7: layer-2 aggregation; h2 gathered as bf16. o2 fp32.
__global__ __launch_bounds__(256) void k_agg2(
    const int* __restrict__ obeg, const int* __restrict__ oend, const int* __restrict__ csr,
    const unsigned short* __restrict__ h2b, const float* __restrict__ as2, const float* __restrict__ ad2,
    const float* __restrict__ bias2, float* __restrict__ o2) {
    int l = threadIdx.x & 63;
    int dst = blockIdx.x * 4 + (threadIdx.x >> 6);
    if (dst >= NN) return;
    int g = l >> 3;            // edge slot 0..7
    int q = l & 7;             // 4-channel group
    int beg = obeg[dst], end = oend[dst];
    int lastj = end - 1;
    float adh = ad2[dst];
    const uint2* __restrict__ h2u = reinterpret_cast<const uint2*>(h2b);

    float4 acc = make_float4(0.f, 0.f, 0.f, 0.f);
    float dsum = 0.f;

    int sA[4], sB[4];
#pragma unroll
    for (int p = 0; p < 4; ++p) sA[p] = csr[min(beg + p * 8 + g, lastj)];
    for (int j = beg; j < end; j += 32) {
#pragma unroll
        for (int p = 0; p < 4; ++p) sB[p] = csr[min(j + 32 + p * 8 + g, lastj)];
        float av[4]; uint2 vv[4];
#pragma unroll
        for (int p = 0; p < 4; ++p) {
            av[p] = as2[sA[p]];
            vv[p] = h2u[(size_t)sA[p] * 8 + q];
        }
#pragma unroll
        for (int p = 0; p < 4; ++p) {
            float e = av[p] + adh; e = (e > 0.f) ? e : 0.2f * e;
            float w = __expf(e);
            w = (j + p * 8 + g < end) ? w : 0.f;
            float x0 = __uint_as_float(vv[p].x << 16);
            float x1 = __uint_as_float(vv[p].x & 0xffff0000u);
            float x2 = __uint_as_float(vv[p].y << 16);
            float x3 = __uint_as_float(vv[p].y & 0xffff0000u);
            acc.x += w * x0; acc.y += w * x1;
            acc.z += w * x2; acc.w += w * x3;
            dsum += w;
        }
#pragma unroll
        for (int p = 0; p < 4; ++p) sA[p] = sB[p];
    }

#pragma unroll
    for (int ofs = 8; ofs <= 32; ofs <<= 1) {
        acc.x += __shfl_xor(acc.x, ofs);
        acc.y += __shfl_xor(acc.y, ofs);
        acc.z += __shfl_xor(acc.z, ofs);
        acc.w += __shfl_xor(acc.w, ofs);
        dsum  += __shfl_xor(dsum, ofs);
    }

    if (g == 0) {
        float inv = 1.f / (dsum + 1e-16f);
        const float4 bq = reinterpret_cast<const float4*>(bias2)[q];
        float4 r;
        r.x = acc.x * inv + bq.x;
        r.y = acc.y * inv + bq.y;
        r.z = acc.z * inv + bq.z;
        r.w = acc.w * inv + bq.w;
        reinterpret_cast<float4*>(o2)[dst * 8 + q] = r;
    }
}

// ---------------- K9: pooled sums.
__global__ __launch_bounds__(256) void k_pool(const float* __restrict__ o2, const int* __restrict__ lo,
                                              float* __restrict__ pooled) {
    __shared__ float red[256];
    int g = blockIdx.x & 63, q = blockIdx.x >> 6;
    int beg = lo[g], end = lo[g + 1];
    int c = threadIdx.x & 31, row = threadIdx.x >> 5;
    float s = 0.f;
    for (int n = beg + q * 8 + row; n < end; n += 32) s += o2[n * 32 + c];
    red[threadIdx.x] = s;
    __syncthreads();
    for (int rr = 4; rr >= 1; rr >>= 1) {
        if (row < rr) red[threadIdx.x] += red[(row + rr) * 32 + c];
        __syncthreads();
    }
    if (row == 0) atomicAdd(&pooled[g * 32 + c], red[c]);
}

// ---------------- K10: mean + final linear -> out[64][2]
__global__ void k_fin(const float* __restrict__ pooled, const int* __restrict__ lo,
                      const float* __restrict__ lw, const float* __restrict__ lb,
                      float* __restrict__ out) {
    int t = threadIdx.x;
    if (t >= 128) return;
    int g = t >> 1, o = t & 1;
    int cnt = lo[g + 1] - lo[g];
    float inv = 1.f / fmaxf((float)cnt, 1.f);
    float s = 0.f;
#pragma unroll
    for (int c = 0; c < 32; ++c) s += pooled[g * 32 + c] * lw[c * 2 + o];
    out[g * 2 + o] = s * inv + lb[o];
}

// ----------------------------------------------------------------------------
extern "C" void kernel_launch(void* const* d_in, const int* in_sizes, int n_in,
                              void* d_out, int out_size, void* d_ws, size_t ws_size,
                              hipStream_t stream) {
    const float* x   = (const float*)d_in[0];
    const int*   ei  = (const int*)d_in[1];     // [2][NE]
    const int*   bat = (const int*)d_in[2];
    const float* W1  = (const float*)d_in[3];
    const float* aS1 = (const float*)d_in[4];
    const float* aD1 = (const float*)d_in[5];
    const float* b1  = (const float*)d_in[6];
    const float* W2  = (const float*)d_in[7];
    const float* aS2 = (const float*)d_in[8];
    const float* aD2 = (const float*)d_in[9];
    const float* b2  = (const float*)d_in[10];
    const float* lw  = (const float*)d_in[11];
    const float* lb  = (const float*)d_in[12];
    float* out = (float*)d_out;

    const int* esrc = ei;
    const int* edst = ei + NE;

    char* ws = (char*)d_ws;
    size_t off = 0;
    auto alloc = [&](size_t bytes) -> void* {
        off = (off + 255) & ~(size_t)255;
        void* p = ws + off;
        off += bytes;
        return p;
    };

    unsigned short* h1b = (unsigned short*)alloc((size_t)NN * 64 * 2);
    unsigned short* h2b = (unsigned short*)alloc((size_t)NN * 32 * 2);
    float* o2   = (float*)alloc((size_t)NN * 32 * 4);
    float* as1  = (float*)alloc((size_t)NN * 8 * 4);
    float* ad1  = (float*)alloc((size_t)NN * 8 * 4);
    float* as2  = (float*)alloc((size_t)NN * 4);
    float* ad2  = (float*)alloc((size_t)NN * 4);
    int*   obeg = (int*)alloc((size_t)NN * 4);
    int*   oend = (int*)alloc((size_t)NN * 4);
    int*   csr  = (int*)alloc((size_t)NB * CAP * 4);
    unsigned* rec = (unsigned*)alloc((size_t)NB * CAP * 4);
    int*   gcnt = (int*)alloc((size_t)NB * 4);
    unsigned short* w1f = (unsigned short*)alloc((size_t)512 * 64 * 2);
    float* pooled = (float*)alloc((size_t)NG * 32 * 4);
    int*   lo   = (int*)alloc((size_t)(NG + 1) * 4);
    if (off > ws_size) return;   // workspace too small: leave d_out poisoned (visible failure)

    hipMemsetAsync(gcnt, 0, (size_t)NB * 4, stream);
    hipMemsetAsync(pooled, 0, (size_t)NG * 32 * 4, stream);

    k_f0<<<BIN_BLOCKS + WFRAG_BLOCKS + SCAN_BLOCKS, 256, 0, stream>>>(
        esrc, edst, gcnt, rec, W1, w1f, bat, lo);
    k_f1<<<NB + GEMM1_BLOCKS, 256, 0, stream>>>(
        gcnt, rec, obeg, oend, csr, x, w1f, aS1, aD1, h1b, as1, ad1);

    k_agg1g<<<(NN + 3) / 4, 256, 0, stream>>>(obeg, oend, csr, h1b, as1, ad1, b1,
                                              W2, aS2, aD2, h2b, as2, ad2);
    k_agg2<<<(NN + 3) / 4, 256, 0, stream>>>(obeg, oend, csr, h2b, as2, ad2, b2, o2);

    k_pool<<<NG * 4, 256, 0, stream>>>(o2, lo, pooled);
    k_fin<<<1, 128, 0, stream>>>(pooled, lo, lw, lb, out);
}

// Round 24
// 151.519 us; speedup vs baseline: 1.8071x; 1.0065x over previous
//
#include <hip/hip_runtime.h>
#include <cstdint>
#include <cstddef>

#define NN 50000
#define NE 1600000
#define ET (NE + NN)          // edges + self loops
#define NG 64
#define SCAN_BLOCKS ((NN + 255) / 256)   // 196
#define NB ((NN + 127) >> 7)             // 391 dst-buckets, 128 nodes each
#define CAP 6144                         // slots per bucket segment
#define EPT 16
#define EPB (256 * EPT)                  // 4096 edges per bin-block
#define BIN_BLOCKS ((ET + EPB - 1) / EPB)
#define GEMM1_BLOCKS ((NN + 63) / 64)    // 782
#define WFRAG_BLOCKS 16                  // 4096 frag-slots / 256

typedef __attribute__((ext_vector_type(8))) short short8v;
typedef __attribute__((ext_vector_type(4))) float f32x4;

__device__ inline unsigned short f2bf(float f) {
    unsigned u = __float_as_uint(f);
    u += 0x7fffu + ((u >> 16) & 1u);     // round-to-nearest-even
    return (unsigned short)(u >> 16);
}

// ---------------- F0: bin (403) || wfrag (16) || bound (196)
__global__ __launch_bounds__(256) void k_f0(
    const int* __restrict__ esrc, const int* __restrict__ edst,
    int* __restrict__ gcnt, unsigned* __restrict__ rec,
    const float* __restrict__ W1, unsigned short* __restrict__ w1f,
    const int* __restrict__ batch, int* __restrict__ lo) {
    __shared__ int bcnt[NB];
    int bid = blockIdx.x, tid = threadIdx.x;
    if (bid < BIN_BLOCKS) {
        for (int b = tid; b < NB; b += 256) bcnt[b] = 0;
        __syncthreads();
        int e0 = bid * EPB;
        unsigned rv[EPT]; int bk[EPT]; int rk[EPT];
#pragma unroll
        for (int q = 0; q < EPT; ++q) {
            int e = e0 + q * 256 + tid;
            rk[q] = -1;
            if (e < ET) {
                int s, d;
                if (e < NE) { s = esrc[e]; d = edst[e]; } else { s = d = e - NE; }
                rv[q] = ((unsigned)s << 7) | (unsigned)(d & 127);
                bk[q] = d >> 7;
                rk[q] = atomicAdd(&bcnt[bk[q]], 1);
            }
        }
        __syncthreads();
        for (int b = tid; b < NB; b += 256)
            bcnt[b] = atomicAdd(&gcnt[b], bcnt[b]);
        __syncthreads();
#pragma unroll
        for (int q = 0; q < EPT; ++q) {
            if (rk[q] >= 0) rec[(size_t)bk[q] * CAP + bcnt[bk[q]] + rk[q]] = rv[q];
        }
    } else if (bid < BIN_BLOCKS + WFRAG_BLOCKS) {
        // ---- wfrag: pack W1 (512x64 fp32) into MFMA B-fragment order, bf16.
        // slot = (S,ct,l): value j -> W1[S*32 + (l>>4)*8 + j][ct*16 + (l&15)]
        int slot = (bid - BIN_BLOCKS) * 256 + tid;   // 0..4095
        int S = slot >> 8;
        int ct = (slot >> 6) & 3;
        int l = slot & 63;
        int kb = S * 32 + ((l >> 4) << 3);
        int c = ct * 16 + (l & 15);
        unsigned short* dst = w1f + (size_t)slot * 8;
#pragma unroll
        for (int j = 0; j < 8; ++j)
            dst[j] = f2bf(W1[(kb + j) * 64 + c]);
    } else {
        int n = (bid - BIN_BLOCKS - WFRAG_BLOCKS) * 256 + tid;
        if (n >= NN) return;
        int b = batch[n];
        if (n == 0) {
            for (int g = 0; g <= b; ++g) lo[g] = 0;
        } else {
            int pb = batch[n - 1];
            for (int g = pb + 1; g <= b; ++g) lo[g] = n;
        }
        if (n == NN - 1) {
            for (int g = b + 1; g <= NG; ++g) lo[g] = NN;
        }
    }
}

// ---------------- F1: unbin2 (391 blocks) || gemm1-MFMA barrier-free (782).
__global__ __launch_bounds__(256, 8) void k_f1(
    const int* __restrict__ gcnt, const unsigned* __restrict__ rec,
    int* __restrict__ obeg, int* __restrict__ oend, int* __restrict__ csr,
    const float* __restrict__ x, const unsigned short* __restrict__ w1f,
    const float* __restrict__ aS, const float* __restrict__ aD,
    unsigned short* __restrict__ h1b, float* __restrict__ as1, float* __restrict__ ad1) {
    __shared__ int sm[256];           // 1 KB, unbin2 only
    int bid = blockIdx.x, t = threadIdx.x;

    if (bid < NB) {
        // ======== unbin2 ========
        int* cnt  = sm;
        int* lcur = sm + 128;
        int b = bid, tid = t;
        if (tid < 128) cnt[tid] = 0;
        __syncthreads();
        size_t base = (size_t)b * CAP;
        int nrec = gcnt[b];
        for (int i = tid; i < nrec; i += 256)
            atomicAdd(&cnt[rec[base + i] & 127], 1);
        __syncthreads();
        int v = 0, incl = 0;
        if (tid < 128) {
            int lane = tid & 63;
            v = cnt[tid];
            incl = v;
#pragma unroll
            for (int ofs = 1; ofs < 64; ofs <<= 1) {
                int o = __shfl_up(incl, ofs);
                if (lane >= ofs) incl += o;
            }
            cnt[tid] = incl;
        }
        __syncthreads();
        if (tid < 128) {
            int ex = incl - v + ((tid >= 64) ? cnt[63] : 0);
            int n = (b << 7) + tid;
            int pos = (int)base + ex;
            if (n < NN) { obeg[n] = pos; oend[n] = pos + v; }
            lcur[tid] = pos;
        }
        __syncthreads();
        for (int i = tid; i < nrec; i += 256) {
            unsigned r = rec[base + i];
            int pos = atomicAdd(&lcur[r & 127], 1);
            csr[pos] = (int)(r >> 7);
        }
    } else {
        // ======== gemm1-MFMA: no LDS, no barriers. B frags from L2-resident w1f. ========
        int w = t >> 6, l = t & 63;
        int n0 = (bid - NB) * 64;
        int rrow = n0 + w * 16 + (l & 15);                // A-load row for this lane
        int rc = (rrow < NN) ? rrow : (NN - 1);
        const float* __restrict__ xr = x + (size_t)rc * 512;
        const short8v* __restrict__ wv8 = reinterpret_cast<const short8v*>(w1f);

        f32x4 acc0 = {0.f, 0.f, 0.f, 0.f};
        f32x4 acc1 = {0.f, 0.f, 0.f, 0.f};
        f32x4 acc2 = {0.f, 0.f, 0.f, 0.f};
        f32x4 acc3 = {0.f, 0.f, 0.f, 0.f};

        int lk = (l >> 4) << 3;   // k-offset of this lane's A frag within a 32-k step
#pragma unroll 4
        for (int s = 0; s < 16; ++s) {
            int k0 = s * 32 + lk;
            const float4* xp = reinterpret_cast<const float4*>(xr + k0);
            float4 a0 = xp[0];
            float4 a1 = xp[1];
            short8v af;
            af[0] = (short)f2bf(a0.x); af[1] = (short)f2bf(a0.y);
            af[2] = (short)f2bf(a0.z); af[3] = (short)f2bf(a0.w);
            af[4] = (short)f2bf(a1.x); af[5] = (short)f2bf(a1.y);
            af[6] = (short)f2bf(a1.z); af[7] = (short)f2bf(a1.w);
            const short8v* bp = wv8 + (size_t)(s * 4) * 64 + l;
            short8v bf0 = bp[0];
            short8v bf1 = bp[64];
            short8v bf2 = bp[128];
            short8v bf3 = bp[192];
            acc0 = __builtin_amdgcn_mfma_f32_16x16x32_bf16(af, bf0, acc0, 0, 0, 0);
            acc1 = __builtin_amdgcn_mfma_f32_16x16x32_bf16(af, bf1, acc1, 0, 0, 0);
            acc2 = __builtin_amdgcn_mfma_f32_16x16x32_bf16(af, bf2, acc2, 0, 0, 0);
            acc3 = __builtin_amdgcn_mfma_f32_16x16x32_bf16(af, bf3, acc3, 0, 0, 0);
        }

        // epilogue: C/D layout col=lane&15, row=(lane>>4)*4+reg (m89-verified)
        int hi = (l & 15) >> 3;   // head parity
        int cc = l & 7;           // channel within head
#pragma unroll
        for (int reg = 0; reg < 4; ++reg) {
            int row16 = ((l >> 4) << 2) + reg;
            int r = n0 + w * 16 + row16;
            float v0 = acc0[reg], v1 = acc1[reg], v2 = acc2[reg], v3 = acc3[reg];
            if (r < NN) {
                unsigned short* hp = h1b + (size_t)r * 64 + (l & 15);
                hp[0]  = f2bf(v0);
                hp[16] = f2bf(v1);
                hp[32] = f2bf(v2);
                hp[48] = f2bf(v3);
            }
            float ps[4], pd[4];
            float vv[4] = {v0, v1, v2, v3};
#pragma unroll
            for (int ct = 0; ct < 4; ++ct) {
                int h = ct * 2 + hi;
                ps[ct] = vv[ct] * aS[h * 8 + cc];
                pd[ct] = vv[ct] * aD[h * 8 + cc];
            }
#pragma unroll
            for (int ofs = 1; ofs <= 4; ofs <<= 1) {
#pragma unroll
                for (int ct = 0; ct < 4; ++ct) {
                    ps[ct] += __shfl_xor(ps[ct], ofs);
                    pd[ct] += __shfl_xor(pd[ct], ofs);
                }
            }
            if (cc == 0 && r < NN) {
#pragma unroll
                for (int ct = 0; ct < 4; ++ct) {
                    int h = ct * 2 + hi;
                    as1[r * 8 + h] = ps[ct];
                    ad1[r * 8 + h] = pd[ct];
                }
            }
        }
    }
}

// ---------------- K4: fused layer-1 aggregation + layer-2 GEMM. h1 gathered as bf16.
__global__ __launch_bounds__(256) void k_agg1g(
    const int* __restrict__ obeg, const int* __restrict__ oend, const int* __restrict__ csr,
    const unsigned short* __restrict__ h1b, const float* __restrict__ as1, const float* __restrict__ ad1,
    const float* __restrict__ bias1, const float* __restrict__ W2,
    const float* __restrict__ aS2, const float* __restrict__ aD2,
    unsigned short* __restrict__ h2b, float* __restrict__ as2, float* __restrict__ ad2) {
    __shared__ float w2l[64 * 32];     // 8 KB
    __shared__ float h1ol[4][64];      // per-wave h1o row
    int tid = threadIdx.x;
    for (int i = tid; i < 2048; i += 256) w2l[i] = W2[i];
    __syncthreads();

    int l = tid & 63;
    int wv = tid >> 6;
    int dst = blockIdx.x * 4 + wv;
    if (dst >= NN) return;
    int g = l >> 4;            // edge slot 0..3
    int q = l & 15;            // 4-channel group
    int h = q >> 1;            // head
    int beg = obeg[dst], end = oend[dst];
    int lastj = end - 1;
    float adh = ad1[dst * 8 + h];
    const uint2* __restrict__ h1u = reinterpret_cast<const uint2*>(h1b);

    float4 acc = make_float4(0.f, 0.f, 0.f, 0.f);
    float dsum = 0.f;

    int sA[4], sB[4];
#pragma unroll
    for (int p = 0; p < 4; ++p) sA[p] = csr[min(beg + p * 4 + g, lastj)];
    for (int j = beg; j < end; j += 16) {
#pragma unroll
        for (int p = 0; p < 4; ++p) sB[p] = csr[min(j + 16 + p * 4 + g, lastj)];
        float av[4]; uint2 vv[4];
#pragma unroll
        for (int p = 0; p < 4; ++p) {
            av[p] = as1[sA[p] * 8 + h];
            vv[p] = h1u[(size_t)sA[p] * 16 + q];
        }
#pragma unroll
        for (int p = 0; p < 4; ++p) {
            float e = av[p] + adh; e = (e > 0.f) ? e : 0.2f * e;
            float w = __expf(e);
            w = (j + p * 4 + g < end) ? w : 0.f;
            float x0 = __uint_as_float(vv[p].x << 16);
            float x1 = __uint_as_float(vv[p].x & 0xffff0000u);
            float x2 = __uint_as_float(vv[p].y << 16);
            float x3 = __uint_as_float(vv[p].y & 0xffff0000u);
            acc.x += w * x0; acc.y += w * x1;
            acc.z += w * x2; acc.w += w * x3;
            dsum += w;
        }
#pragma unroll
        for (int p = 0; p < 4; ++p) sA[p] = sB[p];
    }

#pragma unroll
    for (int ofs = 16; ofs <= 32; ofs <<= 1) {
        acc.x += __shfl_xor(acc.x, ofs);
        acc.y += __shfl_xor(acc.y, ofs);
        acc.z += __shfl_xor(acc.z, ofs);
        acc.w += __shfl_xor(acc.w, ofs);
        dsum  += __shfl_xor(dsum, ofs);
    }

    if (g == 0) {
        float inv = 1.f / (dsum + 1e-16f);
        const float4 bq = reinterpret_cast<const float4*>(bias1)[q];
        float4 r;
        r.x = acc.x * inv + bq.x;
        r.y = acc.y * inv + bq.y;
        r.z = acc.z * inv + bq.z;
        r.w = acc.w * inv + bq.w;
        r.x = (r.x > 0.f) ? r.x : (__expf(r.x) - 1.f);
        r.y = (r.y > 0.f) ? r.y : (__expf(r.y) - 1.f);
        r.z = (r.z > 0.f) ? r.z : (__expf(r.z) - 1.f);
        r.w = (r.w > 0.f) ? r.w : (__expf(r.w) - 1.f);
        h1ol[wv][q * 4 + 0] = r.x;
        h1ol[wv][q * 4 + 1] = r.y;
        h1ol[wv][q * 4 + 2] = r.z;
        h1ol[wv][q * 4 + 3] = r.w;
    }

    // fused gemm2; h2 stored bf16
    int c = l & 31, half = l >> 5;
    const float* hrow = h1ol[wv];
    float acc2 = 0.f;
#pragma unroll 8
    for (int kk = 0; kk < 32; ++kk) {
        int k = half * 32 + kk;
        acc2 += hrow[k] * w2l[k * 32 + c];
    }
    acc2 += __shfl_xor(acc2, 32);
    if (l < 32) h2b[(size_t)dst * 32 + c] = f2bf(acc2);
    float ps = acc2 * aS2[c], pd = acc2 * aD2[c];
#pragma unroll
    for (int ofs = 1; ofs <= 16; ofs <<= 1) {
        ps += __shfl_xor(ps, ofs);
        pd += __shfl_xor(pd, ofs);
    }
    if (l == 0) { as2[dst] = ps; ad2[dst] = pd; }
}

// ---------------- K7: layer-2 aggregation; h2 gathered as bf16. o2 fp32.
__global__ __launch_bounds__(256) void k_agg2(
    const int* __restrict__ obeg, const int* __restrict__ oend, const int* __restrict__ csr,
    const unsigned short* __restrict__ h2b, const float* __restrict__ as2, const float* __restrict__ ad2,
    const float* __restrict__ bias2, float* __restrict__ o2) {
    int l = threadIdx.x & 63;
    int dst = blockIdx.x * 4 + (threadIdx.x >> 6);
    if (dst >= NN) return;
    int g = l >> 3;            // edge slot 0..7
    int q = l & 7;             // 4-channel group
    int beg = obeg[dst], end = oend[dst];
    int lastj = end - 1;
    float adh = ad2[dst];
    const uint2* __restrict__ h2u = reinterpret_cast<const uint2*>(h2b);

    float4 acc = make_float4(0.f, 0.f, 0.f, 0.f);
    float dsum = 0.f;

    int sA[4], sB[4];
#pragma unroll
    for (int p = 0; p < 4; ++p) sA[p] = csr[min(beg + p * 8 + g, lastj)];
    for (int j = beg; j < end; j += 32) {
#pragma unroll
        for (int p = 0; p < 4; ++p) sB[p] = csr[min(j + 32 + p * 8 + g, lastj)];
        float av[4]; uint2 vv[4];
#pragma unroll
        for (int p = 0; p < 4; ++p) {
            av[p] = as2[sA[p]];
            vv[p] = h2u[(size_t)sA[p] * 8 + q];
        }
#pragma unroll
        for (int p = 0; p < 4; ++p) {
            float e = av[p] + adh; e = (e > 0.f) ? e : 0.2f * e;
            float w = __expf(e);
            w = (j + p * 8 + g < end) ? w : 0.f;
            float x0 = __uint_as_float(vv[p].x << 16);
            float x1 = __uint_as_float(vv[p].x & 0xffff0000u);
            float x2 = __uint_as_float(vv[p].y << 16);
            float x3 = __uint_as_float(vv[p].y & 0xffff0000u);
            acc.x += w * x0; acc.y += w * x1;
            acc.z += w * x2; acc.w += w * x3;
            dsum += w;
        }
#pragma unroll
        for (int p = 0; p < 4; ++p) sA[p] = sB[p];
    }

#pragma unroll
    for (int ofs = 8; ofs <= 32; ofs <<= 1) {
        acc.x += __shfl_xor(acc.x, ofs);
        acc.y += __shfl_xor(acc.y, ofs);
        acc.z += __shfl_xor(acc.z, ofs);
        acc.w += __shfl_xor(acc.w, ofs);
        dsum  += __shfl_xor(dsum, ofs);
    }

    if (g == 0) {
        float inv = 1.f / (dsum + 1e-16f);
        const float4 bq = reinterpret_cast<const float4*>(bias2)[q];
        float4 r;
        r.x = acc.x * inv + bq.x;
        r.y = acc.y * inv + bq.y;
        r.z = acc.z * inv + bq.z;
        r.w = acc.w * inv + bq.w;
        reinterpret_cast<float4*>(o2)[dst * 8 + q] = r;
    }
}

// ---------------- K9: pooled sums.
__global__ __launch_bounds__(256) void k_pool(const float* __restrict__ o2, const int* __restrict__ lo,
                                              float* __restrict__ pooled) {
    __shared__ float red[256];
    int g = blockIdx.x & 63, q = blockIdx.x >> 6;
    int beg = lo[g], end = lo[g + 1];
    int c = threadIdx.x & 31, row = threadIdx.x >> 5;
    float s = 0.f;
    for (int n = beg + q * 8 + row; n < end; n += 32) s += o2[n * 32 + c];
    red[threadIdx.x] = s;
    __syncthreads();
    for (int rr = 4; rr >= 1; rr >>= 1) {
        if (row < rr) red[threadIdx.x] += red[(row + rr) * 32 + c];
        __syncthreads();
    }
    if (row == 0) atomicAdd(&pooled[g * 32 + c], red[c]);
}

// ---------------- K10: mean + final linear -> out[64][2]
__global__ void k_fin(const float* __restrict__ pooled, const int* __restrict__ lo,
                      const float* __restrict__ lw, const float* __restrict__ lb,
                      float* __restrict__ out) {
    int t = threadIdx.x;
    if (t >= 128) return;
    int g = t >> 1, o = t & 1;
    int cnt = lo[g + 1] - lo[g];
    float inv = 1.f / fmaxf((float)cnt, 1.f);
    float s = 0.f;
#pragma unroll
    for (int c = 0; c < 32; ++c) s += pooled[g * 32 + c] * lw[c * 2 + o];
    out[g * 2 + o] = s * inv + lb[o];
}

// ----------------------------------------------------------------------------
extern "C" void kernel_launch(void* const* d_in, const int* in_sizes, int n_in,
                              void* d_out, int out_size, void* d_ws, size_t ws_size,
                              hipStream_t stream) {
    const float* x   = (const float*)d_in[0];
    const int*   ei  = (const int*)d_in[1];     // [2][NE]
    const int*   bat = (const int*)d_in[2];
    const float* W1  = (const float*)d_in[3];
    const float* aS1 = (const float*)d_in[4];
    const float* aD1 = (const float*)d_in[5];
    const float* b1  = (const float*)d_in[6];
    const float* W2  = (const float*)d_in[7];
    const float* aS2 = (const float*)d_in[8];
    const float* aD2 = (const float*)d_in[9];
    const float* b2  = (const float*)d_in[10];
    const float* lw  = (const float*)d_in[11];
    const float* lb  = (const float*)d_in[12];
    float* out = (float*)d_out;

    const int* esrc = ei;
    const int* edst = ei + NE;

    char* ws = (char*)d_ws;
    size_t off = 0;
    auto alloc = [&](size_t bytes) -> void* {
        off = (off + 255) & ~(size_t)255;
        void* p = ws + off;
        off += bytes;
        return p;
    };

    unsigned short* h1b = (unsigned short*)alloc((size_t)NN * 64 * 2);
    unsigned short* h2b = (unsigned short*)alloc((size_t)NN * 32 * 2);
    float* o2   = (float*)alloc((size_t)NN * 32 * 4);
    float* as1  = (float*)alloc((size_t)NN * 8 * 4);
    float* ad1  = (float*)alloc((size_t)NN * 8 * 4);
    float* as2  = (float*)alloc((size_t)NN * 4);
    float* ad2  = (float*)alloc((size_t)NN * 4);
    int*   obeg = (int*)alloc((size_t)NN * 4);
    int*   oend = (int*)alloc((size_t)NN * 4);
    int*   csr  = (int*)alloc((size_t)NB * CAP * 4);
    unsigned* rec = (unsigned*)alloc((size_t)NB * CAP * 4);
    int*   gcnt = (int*)alloc((size_t)NB * 4);
    unsigned short* w1f = (unsigned short*)alloc((size_t)512 * 64 * 2);
    float* pooled = (float*)alloc((size_t)NG * 32 * 4);
    int*   lo   = (int*)alloc((size_t)(NG + 1) * 4);
    if (off > ws_size) return;   // workspace too small: leave d_out poisoned (visible failure)

    hipMemsetAsync(gcnt, 0, (size_t)NB * 4, stream);
    hipMemsetAsync(pooled, 0, (size_t)NG * 32 * 4, stream);

    k_f0<<<BIN_BLOCKS + WFRAG_BLOCKS + SCAN_BLOCKS, 256, 0, stream>>>(
        esrc, edst, gcnt, rec, W1, w1f, bat, lo);
    k_f1<<<NB + GEMM1_BLOCKS, 256, 0, stream>>>(
        gcnt, rec, obeg, oend, csr, x, w1f, aS1, aD1, h1b, as1, ad1);

    k_agg1g<<<(NN + 3) / 4, 256, 0, stream>>>(obeg, oend, csr, h1b, as1, ad1, b1,
                                              W2, aS2, aD2, h2b, as2, ad2);
    k_agg2<<<(NN + 3) / 4, 256, 0, stream>>>(obeg, oend, csr, h2b, as2, ad2, b2, o2);

    k_pool<<<NG * 4, 256, 0, stream>>>(o2, lo, pooled);
    k_fin<<<1, 128, 0, stream>>>(pooled, lo, lw, lb, out);
}

// Round 25
// 150.925 us; speedup vs baseline: 1.8142x; 1.0039x over previous
//
#include <hip/hip_runtime.h>
#include <cstdint>
#include <cstddef>

#define NN 50000
#define NE 1600000
#define ET (NE + NN)          // edges + self loops
#define NG 64
#define SCAN_BLOCKS ((NN + 255) / 256)   // 196
#define NB ((NN + 127) >> 7)             // 391 dst-buckets, 128 nodes each
#define CAP 6144                         // slots per bucket segment
#define EPT 16
#define EPB (256 * EPT)                  // 4096 edges per bin-block
#define BIN_BLOCKS ((ET + EPB - 1) / EPB)
#define GEMM1_BLOCKS ((NN + 63) / 64)    // 782
#define WFRAG_BLOCKS 16                  // 4096 frag-slots / 256

typedef __attribute__((ext_vector_type(8))) short short8v;
typedef __attribute__((ext_vector_type(4))) float f32x4;

__device__ inline unsigned short f2bf(float f) {
    unsigned u = __float_as_uint(f);
    u += 0x7fffu + ((u >> 16) & 1u);     // round-to-nearest-even
    return (unsigned short)(u >> 16);
}

// ---------------- F0: bin (403) || wfrag (16) || bound (196)
__global__ __launch_bounds__(256) void k_f0(
    const int* __restrict__ esrc, const int* __restrict__ edst,
    int* __restrict__ gcnt, unsigned* __restrict__ rec,
    const float* __restrict__ W1, unsigned short* __restrict__ w1f,
    const int* __restrict__ batch, int* __restrict__ lo) {
    __shared__ int bcnt[NB];
    int bid = blockIdx.x, tid = threadIdx.x;
    if (bid < BIN_BLOCKS) {
        for (int b = tid; b < NB; b += 256) bcnt[b] = 0;
        __syncthreads();
        int e0 = bid * EPB;
        unsigned rv[EPT]; int bk[EPT]; int rk[EPT];
#pragma unroll
        for (int q = 0; q < EPT; ++q) {
            int e = e0 + q * 256 + tid;
            rk[q] = -1;
            if (e < ET) {
                int s, d;
                if (e < NE) { s = esrc[e]; d = edst[e]; } else { s = d = e - NE; }
                rv[q] = ((unsigned)s << 7) | (unsigned)(d & 127);
                bk[q] = d >> 7;
                rk[q] = atomicAdd(&bcnt[bk[q]], 1);
            }
        }
        __syncthreads();
        for (int b = tid; b < NB; b += 256)
            bcnt[b] = atomicAdd(&gcnt[b], bcnt[b]);
        __syncthreads();
#pragma unroll
        for (int q = 0; q < EPT; ++q) {
            if (rk[q] >= 0) rec[(size_t)bk[q] * CAP + bcnt[bk[q]] + rk[q]] = rv[q];
        }
    } else if (bid < BIN_BLOCKS + WFRAG_BLOCKS) {
        // ---- wfrag: pack W1 (512x64 fp32) into MFMA B-fragment order, bf16.
        int slot = (bid - BIN_BLOCKS) * 256 + tid;   // 0..4095
        int S = slot >> 8;
        int ct = (slot >> 6) & 3;
        int l = slot & 63;
        int kb = S * 32 + ((l >> 4) << 3);
        int c = ct * 16 + (l & 15);
        unsigned short* dst = w1f + (size_t)slot * 8;
#pragma unroll
        for (int j = 0; j < 8; ++j)
            dst[j] = f2bf(W1[(kb + j) * 64 + c]);
    } else {
        int n = (bid - BIN_BLOCKS - WFRAG_BLOCKS) * 256 + tid;
        if (n >= NN) return;
        int b = batch[n];
        if (n == 0) {
            for (int g = 0; g <= b; ++g) lo[g] = 0;
        } else {
            int pb = batch[n - 1];
            for (int g = pb + 1; g <= b; ++g) lo[g] = n;
        }
        if (n == NN - 1) {
            for (int g = b + 1; g <= NG; ++g) lo[g] = NN;
        }
    }
}

// ---------------- F1: unbin2 (391 blocks) || gemm1-MFMA barrier-free, reg-dbuf (782).
__global__ __launch_bounds__(256, 4) void k_f1(
    const int* __restrict__ gcnt, const unsigned* __restrict__ rec,
    int* __restrict__ obeg, int* __restrict__ oend, int* __restrict__ csr,
    const float* __restrict__ x, const unsigned short* __restrict__ w1f,
    const float* __restrict__ aS, const float* __restrict__ aD,
    unsigned short* __restrict__ h1b, float* __restrict__ as1, float* __restrict__ ad1) {
    __shared__ int sm[256];           // 1 KB, unbin2 only
    int bid = blockIdx.x, t = threadIdx.x;

    if (bid < NB) {
        // ======== unbin2 ========
        int* cnt  = sm;
        int* lcur = sm + 128;
        int b = bid, tid = t;
        if (tid < 128) cnt[tid] = 0;
        __syncthreads();
        size_t base = (size_t)b * CAP;
        int nrec = gcnt[b];
        for (int i = tid; i < nrec; i += 256)
            atomicAdd(&cnt[rec[base + i] & 127], 1);
        __syncthreads();
        int v = 0, incl = 0;
        if (tid < 128) {
            int lane = tid & 63;
            v = cnt[tid];
            incl = v;
#pragma unroll
            for (int ofs = 1; ofs < 64; ofs <<= 1) {
                int o = __shfl_up(incl, ofs);
                if (lane >= ofs) incl += o;
            }
            cnt[tid] = incl;
        }
        __syncthreads();
        if (tid < 128) {
            int ex = incl - v + ((tid >= 64) ? cnt[63] : 0);
            int n = (b << 7) + tid;
            int pos = (int)base + ex;
            if (n < NN) { obeg[n] = pos; oend[n] = pos + v; }
            lcur[tid] = pos;
        }
        __syncthreads();
        for (int i = tid; i < nrec; i += 256) {
            unsigned r = rec[base + i];
            int pos = atomicAdd(&lcur[r & 127], 1);
            csr[pos] = (int)(r >> 7);
        }
    } else {
        // ======== gemm1-MFMA: no LDS, no barriers, register double-buffer over steps ========
        int w = t >> 6, l = t & 63;
        int n0 = (bid - NB) * 64;
        int rrow = n0 + w * 16 + (l & 15);                // A-load row for this lane
        int rc = (rrow < NN) ? rrow : (NN - 1);
        const float* __restrict__ xr = x + (size_t)rc * 512;
        const short8v* __restrict__ wv8 = reinterpret_cast<const short8v*>(w1f);

        f32x4 acc0 = {0.f, 0.f, 0.f, 0.f};
        f32x4 acc1 = {0.f, 0.f, 0.f, 0.f};
        f32x4 acc2 = {0.f, 0.f, 0.f, 0.f};
        f32x4 acc3 = {0.f, 0.f, 0.f, 0.f};

        int lk = (l >> 4) << 3;   // k-offset of this lane's A frag within a 32-k step

#define LDA(S, A0, A1) { const float4* _p = reinterpret_cast<const float4*>(xr + (S) * 32 + lk); \
                         A0 = _p[0]; A1 = _p[1]; }
#define LDB(S, B0, B1, B2, B3) { const short8v* _bp = wv8 + (size_t)((S) * 4) * 64 + l; \
                         B0 = _bp[0]; B1 = _bp[64]; B2 = _bp[128]; B3 = _bp[192]; }

        float4 aA0, aA1, aB0, aB1;
        short8v bA0, bA1, bA2, bA3, bB0, bB1, bB2, bB3;
        LDA(0, aA0, aA1);
        LDB(0, bA0, bA1, bA2, bA3);

#pragma unroll
        for (int s = 0; s < 16; ++s) {
            int sn = (s + 1 < 16) ? (s + 1) : 15;   // clamped prefetch (no OOB on last row)
            if (s & 1) {
                LDA(sn, aA0, aA1);
                LDB(sn, bA0, bA1, bA2, bA3);
                short8v af;
                af[0] = (short)f2bf(aB0.x); af[1] = (short)f2bf(aB0.y);
                af[2] = (short)f2bf(aB0.z); af[3] = (short)f2bf(aB0.w);
                af[4] = (short)f2bf(aB1.x); af[5] = (short)f2bf(aB1.y);
                af[6] = (short)f2bf(aB1.z); af[7] = (short)f2bf(aB1.w);
                acc0 = __builtin_amdgcn_mfma_f32_16x16x32_bf16(af, bB0, acc0, 0, 0, 0);
                acc1 = __builtin_amdgcn_mfma_f32_16x16x32_bf16(af, bB1, acc1, 0, 0, 0);
                acc2 = __builtin_amdgcn_mfma_f32_16x16x32_bf16(af, bB2, acc2, 0, 0, 0);
                acc3 = __builtin_amdgcn_mfma_f32_16x16x32_bf16(af, bB3, acc3, 0, 0, 0);
            } else {
                LDA(sn, aB0, aB1);
                LDB(sn, bB0, bB1, bB2, bB3);
                short8v af;
                af[0] = (short)f2bf(aA0.x); af[1] = (short)f2bf(aA0.y);
                af[2] = (short)f2bf(aA0.z); af[3] = (short)f2bf(aA0.w);
                af[4] = (short)f2bf(aA1.x); af[5] = (short)f2bf(aA1.y);
                af[6] = (short)f2bf(aA1.z); af[7] = (short)f2bf(aA1.w);
                acc0 = __builtin_amdgcn_mfma_f32_16x16x32_bf16(af, bA0, acc0, 0, 0, 0);
                acc1 = __builtin_amdgcn_mfma_f32_16x16x32_bf16(af, bA1, acc1, 0, 0, 0);
                acc2 = __builtin_amdgcn_mfma_f32_16x16x32_bf16(af, bA2, acc2, 0, 0, 0);
                acc3 = __builtin_amdgcn_mfma_f32_16x16x32_bf16(af, bA3, acc3, 0, 0, 0);
            }
        }
#undef LDA
#undef LDB

        // epilogue: C/D layout col=lane&15, row=(lane>>4)*4+reg (m89-verified)
        int hi = (l & 15) >> 3;   // head parity
        int cc = l & 7;           // channel within head
#pragma unroll
        for (int reg = 0; reg < 4; ++reg) {
            int row16 = ((l >> 4) << 2) + reg;
            int r = n0 + w * 16 + row16;
            float v0 = acc0[reg], v1 = acc1[reg], v2 = acc2[reg], v3 = acc3[reg];
            if (r < NN) {
                unsigned short* hp = h1b + (size_t)r * 64 + (l & 15);
                hp[0]  = f2bf(v0);
                hp[16] = f2bf(v1);
                hp[32] = f2bf(v2);
                hp[48] = f2bf(v3);
            }
            float ps[4], pd[4];
            float vv[4] = {v0, v1, v2, v3};
#pragma unroll
            for (int ct = 0; ct < 4; ++ct) {
                int h = ct * 2 + hi;
                ps[ct] = vv[ct] * aS[h * 8 + cc];
                pd[ct] = vv[ct] * aD[h * 8 + cc];
            }
#pragma unroll
            for (int ofs = 1; ofs <= 4; ofs <<= 1) {
#pragma unroll
                for (int ct = 0; ct < 4; ++ct) {
                    ps[ct] += __shfl_xor(ps[ct], ofs);
                    pd[ct] += __shfl_xor(pd[ct], ofs);
                }
            }
            if (cc == 0 && r < NN) {
#pragma unroll
                for (int ct = 0; ct < 4; ++ct) {
                    int h = ct * 2 + hi;
                    as1[r * 8 + h] = ps[ct];
                    ad1[r * 8 + h] = pd[ct];
                }
            }
        }
    }
}

// ---------------- K4: fused layer-1 aggregation + layer-2 GEMM. h1 gathered as bf16.
__global__ __launch_bounds__(256) void k_agg1g(
    const int* __restrict__ obeg, const int* __restrict__ oend, const int* __restrict__ csr,
    const unsigned short* __restrict__ h1b, const float* __restrict__ as1, const float* __restrict__ ad1,
    const float* __restrict__ bias1, const float* __restrict__ W2,
    const float* __restrict__ aS2, const float* __restrict__ aD2,
    unsigned short* __restrict__ h2b, float* __restrict__ as2, float* __restrict__ ad2) {
    __shared__ float w2l[64 * 32];     // 8 KB
    __shared__ float h1ol[4][64];      // per-wave h1o row
    int tid = threadIdx.x;
    for (int i = tid; i < 2048; i += 256) w2l[i] = W2[i];
    __syncthreads();

    int l = tid & 63;
    int wv = tid >> 6;
    int dst = blockIdx.x * 4 + wv;
    if (dst >= NN) return;
    int g = l >> 4;            // edge slot 0..3
    int q = l & 15;            // 4-channel group
    int h = q >> 1;            // head
    int beg = obeg[dst], end = oend[dst];
    int lastj = end - 1;
    float adh = ad1[dst * 8 + h];
    const uint2* __restrict__ h1u = reinterpret_cast<const uint2*>(h1b);

    float4 acc = make_float4(0.f, 0.f, 0.f, 0.f);
    float dsum = 0.f;

    int sA[4], sB[4];
#pragma unroll
    for (int p = 0; p < 4; ++p) sA[p] = csr[min(beg + p * 4 + g, lastj)];
    for (int j = beg; j < end; j += 16) {
#pragma unroll
        for (int p = 0; p < 4; ++p) sB[p] = csr[min(j + 16 + p * 4 + g, lastj)];
        float av[4]; uint2 vv[4];
#pragma unroll
        for (int p = 0; p < 4; ++p) {
            av[p] = as1[sA[p] * 8 + h];
            vv[p] = h1u[(size_t)sA[p] * 16 + q];
        }
#pragma unroll
        for (int p = 0; p < 4; ++p) {
            float e = av[p] + adh; e = (e > 0.f) ? e : 0.2f * e;
            float w = __expf(e);
            w = (j + p * 4 + g < end) ? w : 0.f;
            float x0 = __uint_as_float(vv[p].x << 16);
            float x1 = __uint_as_float(vv[p].x & 0xffff0000u);
            float x2 = __uint_as_float(vv[p].y << 16);
            float x3 = __uint_as_float(vv[p].y & 0xffff0000u);
            acc.x += w * x0; acc.y += w * x1;
            acc.z += w * x2; acc.w += w * x3;
            dsum += w;
        }
#pragma unroll
        for (int p = 0; p < 4; ++p) sA[p] = sB[p];
    }

#pragma unroll
    for (int ofs = 16; ofs <= 32; ofs <<= 1) {
        acc.x += __shfl_xor(acc.x, ofs);
        acc.y += __shfl_xor(acc.y, ofs);
        acc.z += __shfl_xor(acc.z, ofs);
        acc.w += __shfl_xor(acc.w, ofs);
        dsum  += __shfl_xor(dsum, ofs);
    }

    if (g == 0) {
        float inv = 1.f / (dsum + 1e-16f);
        const float4 bq = reinterpret_cast<const float4*>(bias1)[q];
        float4 r;
        r.x = acc.x * inv + bq.x;
        r.y = acc.y * inv + bq.y;
        r.z = acc.z * inv + bq.z;
        r.w = acc.w * inv + bq.w;
        r.x = (r.x > 0.f) ? r.x : (__expf(r.x) - 1.f);
        r.y = (r.y > 0.f) ? r.y : (__expf(r.y) - 1.f);
        r.z = (r.z > 0.f) ? r.z : (__expf(r.z) - 1.f);
        r.w = (r.w > 0.f) ? r.w : (__expf(r.w) - 1.f);
        h1ol[wv][q * 4 + 0] = r.x;
        h1ol[wv][q * 4 + 1] = r.y;
        h1ol[wv][q * 4 + 2] = r.z;
        h1ol[wv][q * 4 + 3] = r.w;
    }

    // fused gemm2; h2 stored bf16
    int c = l & 31, half = l >> 5;
    const float* hrow = h1ol[wv];
    float acc2 = 0.f;
#pragma unroll 8
    for (int kk = 0; kk < 32; ++kk) {
        int k = half * 32 + kk;
        acc2 += hrow[k] * w2l[k * 32 + c];
    }
    acc2 += __shfl_xor(acc2, 32);
    if (l < 32) h2b[(size_t)dst * 32 + c] = f2bf(acc2);
    float ps = acc2 * aS2[c], pd = acc2 * aD2[c];
#pragma unroll
    for (int ofs = 1; ofs <= 16; ofs <<= 1) {
        ps += __shfl_xor(ps, ofs);
        pd += __shfl_xor(pd, ofs);
    }
    if (l == 0) { as2[dst] = ps; ad2[dst] = pd; }
}

// ---------------- K7: layer-2 aggregation; h2 gathered as bf16. o2 fp32.
__global__ __launch_bounds__(256) void k_agg2(
    const int* __restrict__ obeg, const int* __restrict__ oend, const int* __restrict__ csr,
    const unsigned short* __restrict__ h2b, const float* __restrict__ as2, const float* __restrict__ ad2,
    const float* __restrict__ bias2, float* __restrict__ o2) {
    int l = threadIdx.x & 63;
    int dst = blockIdx.x * 4 + (threadIdx.x >> 6);
    if (dst >= NN) return;
    int g = l >> 3;            // edge slot 0..7
    int q = l & 7;             // 4-channel group
    int beg = obeg[dst], end = oend[dst];
    int lastj = end - 1;
    float adh = ad2[dst];
    const uint2* __restrict__ h2u = reinterpret_cast<const uint2*>(h2b);

    float4 acc = make_float4(0.f, 0.f, 0.f, 0.f);
    float dsum = 0.f;

    int sA[4], sB[4];
#pragma unroll
    for (int p = 0; p < 4; ++p) sA[p] = csr[min(beg + p * 8 + g, lastj)];
    for (int j = beg; j < end; j += 32) {
#pragma unroll
        for (int p = 0; p < 4; ++p) sB[p] = csr[min(j + 32 + p * 8 + g, lastj)];
        float av[4]; uint2 vv[4];
#pragma unroll
        for (int p = 0; p < 4; ++p) {
            av[p] = as2[sA[p]];
            vv[p] = h2u[(size_t)sA[p] * 8 + q];
        }
#pragma unroll
        for (int p = 0; p < 4; ++p) {
            float e = av[p] + adh; e = (e > 0.f) ? e : 0.2f * e;
            float w = __expf(e);
            w = (j + p * 8 + g < end) ? w : 0.f;
            float x0 = __uint_as_float(vv[p].x << 16);
            float x1 = __uint_as_float(vv[p].x & 0xffff0000u);
            float x2 = __uint_as_float(vv[p].y << 16);
            float x3 = __uint_as_float(vv[p].y & 0xffff0000u);
            acc.x += w * x0; acc.y += w * x1;
            acc.z += w * x2; acc.w += w * x3;
            dsum += w;
        }
#pragma unroll
        for (int p = 0; p < 4; ++p) sA[p] = sB[p];
    }

#pragma unroll
    for (int ofs = 8; ofs <= 32; ofs <<= 1) {
        acc.x += __shfl_xor(acc.x, ofs);
        acc.y += __shfl_xor(acc.y, ofs);
        acc.z += __shfl_xor(acc.z, ofs);
        acc.w += __shfl_xor(acc.w, ofs);
        dsum  += __shfl_xor(dsum, ofs);
    }

    if (g == 0) {
        float inv = 1.f / (dsum + 1e-16f);
        const float4 bq = reinterpret_cast<const float4*>(bias2)[q];
        float4 r;
        r.x = acc.x * inv + bq.x;
        r.y = acc.y * inv + bq.y;
        r.z = acc.z * inv + bq.z;
        r.w = acc.w * inv + bq.w;
        reinterpret_cast<float4*>(o2)[dst * 8 + q] = r;
    }
}

// ---------------- K9: pooled sums.
__global__ __launch_bounds__(256) void k_pool(const float* __restrict__ o2, const int* __restrict__ lo,
                                              float* __restrict__ pooled) {
    __shared__ float red[256];
    int g = blockIdx.x & 63, q = blockIdx.x >> 6;
    int beg = lo[g], end = lo[g + 1];
    int c = threadIdx.x & 31, row = threadIdx.x >> 5;
    float s = 0.f;
    for (int n = beg + q * 8 + row; n < end; n += 32) s += o2[n * 32 + c];
    red[threadIdx.x] = s;
    __syncthreads();
    for (int rr = 4; rr >= 1; rr >>= 1) {
        if (row < rr) red[threadIdx.x] += red[(row + rr) * 32 + c];
        __syncthreads();
    }
    if (row == 0) atomicAdd(&pooled[g * 32 + c], red[c]);
}

// ---------------- K10: mean + final linear -> out[64][2]
__global__ void k_fin(const float* __restrict__ pooled, const int* __restrict__ lo,
                      const float* __restrict__ lw, const float* __restrict__ lb,
                      float* __restrict__ out) {
    int t = threadIdx.x;
    if (t >= 128) return;
    int g = t >> 1, o = t & 1;
    int cnt = lo[g + 1] - lo[g];
    float inv = 1.f / fmaxf((float)cnt, 1.f);
    float s = 0.f;
#pragma unroll
    for (int c = 0; c < 32; ++c) s += pooled[g * 32 + c] * lw[c * 2 + o];
    out[g * 2 + o] = s * inv + lb[o];
}

// ----------------------------------------------------------------------------
extern "C" void kernel_launch(void* const* d_in, const int* in_sizes, int n_in,
                              void* d_out, int out_size, void* d_ws, size_t ws_size,
                              hipStream_t stream) {
    const float* x   = (const float*)d_in[0];
    const int*   ei  = (const int*)d_in[1];     // [2][NE]
    const int*   bat = (const int*)d_in[2];
    const float* W1  = (const float*)d_in[3];
    const float* aS1 = (const float*)d_in[4];
    const float* aD1 = (const float*)d_in[5];
    const float* b1  = (const float*)d_in[6];
    const float* W2  = (const float*)d_in[7];
    const float* aS2 = (const float*)d_in[8];
    const float* aD2 = (const float*)d_in[9];
    const float* b2  = (const float*)d_in[10];
    const float* lw  = (const float*)d_in[11];
    const float* lb  = (const float*)d_in[12];
    float* out = (float*)d_out;

    const int* esrc = ei;
    const int* edst = ei + NE;

    char* ws = (char*)d_ws;
    size_t off = 0;
    auto alloc = [&](size_t bytes) -> void* {
        off = (off + 255) & ~(size_t)255;
        void* p = ws + off;
        off += bytes;
        return p;
    };

    unsigned short* h1b = (unsigned short*)alloc((size_t)NN * 64 * 2);
    unsigned short* h2b = (unsigned short*)alloc((size_t)NN * 32 * 2);
    float* o2   = (float*)alloc((size_t)NN * 32 * 4);
    float* as1  = (float*)alloc((size_t)NN * 8 * 4);
    float* ad1  = (float*)alloc((size_t)NN * 8 * 4);
    float* as2  = (float*)alloc((size_t)NN * 4);
    float* ad2  = (float*)alloc((size_t)NN * 4);
    int*   obeg = (int*)alloc((size_t)NN * 4);
    int*   oend = (int*)alloc((size_t)NN * 4);
    int*   csr  = (int*)alloc((size_t)NB * CAP * 4);
    unsigned* rec = (unsigned*)alloc((size_t)NB * CAP * 4);
    int*   gcnt = (int*)alloc((size_t)NB * 4);
    unsigned short* w1f = (unsigned short*)alloc((size_t)512 * 64 * 2);
    float* pooled = (float*)alloc((size_t)NG * 32 * 4);
    int*   lo   = (int*)alloc((size_t)(NG + 1) * 4);
    if (off > ws_size) return;   // workspace too small: leave d_out poisoned (visible failure)

    hipMemsetAsync(gcnt, 0, (size_t)NB * 4, stream);
    hipMemsetAsync(pooled, 0, (size_t)NG * 32 * 4, stream);

    k_f0<<<BIN_BLOCKS + WFRAG_BLOCKS + SCAN_BLOCKS, 256, 0, stream>>>(
        esrc, edst, gcnt, rec, W1, w1f, bat, lo);
    k_f1<<<NB + GEMM1_BLOCKS, 256, 0, stream>>>(
        gcnt, rec, obeg, oend, csr, x, w1f, aS1, aD1, h1b, as1, ad1);

    k_agg1g<<<(NN + 3) / 4, 256, 0, stream>>>(obeg, oend, csr, h1b, as1, ad1, b1,
                                              W2, aS2, aD2, h2b, as2, ad2);
    k_agg2<<<(NN + 3) / 4, 256, 0, stream>>>(obeg, oend, csr, h2b, as2, ad2, b2, o2);

    k_pool<<<NG * 4, 256, 0, stream>>>(o2, lo, pooled);
    k_fin<<<1, 128, 0, stream>>>(pooled, lo, lw, lb, out);
}